// Round 2
// baseline (878.149 us; speedup 1.0000x reference)
//
#include <hip/hip_runtime.h>
#include <hip/hip_bf16.h>

#define NNODES 50000
#define NEDGES 400000
#define ETOT   (NEDGES + NNODES)
#define CIN    15
#define HID    128
#define HEADS  4
#define EPS_BN 1e-5f

// ---------------------------------------------------------------------------
// Generic tiled f32 GEMM:  C[M,Ncols] = act(A[M,K] @ B[K,Ncols] + bias)
// BM=BN=64, BK=64, block 256, 4x4 register tile, LDS padded stride 68 (odd*4)
// ---------------------------------------------------------------------------
__global__ __launch_bounds__(256) void gemm_kernel(
    const float* __restrict__ A, const float* __restrict__ B,
    const float* __restrict__ bias, float* __restrict__ C,
    int M, int Ncols, int K, int act) {
  constexpr int BKP = 68;
  __shared__ __align__(16) float As[64 * BKP];
  __shared__ __align__(16) float Bs[64 * BKP];  // transposed: Bs[c][k]
  const int bm = blockIdx.x * 64;
  const int bn = blockIdx.y * 64;
  const int tid = threadIdx.x;
  const int tr = tid >> 4;   // 0..15
  const int tc = tid & 15;   // 0..15

  float acc[4][4] = {};

  for (int kt = 0; kt < K; kt += 64) {
    // load A tile (64 rows x 64 k), coalesced along k
    for (int l = tid; l < 64 * 64; l += 256) {
      int r = l >> 6, kk = l & 63;
      int gr = bm + r, gk = kt + kk;
      As[r * BKP + kk] = (gr < M && gk < K) ? A[(size_t)gr * K + gk] : 0.0f;
    }
    // load B tile transposed (Bs[c][k]), coalesced along c
    for (int l = tid; l < 64 * 64; l += 256) {
      int kk = l >> 6, c = l & 63;
      int gk = kt + kk, gc = bn + c;
      Bs[c * BKP + kk] = (gk < K && gc < Ncols) ? B[(size_t)gk * Ncols + gc] : 0.0f;
    }
    __syncthreads();

    int kmax = K - kt; if (kmax > 64) kmax = 64;
    int K4 = (kmax + 3) & ~3;  // padded region is zero, safe
    for (int k = 0; k < K4; k += 4) {
      float4 a[4], b[4];
#pragma unroll
      for (int i = 0; i < 4; ++i)
        a[i] = *(const float4*)&As[(tr + 16 * i) * BKP + k];
#pragma unroll
      for (int j = 0; j < 4; ++j)
        b[j] = *(const float4*)&Bs[(tc + 16 * j) * BKP + k];
#pragma unroll
      for (int i = 0; i < 4; ++i)
#pragma unroll
        for (int j = 0; j < 4; ++j)
          acc[i][j] += a[i].x * b[j].x + a[i].y * b[j].y +
                       a[i].z * b[j].z + a[i].w * b[j].w;
    }
    __syncthreads();
  }

#pragma unroll
  for (int i = 0; i < 4; ++i) {
    int r = bm + tr + 16 * i;
    if (r >= M) continue;
#pragma unroll
    for (int j = 0; j < 4; ++j) {
      int c = bn + tc + 16 * j;
      if (c >= Ncols) continue;
      float v = acc[i][j];
      if (bias) v += bias[c];
      if (act) v = fmaxf(v, 0.0f);
      C[(size_t)r * Ncols + c] = v;
    }
  }
}

// ---------------------------------------------------------------------------
// GAT attention coefficients: a_s[n,h] = <hg[n,h,:], att_src[h,:]>, same a_d.
// One block (256 thr = 4 waves) per node; wave h reduces 128 channels.
// ---------------------------------------------------------------------------
__global__ __launch_bounds__(256) void att_coef_kernel(
    const float* __restrict__ hg, const float* __restrict__ att_src,
    const float* __restrict__ att_dst, float* __restrict__ a_s,
    float* __restrict__ a_d) {
  int n = blockIdx.x;
  int h = threadIdx.x >> 6;
  int lane = threadIdx.x & 63;
  const float* row = hg + (size_t)n * (HEADS * HID) + h * HID;
  float v0 = row[lane], v1 = row[64 + lane];
  const float* as = att_src + h * HID;
  const float* ad = att_dst + h * HID;
  float s = v0 * as[lane] + v1 * as[64 + lane];
  float d = v0 * ad[lane] + v1 * ad[64 + lane];
#pragma unroll
  for (int off = 32; off > 0; off >>= 1) {
    s += __shfl_down(s, off);
    d += __shfl_down(d, off);
  }
  if (lane == 0) {
    a_s[n * HEADS + h] = s;
    a_d[n * HEADS + h] = d;
  }
}

// ---------------------------------------------------------------------------
// CSR build (by dst): count -> scan -> scatter
// ---------------------------------------------------------------------------
__global__ void count_kernel(const int* __restrict__ ei, int* __restrict__ cnt) {
  int i = blockIdx.x * blockDim.x + threadIdx.x;
  if (i >= ETOT) return;
  int d = (i < NEDGES) ? ei[NEDGES + i] : (i - NEDGES);
  atomicAdd(&cnt[d], 1);
}

__global__ __launch_bounds__(1024) void scan_kernel(const int* __restrict__ cnt,
                                                    int* __restrict__ rowptr) {
  __shared__ int sums[1024];
  int t = threadIdx.x;
  int chunk = (NNODES + 1023) / 1024;
  int beg = t * chunk;
  int end = beg + chunk; if (end > NNODES) end = NNODES;
  int s = 0;
  for (int i = beg; i < end && i < NNODES; ++i) s += cnt[i];
  sums[t] = s;
  __syncthreads();
  for (int off = 1; off < 1024; off <<= 1) {
    int v = (t >= off) ? sums[t - off] : 0;
    __syncthreads();
    sums[t] += v;
    __syncthreads();
  }
  int run = (t == 0) ? 0 : sums[t - 1];
  for (int i = beg; i < end && i < NNODES; ++i) {
    rowptr[i] = run;
    run += cnt[i];
  }
  if (t == 1023) rowptr[NNODES] = sums[1023];
}

__global__ void scatter_kernel(const int* __restrict__ ei,
                               const float* __restrict__ ea,
                               const int* __restrict__ rowptr,
                               int* __restrict__ cursor,
                               int* __restrict__ csr_src,
                               float* __restrict__ csr_ew) {
  int i = blockIdx.x * blockDim.x + threadIdx.x;
  if (i >= ETOT) return;
  int s, d; float w;
  if (i < NEDGES) { s = ei[i]; d = ei[NEDGES + i]; w = ea[i]; }
  else            { s = d = i - NEDGES; w = 1.0f; }
  int pos = rowptr[d] + atomicAdd(&cursor[d], 1);
  csr_src[pos] = s;
  csr_ew[pos] = w;
}

__global__ void dinv_kernel(const int* __restrict__ rowptr,
                            const float* __restrict__ csr_ew,
                            float* __restrict__ dinv) {
  int n = blockIdx.x * blockDim.x + threadIdx.x;
  if (n >= NNODES) return;
  float s = 0.0f;
  int e0 = rowptr[n], e1 = rowptr[n + 1];
  for (int e = e0; e < e1; ++e) s += csr_ew[e];
  dinv[n] = (s > 0.0f) ? rsqrtf(fmaxf(s, 1e-12f)) : 0.0f;
}

// ---------------------------------------------------------------------------
// GAT gather: per dst node, 2-pass softmax over incoming edges (CSR),
// head-mean + bias + BN0 + ReLU fused. Block=128 threads (one per channel).
// ---------------------------------------------------------------------------
__device__ __forceinline__ float lrelu02(float x) {
  return x > 0.0f ? x : 0.2f * x;
}

__global__ __launch_bounds__(128) void gat_gather_kernel(
    const float* __restrict__ hg, const float* __restrict__ a_s,
    const float* __restrict__ a_d, const int* __restrict__ rowptr,
    const int* __restrict__ csr_src, const float* __restrict__ b_gat,
    const float* __restrict__ bg, const float* __restrict__ bb,
    const float* __restrict__ bm, const float* __restrict__ bv,
    float* __restrict__ out) {
  int n = blockIdx.x;
  int c = threadIdx.x;
  int e0 = rowptr[n], e1 = rowptr[n + 1];
  float ad0 = a_d[n * 4 + 0], ad1 = a_d[n * 4 + 1];
  float ad2 = a_d[n * 4 + 2], ad3 = a_d[n * 4 + 3];

  // pass 1: per-head max (redundant across threads, cheap)
  float m0 = -1e30f, m1 = -1e30f, m2 = -1e30f, m3 = -1e30f;
  for (int e = e0; e < e1; ++e) {
    int s = csr_src[e];
    m0 = fmaxf(m0, lrelu02(a_s[s * 4 + 0] + ad0));
    m1 = fmaxf(m1, lrelu02(a_s[s * 4 + 1] + ad1));
    m2 = fmaxf(m2, lrelu02(a_s[s * 4 + 2] + ad2));
    m3 = fmaxf(m3, lrelu02(a_s[s * 4 + 3] + ad3));
  }

  // pass 2: exp-sum + weighted accumulate
  float s0 = 0.f, s1 = 0.f, s2 = 0.f, s3 = 0.f;
  float acc0 = 0.f, acc1 = 0.f, acc2 = 0.f, acc3 = 0.f;
  for (int e = e0; e < e1; ++e) {
    int s = csr_src[e];
    const float* hrow = hg + (size_t)s * (HEADS * HID);
    float x0 = expf(lrelu02(a_s[s * 4 + 0] + ad0) - m0);
    float x1 = expf(lrelu02(a_s[s * 4 + 1] + ad1) - m1);
    float x2 = expf(lrelu02(a_s[s * 4 + 2] + ad2) - m2);
    float x3 = expf(lrelu02(a_s[s * 4 + 3] + ad3) - m3);
    s0 += x0; s1 += x1; s2 += x2; s3 += x3;
    acc0 += x0 * hrow[c];
    acc1 += x1 * hrow[HID + c];
    acc2 += x2 * hrow[2 * HID + c];
    acc3 += x3 * hrow[3 * HID + c];
  }

  float o = 0.25f * (acc0 / (s0 + 1e-16f) + acc1 / (s1 + 1e-16f) +
                     acc2 / (s2 + 1e-16f) + acc3 / (s3 + 1e-16f)) + b_gat[c];
  // BN(layer 0) + ReLU
  o = bg[c] * (o - bm[c]) * rsqrtf(bv[c] + EPS_BN) + bb[c];
  o = fmaxf(o, 0.0f);
  out[(size_t)n * HID + c] = o;
}

// ---------------------------------------------------------------------------
// GCN gather: out[n,c] = relu(BN(sum_e norm_e * h[src_e, c] + bias[c]))
// ---------------------------------------------------------------------------
__global__ __launch_bounds__(128) void gcn_gather_kernel(
    const float* __restrict__ h, const float* __restrict__ dinv,
    const int* __restrict__ rowptr, const int* __restrict__ csr_src,
    const float* __restrict__ csr_ew, const float* __restrict__ bias,
    const float* __restrict__ bg, const float* __restrict__ bb,
    const float* __restrict__ bm, const float* __restrict__ bv,
    float* __restrict__ out) {
  int n = blockIdx.x;
  int c = threadIdx.x;
  int e0 = rowptr[n], e1 = rowptr[n + 1];
  float di = dinv[n];
  float acc = 0.0f;
  for (int e = e0; e < e1; ++e) {
    int s = csr_src[e];
    float w = dinv[s] * csr_ew[e] * di;
    acc += w * h[(size_t)s * HID + c];
  }
  float o = acc + bias[c];
  o = bg[c] * (o - bm[c]) * rsqrtf(bv[c] + EPS_BN) + bb[c];
  o = fmaxf(o, 0.0f);
  out[(size_t)n * HID + c] = o;
}

// ---------------------------------------------------------------------------
// Pack the three 128x64 head weights into one contiguous 128x192 matrix
// ---------------------------------------------------------------------------
__global__ void pack_heads_kernel(
    const float* __restrict__ w_m1, const float* __restrict__ w_i1,
    const float* __restrict__ w_e1, const float* __restrict__ b_m1,
    const float* __restrict__ b_i1, const float* __restrict__ b_e1,
    float* __restrict__ w192, float* __restrict__ b192) {
  int i = blockIdx.x * blockDim.x + threadIdx.x;
  if (i < 128 * 192) {
    int k = i / 192, c = i % 192;
    float v = (c < 64) ? w_m1[k * 64 + c]
            : (c < 128) ? w_i1[k * 64 + (c - 64)]
                        : w_e1[k * 64 + (c - 128)];
    w192[i] = v;
  }
  if (i < 192) {
    b192[i] = (i < 64) ? b_m1[i] : (i < 128) ? b_i1[i - 64] : b_e1[i - 128];
  }
}

// ---------------------------------------------------------------------------
// Final heads: from h192[N,192] (hm|hi|he) compute 5 outputs per node.
// One wave per node; 64-lane shuffle reductions.
// ---------------------------------------------------------------------------
__global__ __launch_bounds__(256) void heads_final_kernel(
    const float* __restrict__ h192, const float* __restrict__ w_m2,
    const float* __restrict__ b_m2, const float* __restrict__ w_i2,
    const float* __restrict__ b_i2, const float* __restrict__ w_e2,
    const float* __restrict__ b_e2, float* __restrict__ out) {
  int wid = threadIdx.x >> 6;
  int lane = threadIdx.x & 63;
  int n = blockIdx.x * 4 + wid;
  if (n >= NNODES) return;
  const float* row = h192 + (size_t)n * 192;
  float hm = row[lane], hi = row[64 + lane], he = row[128 + lane];
  float p0 = hm * w_m2[lane * 2 + 0];
  float p1 = hm * w_m2[lane * 2 + 1];
  float p2 = hi * w_i2[lane * 2 + 0];
  float p3 = hi * w_i2[lane * 2 + 1];
  float p4 = he * w_e2[lane];
#pragma unroll
  for (int off = 32; off > 0; off >>= 1) {
    p0 += __shfl_down(p0, off);
    p1 += __shfl_down(p1, off);
    p2 += __shfl_down(p2, off);
    p3 += __shfl_down(p3, off);
    p4 += __shfl_down(p4, off);
  }
  if (lane == 0) {
    out[n * 2 + 0] = p0 + b_m2[0];
    out[n * 2 + 1] = p1 + b_m2[1];
    out[2 * NNODES + n * 2 + 0] = p2 + b_i2[0];
    out[2 * NNODES + n * 2 + 1] = p3 + b_i2[1];
    out[4 * NNODES + n] = p4 + b_e2[0];
  }
}

// ---------------------------------------------------------------------------
extern "C" void kernel_launch(void* const* d_in, const int* in_sizes, int n_in,
                              void* d_out, int out_size, void* d_ws, size_t ws_size,
                              hipStream_t stream) {
  const float* x       = (const float*)d_in[0];
  const int*   ei      = (const int*)d_in[1];
  const float* ea      = (const float*)d_in[2];
  const float* w_gat   = (const float*)d_in[3];
  const float* att_src = (const float*)d_in[4];
  const float* att_dst = (const float*)d_in[5];
  const float* b_gat   = (const float*)d_in[6];
  const float* w2 = (const float*)d_in[7];  const float* b2 = (const float*)d_in[8];
  const float* w3 = (const float*)d_in[9];  const float* b3 = (const float*)d_in[10];
  const float* w4 = (const float*)d_in[11]; const float* b4 = (const float*)d_in[12];
  const float* bn_g = (const float*)d_in[13];
  const float* bn_b = (const float*)d_in[14];
  const float* bn_m = (const float*)d_in[15];
  const float* bn_v = (const float*)d_in[16];
  const float* w_shared = (const float*)d_in[17]; const float* b_shared = (const float*)d_in[18];
  const float* w_m1 = (const float*)d_in[19]; const float* b_m1 = (const float*)d_in[20];
  const float* w_m2 = (const float*)d_in[21]; const float* b_m2 = (const float*)d_in[22];
  const float* w_i1 = (const float*)d_in[23]; const float* b_i1 = (const float*)d_in[24];
  const float* w_i2 = (const float*)d_in[25]; const float* b_i2 = (const float*)d_in[26];
  const float* w_e1 = (const float*)d_in[27]; const float* b_e1 = (const float*)d_in[28];
  const float* w_e2 = (const float*)d_in[29]; const float* b_e2 = (const float*)d_in[30];
  float* out = (float*)d_out;

  // ---- workspace layout ----
  size_t off = 0;
  auto alloc = [&](size_t bytes) -> char* {
    char* p = (char*)d_ws + off;
    off += (bytes + 255) & ~(size_t)255;
    return p;
  };
  float* hg      = (float*)alloc((size_t)NNODES * 512 * 4);  // GAT h; later aliased
  float* p0      = (float*)alloc((size_t)NNODES * HID * 4);
  float* hb      = (float*)alloc((size_t)NNODES * HID * 4);  // gemm temp
  float* a_s     = (float*)alloc((size_t)NNODES * 4 * 4);
  float* a_d     = (float*)alloc((size_t)NNODES * 4 * 4);
  float* dinv    = (float*)alloc((size_t)NNODES * 4);
  float* csr_ew  = (float*)alloc((size_t)ETOT * 4);
  float* w192    = (float*)alloc((size_t)128 * 192 * 4);
  float* b192    = (float*)alloc((size_t)192 * 4);
  int*   rowptr  = (int*)alloc((size_t)(NNODES + 1) * 4);
  int*   cnt     = (int*)alloc((size_t)NNODES * 4);
  int*   csr_src = (int*)alloc((size_t)ETOT * 4);
  // aliases into the (dead-after-GAT) hg region:
  float* p1   = hg;                          // N*128
  float* h192 = hg + (size_t)NNODES * HID;   // N*192, disjoint from p1

  dim3 blk256(256), blk128(128);

  // 1) hg = x @ w_gat  [N,512], K=15
  gemm_kernel<<<dim3((NNODES + 63) / 64, 512 / 64), blk256, 0, stream>>>(
      x, w_gat, nullptr, hg, NNODES, 512, CIN, 0);

  // 2) attention coefficients
  att_coef_kernel<<<NNODES, blk256, 0, stream>>>(hg, att_src, att_dst, a_s, a_d);

  // 3) CSR build
  hipMemsetAsync(cnt, 0, NNODES * 4, stream);
  count_kernel<<<(ETOT + 255) / 256, blk256, 0, stream>>>(ei, cnt);
  scan_kernel<<<1, 1024, 0, stream>>>(cnt, rowptr);
  hipMemsetAsync(cnt, 0, NNODES * 4, stream);
  scatter_kernel<<<(ETOT + 255) / 256, blk256, 0, stream>>>(
      ei, ea, rowptr, cnt, csr_src, csr_ew);
  dinv_kernel<<<(NNODES + 255) / 256, blk256, 0, stream>>>(rowptr, csr_ew, dinv);

  // 4) GAT gather + BN0 + ReLU  -> p0
  gat_gather_kernel<<<NNODES, blk128, 0, stream>>>(
      hg, a_s, a_d, rowptr, csr_src, b_gat,
      bn_g + 0, bn_b + 0, bn_m + 0, bn_v + 0, p0);

  // pack head weights (independent, do now)
  pack_heads_kernel<<<(128 * 192 + 255) / 256, blk256, 0, stream>>>(
      w_m1, w_i1, w_e1, b_m1, b_i1, b_e1, w192, b192);

  dim3 ggrid((NNODES + 63) / 64, HID / 64);

  // 5) GCN layer 2: hb = p0 @ w2 ; p1 = gather(hb)+b2, BN1, ReLU
  gemm_kernel<<<ggrid, blk256, 0, stream>>>(p0, w2, nullptr, hb, NNODES, HID, HID, 0);
  gcn_gather_kernel<<<NNODES, blk128, 0, stream>>>(
      hb, dinv, rowptr, csr_src, csr_ew, b2,
      bn_g + 128, bn_b + 128, bn_m + 128, bn_v + 128, p1);

  // 6) GCN layer 3
  gemm_kernel<<<ggrid, blk256, 0, stream>>>(p1, w3, nullptr, hb, NNODES, HID, HID, 0);
  gcn_gather_kernel<<<NNODES, blk128, 0, stream>>>(
      hb, dinv, rowptr, csr_src, csr_ew, b3,
      bn_g + 256, bn_b + 256, bn_m + 256, bn_v + 256, p0);

  // 7) GCN layer 4
  gemm_kernel<<<ggrid, blk256, 0, stream>>>(p0, w4, nullptr, hb, NNODES, HID, HID, 0);
  gcn_gather_kernel<<<NNODES, blk128, 0, stream>>>(
      hb, dinv, rowptr, csr_src, csr_ew, b4,
      bn_g + 384, bn_b + 384, bn_m + 384, bn_v + 384, p1);

  // 8) hs = relu(p1 @ w_shared + b_shared) -> p0
  gemm_kernel<<<ggrid, blk256, 0, stream>>>(p1, w_shared, b_shared, p0, NNODES, HID, HID, 1);

  // 9) h192 = relu(p0 @ w192 + b192)
  gemm_kernel<<<dim3((NNODES + 63) / 64, 192 / 64), blk256, 0, stream>>>(
      p0, w192, b192, h192, NNODES, 192, HID, 1);

  // 10) final heads -> d_out
  heads_final_kernel<<<(NNODES + 3) / 4, blk256, 0, stream>>>(
      h192, w_m2, b_m2, w_i2, b_i2, w_e2, b_e2, out);
}

// Round 4
// 776.060 us; speedup vs baseline: 1.1315x; 1.1315x over previous
//
#include <hip/hip_runtime.h>
#include <hip/hip_bf16.h>

#define NNODES 50000
#define NEDGES 400000
#define ETOT   (NEDGES + NNODES)
#define CIN    15
#define HID    128
#define HEADS  4
#define EPS_BN 1e-5f

__device__ __forceinline__ float bfu(unsigned short u) {
  return __uint_as_float(((unsigned)u) << 16);
}
__device__ __forceinline__ float lrelu02(float x) {
  return x > 0.0f ? x : 0.2f * x;
}

// ---------------------------------------------------------------------------
// Generic tiled f32 GEMM:  C[M,Ncols] = act(A[M,K] @ B[K,Ncols] + bias)
// BM=BN=64, BK=64, block 256, 4x4 register tile. obf16: write C as bf16.
// ---------------------------------------------------------------------------
__global__ __launch_bounds__(256) void gemm_kernel(
    const float* __restrict__ A, const float* __restrict__ B,
    const float* __restrict__ bias, void* __restrict__ Cout,
    int M, int Ncols, int K, int act, int obf16) {
  constexpr int BKP = 68;
  __shared__ __align__(16) float As[64 * BKP];
  __shared__ __align__(16) float Bs[64 * BKP];  // transposed: Bs[c][k]
  const int bm = blockIdx.x * 64;
  const int bn = blockIdx.y * 64;
  const int tid = threadIdx.x;
  const int tr = tid >> 4;   // 0..15
  const int tc = tid & 15;   // 0..15

  float acc[4][4] = {};

  for (int kt = 0; kt < K; kt += 64) {
    for (int l = tid; l < 64 * 64; l += 256) {
      int r = l >> 6, kk = l & 63;
      int gr = bm + r, gk = kt + kk;
      As[r * BKP + kk] = (gr < M && gk < K) ? A[(size_t)gr * K + gk] : 0.0f;
    }
    for (int l = tid; l < 64 * 64; l += 256) {
      int kk = l >> 6, c = l & 63;
      int gk = kt + kk, gc = bn + c;
      Bs[c * BKP + kk] = (gk < K && gc < Ncols) ? B[(size_t)gk * Ncols + gc] : 0.0f;
    }
    __syncthreads();

    int kmax = K - kt; if (kmax > 64) kmax = 64;
    int K4 = (kmax + 3) & ~3;
    for (int k = 0; k < K4; k += 4) {
      float4 a[4], b[4];
#pragma unroll
      for (int i = 0; i < 4; ++i)
        a[i] = *(const float4*)&As[(tr + 16 * i) * BKP + k];
#pragma unroll
      for (int j = 0; j < 4; ++j)
        b[j] = *(const float4*)&Bs[(tc + 16 * j) * BKP + k];
#pragma unroll
      for (int i = 0; i < 4; ++i)
#pragma unroll
        for (int j = 0; j < 4; ++j)
          acc[i][j] += a[i].x * b[j].x + a[i].y * b[j].y +
                       a[i].z * b[j].z + a[i].w * b[j].w;
    }
    __syncthreads();
  }

#pragma unroll
  for (int i = 0; i < 4; ++i) {
    int r = bm + tr + 16 * i;
    if (r >= M) continue;
#pragma unroll
    for (int j = 0; j < 4; ++j) {
      int c = bn + tc + 16 * j;
      if (c >= Ncols) continue;
      float v = acc[i][j];
      if (bias) v += bias[c];
      if (act) v = fmaxf(v, 0.0f);
      if (obf16)
        ((__hip_bfloat16*)Cout)[(size_t)r * Ncols + c] = __float2bfloat16(v);
      else
        ((float*)Cout)[(size_t)r * Ncols + c] = v;
    }
  }
}

// ---------------------------------------------------------------------------
// Fused GAT input GEMM:  hg(bf16)[N,512] = x[N,15] @ w_gat[15,512]
// Epilogue also accumulates a_s[n,h] = <h[n,h,:], att_src[h,:]> (and a_d)
// via 16-lane shuffle partials + one f32 atomicAdd per row per block.
// Requires a_s/a_d zero-initialized.
// ---------------------------------------------------------------------------
__global__ __launch_bounds__(256) void gemm_gat_kernel(
    const float* __restrict__ x, const float* __restrict__ w,
    const float* __restrict__ att_s, const float* __restrict__ att_d,
    __hip_bfloat16* __restrict__ hg, float* __restrict__ a_s,
    float* __restrict__ a_d) {
  __shared__ __align__(16) float As[64 * 20];  // [row][k], stride 20
  __shared__ __align__(16) float Bs[64 * 20];  // [col][k], stride 20
  const int bm = blockIdx.x * 64;
  const int bn = blockIdx.y * 64;
  const int tid = threadIdx.x;
  const int tr = tid >> 4;
  const int tc = tid & 15;
  const int head = bn >> 7;            // 64-col tile lies in one head
  const int cih0 = bn & 127;           // col-in-head base

  for (int l = tid; l < 64 * 16; l += 256) {
    int r = l >> 4, k = l & 15;
    int gr = bm + r;
    As[r * 20 + k] = (k < CIN && gr < NNODES) ? x[(size_t)gr * CIN + k] : 0.0f;
  }
  for (int l = tid; l < 64 * 16; l += 256) {
    int k = l >> 6;          // 0..15
    int c = l & 63;
    Bs[c * 20 + k] = (k < CIN) ? w[(size_t)k * 512 + bn + c] : 0.0f;
  }
  __syncthreads();

  float acc[4][4] = {};
  for (int k = 0; k < 16; k += 4) {
    float4 a[4], b[4];
#pragma unroll
    for (int i = 0; i < 4; ++i) a[i] = *(const float4*)&As[(tr + 16 * i) * 20 + k];
#pragma unroll
    for (int j = 0; j < 4; ++j) b[j] = *(const float4*)&Bs[(tc + 16 * j) * 20 + k];
#pragma unroll
    for (int i = 0; i < 4; ++i)
#pragma unroll
      for (int j = 0; j < 4; ++j)
        acc[i][j] += a[i].x * b[j].x + a[i].y * b[j].y +
                     a[i].z * b[j].z + a[i].w * b[j].w;
  }

  // att weights for this thread's 4 columns
  float asc[4], adc[4];
#pragma unroll
  for (int j = 0; j < 4; ++j) {
    int cih = cih0 + tc + 16 * j;
    asc[j] = att_s[head * HID + cih];
    adc[j] = att_d[head * HID + cih];
  }

#pragma unroll
  for (int i = 0; i < 4; ++i) {
    int r = bm + tr + 16 * i;
    float ps = 0.f, pd = 0.f;
    if (r < NNODES) {
#pragma unroll
      for (int j = 0; j < 4; ++j) {
        float v = acc[i][j];
        hg[(size_t)r * 512 + bn + tc + 16 * j] = __float2bfloat16(v);
        ps += v * asc[j];
        pd += v * adc[j];
      }
    }
    // reduce over the 16 tc-lanes (lane groups share tr)
#pragma unroll
    for (int off = 1; off < 16; off <<= 1) {
      ps += __shfl_xor(ps, off);
      pd += __shfl_xor(pd, off);
    }
    if (tc == 0 && r < NNODES) {
      atomicAdd(&a_s[r * 4 + head], ps);
      atomicAdd(&a_d[r * 4 + head], pd);
    }
  }
}

// ---------------------------------------------------------------------------
// CSR build (by dst): count -> scan -> scatter
// ---------------------------------------------------------------------------
__global__ void count_kernel(const int* __restrict__ ei, int* __restrict__ cnt) {
  int i = blockIdx.x * blockDim.x + threadIdx.x;
  if (i >= ETOT) return;
  int d = (i < NEDGES) ? ei[NEDGES + i] : (i - NEDGES);
  atomicAdd(&cnt[d], 1);
}

__global__ __launch_bounds__(1024) void scan_kernel(const int* __restrict__ cnt,
                                                    int* __restrict__ rowptr) {
  __shared__ int sums[1024];
  int t = threadIdx.x;
  int chunk = (NNODES + 1023) / 1024;
  int beg = t * chunk;
  int end = beg + chunk; if (end > NNODES) end = NNODES;
  int s = 0;
  for (int i = beg; i < end; ++i) s += cnt[i];
  sums[t] = s;
  __syncthreads();
  for (int off = 1; off < 1024; off <<= 1) {
    int v = (t >= off) ? sums[t - off] : 0;
    __syncthreads();
    sums[t] += v;
    __syncthreads();
  }
  int run = (t == 0) ? 0 : sums[t - 1];
  for (int i = beg; i < end; ++i) {
    rowptr[i] = run;
    run += cnt[i];
  }
  if (t == 1023) rowptr[NNODES] = sums[1023];
}

__global__ void scatter_kernel(const int* __restrict__ ei,
                               const float* __restrict__ ea,
                               const int* __restrict__ rowptr,
                               int* __restrict__ cursor,
                               int* __restrict__ csr_src,
                               float* __restrict__ csr_ew) {
  int i = blockIdx.x * blockDim.x + threadIdx.x;
  if (i >= ETOT) return;
  int s, d; float w;
  if (i < NEDGES) { s = ei[i]; d = ei[NEDGES + i]; w = ea[i]; }
  else            { s = d = i - NEDGES; w = 1.0f; }
  int pos = rowptr[d] + atomicAdd(&cursor[d], 1);
  csr_src[pos] = s;
  csr_ew[pos] = w;
}

__global__ void dinv_kernel(const int* __restrict__ rowptr,
                            const float* __restrict__ csr_ew,
                            float* __restrict__ dinv) {
  int n = blockIdx.x * blockDim.x + threadIdx.x;
  if (n >= NNODES) return;
  float s = 0.0f;
  int e0 = rowptr[n], e1 = rowptr[n + 1];
  for (int e = e0; e < e1; ++e) s += csr_ew[e];
  dinv[n] = (s > 0.0f) ? rsqrtf(fmaxf(s, 1e-12f)) : 0.0f;
}

// ---------------------------------------------------------------------------
// Per-node (wave) kernel: normalized GAT attention alpha[e][4] and
// in-place GCN edge norm csr_ew[e] <- dinv[src]*ew*dinv[dst].
// ---------------------------------------------------------------------------
__global__ __launch_bounds__(256) void alphaw_kernel(
    const float* __restrict__ a_s, const float* __restrict__ a_d,
    const float* __restrict__ dinv, const int* __restrict__ rowptr,
    const int* __restrict__ csr_src, float* __restrict__ csr_ew,
    float* __restrict__ alpha) {
  int wid = threadIdx.x >> 6, lane = threadIdx.x & 63;
  int n = blockIdx.x * 4 + wid;
  if (n >= NNODES) return;
  int e0 = rowptr[n], e1 = rowptr[n + 1];
  float4 ad = *(const float4*)&a_d[n * 4];
  float di = dinv[n];

  float m0 = -1e30f, m1 = -1e30f, m2 = -1e30f, m3 = -1e30f;
  for (int e = e0 + lane; e < e1; e += 64) {
    int s = csr_src[e];
    float4 as4 = *(const float4*)&a_s[s * 4];
    m0 = fmaxf(m0, lrelu02(as4.x + ad.x));
    m1 = fmaxf(m1, lrelu02(as4.y + ad.y));
    m2 = fmaxf(m2, lrelu02(as4.z + ad.z));
    m3 = fmaxf(m3, lrelu02(as4.w + ad.w));
  }
#pragma unroll
  for (int off = 32; off > 0; off >>= 1) {
    m0 = fmaxf(m0, __shfl_xor(m0, off));
    m1 = fmaxf(m1, __shfl_xor(m1, off));
    m2 = fmaxf(m2, __shfl_xor(m2, off));
    m3 = fmaxf(m3, __shfl_xor(m3, off));
  }

  float s0 = 0.f, s1 = 0.f, s2 = 0.f, s3 = 0.f;
  for (int e = e0 + lane; e < e1; e += 64) {
    int s = csr_src[e];
    float4 as4 = *(const float4*)&a_s[s * 4];
    float x0 = __expf(lrelu02(as4.x + ad.x) - m0);
    float x1 = __expf(lrelu02(as4.y + ad.y) - m1);
    float x2 = __expf(lrelu02(as4.z + ad.z) - m2);
    float x3 = __expf(lrelu02(as4.w + ad.w) - m3);
    s0 += x0; s1 += x1; s2 += x2; s3 += x3;
    float4 o; o.x = x0; o.y = x1; o.z = x2; o.w = x3;
    *(float4*)&alpha[(size_t)e * 4] = o;
    csr_ew[e] = dinv[s] * csr_ew[e] * di;   // GCN normalized weight
  }
#pragma unroll
  for (int off = 32; off > 0; off >>= 1) {
    s0 += __shfl_xor(s0, off);
    s1 += __shfl_xor(s1, off);
    s2 += __shfl_xor(s2, off);
    s3 += __shfl_xor(s3, off);
  }
  float r0 = 1.0f / (s0 + 1e-16f), r1 = 1.0f / (s1 + 1e-16f);
  float r2 = 1.0f / (s2 + 1e-16f), r3 = 1.0f / (s3 + 1e-16f);
  for (int e = e0 + lane; e < e1; e += 64) {
    float4 a = *(const float4*)&alpha[(size_t)e * 4];
    a.x *= r0; a.y *= r1; a.z *= r2; a.w *= r3;
    *(float4*)&alpha[(size_t)e * 4] = a;
  }
}

// ---------------------------------------------------------------------------
// GAT gather (pure fma): wave per node, lane handles channels 2l,2l+1.
// out = BN0(relu-in: 0.25*sum_h sum_e alpha*h) fused.
// ---------------------------------------------------------------------------
__global__ __launch_bounds__(256) void gat_gather_kernel(
    const __hip_bfloat16* __restrict__ hg, const float* __restrict__ alpha,
    const int* __restrict__ rowptr, const int* __restrict__ csr_src,
    const float* __restrict__ b_gat,
    const float* __restrict__ bg, const float* __restrict__ bb,
    const float* __restrict__ bm, const float* __restrict__ bv,
    float* __restrict__ out) {
  int wid = threadIdx.x >> 6, lane = threadIdx.x & 63;
  int n = blockIdx.x * 4 + wid;
  if (n >= NNODES) return;
  int e0 = rowptr[n], e1 = rowptr[n + 1];
  int c = 2 * lane;
  float a0x = 0.f, a0y = 0.f, a1x = 0.f, a1y = 0.f;
  float a2x = 0.f, a2y = 0.f, a3x = 0.f, a3y = 0.f;
  for (int e = e0; e < e1; ++e) {
    int s = csr_src[e];
    float4 al = *(const float4*)&alpha[(size_t)e * 4];
    const __hip_bfloat16* hrow = hg + (size_t)s * 512;
    ushort2 u0 = *(const ushort2*)(hrow + c);
    ushort2 u1 = *(const ushort2*)(hrow + 128 + c);
    ushort2 u2 = *(const ushort2*)(hrow + 256 + c);
    ushort2 u3 = *(const ushort2*)(hrow + 384 + c);
    a0x += al.x * bfu(u0.x); a0y += al.x * bfu(u0.y);
    a1x += al.y * bfu(u1.x); a1y += al.y * bfu(u1.y);
    a2x += al.z * bfu(u2.x); a2y += al.z * bfu(u2.y);
    a3x += al.w * bfu(u3.x); a3y += al.w * bfu(u3.y);
  }
  float ox = 0.25f * (a0x + a1x + a2x + a3x) + b_gat[c];
  float oy = 0.25f * (a0y + a1y + a2y + a3y) + b_gat[c + 1];
  ox = bg[c] * (ox - bm[c]) * rsqrtf(bv[c] + EPS_BN) + bb[c];
  oy = bg[c + 1] * (oy - bm[c + 1]) * rsqrtf(bv[c + 1] + EPS_BN) + bb[c + 1];
  ox = fmaxf(ox, 0.0f); oy = fmaxf(oy, 0.0f);
  float2 o; o.x = ox; o.y = oy;
  *(float2*)&out[(size_t)n * HID + c] = o;
}

// ---------------------------------------------------------------------------
// GCN gather: wave per node; h is bf16, csr_w prenormalized.
// ---------------------------------------------------------------------------
__global__ __launch_bounds__(256) void gcn_gather_kernel(
    const __hip_bfloat16* __restrict__ h, const int* __restrict__ rowptr,
    const int* __restrict__ csr_src, const float* __restrict__ csr_w,
    const float* __restrict__ bias,
    const float* __restrict__ bg, const float* __restrict__ bb,
    const float* __restrict__ bm, const float* __restrict__ bv,
    float* __restrict__ out) {
  int wid = threadIdx.x >> 6, lane = threadIdx.x & 63;
  int n = blockIdx.x * 4 + wid;
  if (n >= NNODES) return;
  int e0 = rowptr[n], e1 = rowptr[n + 1];
  int c = 2 * lane;
  float ax = 0.f, ay = 0.f;
  for (int e = e0; e < e1; ++e) {
    int s = csr_src[e];
    float w = csr_w[e];
    ushort2 u = *(const ushort2*)(h + (size_t)s * HID + c);
    ax += w * bfu(u.x);
    ay += w * bfu(u.y);
  }
  float ox = ax + bias[c];
  float oy = ay + bias[c + 1];
  ox = bg[c] * (ox - bm[c]) * rsqrtf(bv[c] + EPS_BN) + bb[c];
  oy = bg[c + 1] * (oy - bm[c + 1]) * rsqrtf(bv[c + 1] + EPS_BN) + bb[c + 1];
  ox = fmaxf(ox, 0.0f); oy = fmaxf(oy, 0.0f);
  float2 o; o.x = ox; o.y = oy;
  *(float2*)&out[(size_t)n * HID + c] = o;
}

// ---------------------------------------------------------------------------
// Pack the three 128x64 head weights into one contiguous 128x192 matrix
// ---------------------------------------------------------------------------
__global__ void pack_heads_kernel(
    const float* __restrict__ w_m1, const float* __restrict__ w_i1,
    const float* __restrict__ w_e1, const float* __restrict__ b_m1,
    const float* __restrict__ b_i1, const float* __restrict__ b_e1,
    float* __restrict__ w192, float* __restrict__ b192) {
  int i = blockIdx.x * blockDim.x + threadIdx.x;
  if (i < 128 * 192) {
    int k = i / 192, c = i % 192;
    float v = (c < 64) ? w_m1[k * 64 + c]
            : (c < 128) ? w_i1[k * 64 + (c - 64)]
                        : w_e1[k * 64 + (c - 128)];
    w192[i] = v;
  }
  if (i < 192) {
    b192[i] = (i < 64) ? b_m1[i] : (i < 128) ? b_i1[i - 64] : b_e1[i - 128];
  }
}

// ---------------------------------------------------------------------------
// Final heads: from h192[N,192] (hm|hi|he) compute 5 outputs per node.
// ---------------------------------------------------------------------------
__global__ __launch_bounds__(256) void heads_final_kernel(
    const float* __restrict__ h192, const float* __restrict__ w_m2,
    const float* __restrict__ b_m2, const float* __restrict__ w_i2,
    const float* __restrict__ b_i2, const float* __restrict__ w_e2,
    const float* __restrict__ b_e2, float* __restrict__ out) {
  int wid = threadIdx.x >> 6;
  int lane = threadIdx.x & 63;
  int n = blockIdx.x * 4 + wid;
  if (n >= NNODES) return;
  const float* row = h192 + (size_t)n * 192;
  float hm = row[lane], hi = row[64 + lane], he = row[128 + lane];
  float p0 = hm * w_m2[lane * 2 + 0];
  float p1 = hm * w_m2[lane * 2 + 1];
  float p2 = hi * w_i2[lane * 2 + 0];
  float p3 = hi * w_i2[lane * 2 + 1];
  float p4 = he * w_e2[lane];
#pragma unroll
  for (int off = 32; off > 0; off >>= 1) {
    p0 += __shfl_down(p0, off);
    p1 += __shfl_down(p1, off);
    p2 += __shfl_down(p2, off);
    p3 += __shfl_down(p3, off);
    p4 += __shfl_down(p4, off);
  }
  if (lane == 0) {
    out[n * 2 + 0] = p0 + b_m2[0];
    out[n * 2 + 1] = p1 + b_m2[1];
    out[2 * NNODES + n * 2 + 0] = p2 + b_i2[0];
    out[2 * NNODES + n * 2 + 1] = p3 + b_i2[1];
    out[4 * NNODES + n] = p4 + b_e2[0];
  }
}

// ---------------------------------------------------------------------------
extern "C" void kernel_launch(void* const* d_in, const int* in_sizes, int n_in,
                              void* d_out, int out_size, void* d_ws, size_t ws_size,
                              hipStream_t stream) {
  const float* x       = (const float*)d_in[0];
  const int*   ei      = (const int*)d_in[1];
  const float* ea      = (const float*)d_in[2];
  const float* w_gat   = (const float*)d_in[3];
  const float* att_src = (const float*)d_in[4];
  const float* att_dst = (const float*)d_in[5];
  const float* b_gat   = (const float*)d_in[6];
  const float* w2 = (const float*)d_in[7];  const float* b2 = (const float*)d_in[8];
  const float* w3 = (const float*)d_in[9];  const float* b3 = (const float*)d_in[10];
  const float* w4 = (const float*)d_in[11]; const float* b4 = (const float*)d_in[12];
  const float* bn_g = (const float*)d_in[13];
  const float* bn_b = (const float*)d_in[14];
  const float* bn_m = (const float*)d_in[15];
  const float* bn_v = (const float*)d_in[16];
  const float* w_shared = (const float*)d_in[17]; const float* b_shared = (const float*)d_in[18];
  const float* w_m1 = (const float*)d_in[19]; const float* b_m1 = (const float*)d_in[20];
  const float* w_m2 = (const float*)d_in[21]; const float* b_m2 = (const float*)d_in[22];
  const float* w_i1 = (const float*)d_in[23]; const float* b_i1 = (const float*)d_in[24];
  const float* w_i2 = (const float*)d_in[25]; const float* b_i2 = (const float*)d_in[26];
  const float* w_e1 = (const float*)d_in[27]; const float* b_e1 = (const float*)d_in[28];
  const float* w_e2 = (const float*)d_in[29]; const float* b_e2 = (const float*)d_in[30];
  float* out = (float*)d_out;

  // ---- workspace layout ----
  size_t off = 0;
  auto alloc = [&](size_t bytes) -> char* {
    char* p = (char*)d_ws + off;
    off += (bytes + 255) & ~(size_t)255;
    return p;
  };
  char*  hgreg   = alloc((size_t)NNODES * 512 * 4);   // bf16 hg; later aliased f32
  float* p0      = (float*)alloc((size_t)NNODES * HID * 4);
  float* hb_f    = (float*)alloc((size_t)NNODES * HID * 4);  // bf16 hb / f32 alpha alias
  float* a_s     = (float*)alloc((size_t)NNODES * 4 * 4);
  float* a_d     = (float*)alloc((size_t)NNODES * 4 * 4);
  float* dinv    = (float*)alloc((size_t)NNODES * 4);
  float* csr_ew  = (float*)alloc((size_t)ETOT * 4);
  float* w192    = (float*)alloc((size_t)128 * 192 * 4);
  float* b192    = (float*)alloc((size_t)192 * 4);
  int*   rowptr  = (int*)alloc((size_t)(NNODES + 1) * 4);
  int*   cnt     = (int*)alloc((size_t)NNODES * 4);
  int*   csr_src = (int*)alloc((size_t)ETOT * 4);

  __hip_bfloat16* hg = (__hip_bfloat16*)hgreg;          // N*512 bf16
  __hip_bfloat16* hb = (__hip_bfloat16*)hb_f;           // N*128 bf16 (GEMM out)
  float* alpha = hb_f;                                  // ETOT*4 f32 (dead before hb used)
  // aliases into the (dead-after-GAT) hg region:
  float* p1   = (float*)hgreg;                          // N*128 f32
  float* h192 = (float*)hgreg + (size_t)NNODES * HID;   // N*192 f32, disjoint

  dim3 blk256(256);
  dim3 wgrid((NNODES + 3) / 4);  // wave-per-node kernels

  // 0) zero attention accumulators
  hipMemsetAsync(a_s, 0, (size_t)NNODES * 4 * 4, stream);
  hipMemsetAsync(a_d, 0, (size_t)NNODES * 4 * 4, stream);

  // 1) fused GAT GEMM: hg(bf16) + a_s/a_d
  gemm_gat_kernel<<<dim3((NNODES + 63) / 64, 8), blk256, 0, stream>>>(
      x, w_gat, att_src, att_dst, hg, a_s, a_d);

  // 2) CSR build
  hipMemsetAsync(cnt, 0, NNODES * 4, stream);
  count_kernel<<<(ETOT + 255) / 256, blk256, 0, stream>>>(ei, cnt);
  scan_kernel<<<1, 1024, 0, stream>>>(cnt, rowptr);
  hipMemsetAsync(cnt, 0, NNODES * 4, stream);
  scatter_kernel<<<(ETOT + 255) / 256, blk256, 0, stream>>>(
      ei, ea, rowptr, cnt, csr_src, csr_ew);
  dinv_kernel<<<(NNODES + 255) / 256, blk256, 0, stream>>>(rowptr, csr_ew, dinv);

  // 3) per-edge alpha + normalized GCN weights
  alphaw_kernel<<<wgrid, blk256, 0, stream>>>(
      a_s, a_d, dinv, rowptr, csr_src, csr_ew, alpha);

  // 4) GAT gather + BN0 + ReLU -> p0
  gat_gather_kernel<<<wgrid, blk256, 0, stream>>>(
      hg, alpha, rowptr, csr_src, b_gat,
      bn_g + 0, bn_b + 0, bn_m + 0, bn_v + 0, p0);

  // pack head weights
  pack_heads_kernel<<<(128 * 192 + 255) / 256, blk256, 0, stream>>>(
      w_m1, w_i1, w_e1, b_m1, b_i1, b_e1, w192, b192);

  dim3 ggrid((NNODES + 63) / 64, HID / 64);

  // 5) GCN layer 2
  gemm_kernel<<<ggrid, blk256, 0, stream>>>(p0, w2, nullptr, hb, NNODES, HID, HID, 0, 1);
  gcn_gather_kernel<<<wgrid, blk256, 0, stream>>>(
      hb, rowptr, csr_src, csr_ew, b2,
      bn_g + 128, bn_b + 128, bn_m + 128, bn_v + 128, p1);

  // 6) GCN layer 3
  gemm_kernel<<<ggrid, blk256, 0, stream>>>(p1, w3, nullptr, hb, NNODES, HID, HID, 0, 1);
  gcn_gather_kernel<<<wgrid, blk256, 0, stream>>>(
      hb, rowptr, csr_src, csr_ew, b3,
      bn_g + 256, bn_b + 256, bn_m + 256, bn_v + 256, p0);

  // 7) GCN layer 4
  gemm_kernel<<<ggrid, blk256, 0, stream>>>(p0, w4, nullptr, hb, NNODES, HID, HID, 0, 1);
  gcn_gather_kernel<<<wgrid, blk256, 0, stream>>>(
      hb, rowptr, csr_src, csr_ew, b4,
      bn_g + 384, bn_b + 384, bn_m + 384, bn_v + 384, p1);

  // 8) hs = relu(p1 @ w_shared + b_shared) -> p0  (f32 out)
  gemm_kernel<<<ggrid, blk256, 0, stream>>>(p1, w_shared, b_shared, p0, NNODES, HID, HID, 1, 0);

  // 9) h192 = relu(p0 @ w192 + b192)  (f32 out)
  gemm_kernel<<<dim3((NNODES + 63) / 64, 192 / 64), blk256, 0, stream>>>(
      p0, w192, b192, h192, NNODES, 192, HID, 1, 0);

  // 10) final heads -> d_out
  heads_final_kernel<<<wgrid, blk256, 0, stream>>>(
      h192, w_m2, b_m2, w_i2, b_i2, w_e2, b_e2, out);
}

// Round 7
// 699.126 us; speedup vs baseline: 1.2561x; 1.1100x over previous
//
#include <hip/hip_runtime.h>
#include <hip/hip_bf16.h>

#define NNODES 50000
#define NEDGES 400000
#define ETOT   (NEDGES + NNODES)
#define CIN    15
#define HID    128
#define HEADS  4
#define EPS_BN 1e-5f

typedef __attribute__((ext_vector_type(8))) short bf16x8_t;   // 8 bf16 = 4 VGPR
typedef __attribute__((ext_vector_type(4))) float f32x4_t;    // MFMA 16x16 acc

__device__ __forceinline__ float bfu(unsigned short u) {
  return __uint_as_float(((unsigned)u) << 16);
}
__device__ __forceinline__ unsigned short f2bf(float x) {
  union { __hip_bfloat16 b; unsigned short u; } c;
  c.b = __float2bfloat16(x);
  return c.u;
}
__device__ __forceinline__ float lrelu02(float x) {
  return x > 0.0f ? x : 0.2f * x;
}

// ---------------------------------------------------------------------------
// Split-bf16 MFMA GEMM:  C[M, NT*16] = act(A[M,128] @ W + bias)
// A f32; W pre-transposed+split to WTh/WTl [N][K] bf16 (hi + residual lo).
// acc = Ah*Wh + Ah*Wl + Al*Wh  (f32 accumulate) ~ f32 precision.
// Block: 256 thr = 4 waves; 64 rows x full N; K=128 staged once in LDS.
// LDS rows XOR-swizzled (byte ^= (row&7)<<4) for conflict-even ds_read_b128.
// ---------------------------------------------------------------------------
template <int NT>
__global__ __launch_bounds__(256) void gemm_mfma_kernel(
    const float* __restrict__ A, const unsigned short* __restrict__ WTh,
    const unsigned short* __restrict__ WTl, const float* __restrict__ bias,
    void* __restrict__ Cout, int act, int obf16) {
  constexpr int K = 128;
  constexpr int NC = NT * 16;
  __shared__ unsigned short Ah[64 * K];
  __shared__ unsigned short Al[64 * K];
  const int tid = threadIdx.x;
  const int bm = blockIdx.x * 64;

  // stage A tile (64 x 128 f32) -> hi/lo bf16, swizzled
#pragma unroll
  for (int i = 0; i < 4; ++i) {
    int cch = tid + 256 * i;            // chunk of 8 elems
    int r = cch >> 4, k0 = (cch & 15) << 3;
    int gr = bm + r;
    float v[8];
    if (gr < NNODES) {
      float4 v0 = *(const float4*)&A[(size_t)gr * K + k0];
      float4 v1 = *(const float4*)&A[(size_t)gr * K + k0 + 4];
      v[0] = v0.x; v[1] = v0.y; v[2] = v0.z; v[3] = v0.w;
      v[4] = v1.x; v[5] = v1.y; v[6] = v1.z; v[7] = v1.w;
    } else {
#pragma unroll
      for (int j = 0; j < 8; ++j) v[j] = 0.0f;
    }
    bf16x8_t hv, lv;
#pragma unroll
    for (int j = 0; j < 8; ++j) {
      unsigned short h = f2bf(v[j]);
      hv[j] = (short)h;
      lv[j] = (short)f2bf(v[j] - bfu(h));
    }
    int byte = (k0 << 1) ^ ((r & 7) << 4);
    *(bf16x8_t*)((char*)(Ah + r * K) + byte) = hv;
    *(bf16x8_t*)((char*)(Al + r * K) + byte) = lv;
  }
  __syncthreads();

  const int wv = tid >> 6, l = tid & 63;
  const int lrow = (wv << 4) + (l & 15);   // A row in block tile
  const int kg = (l >> 4) << 3;            // k offset within 32-chunk
  const int lcol = l & 15;

  f32x4_t acc[NT];
#pragma unroll
  for (int j = 0; j < NT; ++j) acc[j] = (f32x4_t){0.f, 0.f, 0.f, 0.f};

#pragma unroll
  for (int kc = 0; kc < 4; ++kc) {
    int k = kc * 32 + kg;
    int byte = (k << 1) ^ ((lrow & 7) << 4);
    bf16x8_t ah = *(const bf16x8_t*)((const char*)(Ah + lrow * K) + byte);
    bf16x8_t al = *(const bf16x8_t*)((const char*)(Al + lrow * K) + byte);
#pragma unroll
    for (int j = 0; j < NT; ++j) {
      size_t boff = (size_t)(j * 16 + lcol) * K + k;
      bf16x8_t bh = *(const bf16x8_t*)(WTh + boff);
      bf16x8_t bl = *(const bf16x8_t*)(WTl + boff);
      acc[j] = __builtin_amdgcn_mfma_f32_16x16x32_bf16(ah, bh, acc[j], 0, 0, 0);
      acc[j] = __builtin_amdgcn_mfma_f32_16x16x32_bf16(ah, bl, acc[j], 0, 0, 0);
      acc[j] = __builtin_amdgcn_mfma_f32_16x16x32_bf16(al, bh, acc[j], 0, 0, 0);
    }
  }

  // C/D layout (m89-verified): col = lane&15, row = (lane>>4)*4 + reg
  const int orow0 = bm + (wv << 4) + ((l >> 4) << 2);
#pragma unroll
  for (int j = 0; j < NT; ++j) {
    int col = j * 16 + lcol;
    float bs = bias ? bias[col] : 0.0f;
#pragma unroll
    for (int r = 0; r < 4; ++r) {
      int row = orow0 + r;
      if (row >= NNODES) continue;
      float vv = acc[j][r] + bs;
      if (act) vv = fmaxf(vv, 0.0f);
      if (obf16)
        ((unsigned short*)Cout)[(size_t)row * NC + col] = f2bf(vv);
      else
        ((float*)Cout)[(size_t)row * NC + col] = vv;
    }
  }
}

// ---------------------------------------------------------------------------
// Pack: W[K][N] f32 -> WTh/WTl [N][K] bf16 (transpose + hi/lo split)
// ---------------------------------------------------------------------------
__global__ void pack_wt_kernel(const float* __restrict__ W,
                               unsigned short* __restrict__ WTh,
                               unsigned short* __restrict__ WTl,
                               int K, int N) {
  int i = blockIdx.x * blockDim.x + threadIdx.x;
  if (i >= K * N) return;
  int k = i / N, n = i % N;
  float x = W[i];
  unsigned short h = f2bf(x);
  WTh[(size_t)n * K + k] = h;
  WTl[(size_t)n * K + k] = f2bf(x - bfu(h));
}

// Pack the three 128x64 head weights into WT192 [192][128] hi/lo + b192
__global__ void pack_wt192_kernel(
    const float* __restrict__ w_m1, const float* __restrict__ w_i1,
    const float* __restrict__ w_e1, const float* __restrict__ b_m1,
    const float* __restrict__ b_i1, const float* __restrict__ b_e1,
    unsigned short* __restrict__ WTh, unsigned short* __restrict__ WTl,
    float* __restrict__ b192) {
  int i = blockIdx.x * blockDim.x + threadIdx.x;
  if (i < 192 * 128) {
    int n = i >> 7, k = i & 127;
    float x = (n < 64) ? w_m1[k * 64 + n]
            : (n < 128) ? w_i1[k * 64 + (n - 64)]
                        : w_e1[k * 64 + (n - 128)];
    unsigned short h = f2bf(x);
    WTh[(size_t)n * 128 + k] = h;
    WTl[(size_t)n * 128 + k] = f2bf(x - bfu(h));
  }
  if (i < 192) {
    b192[i] = (i < 64) ? b_m1[i] : (i < 128) ? b_i1[i - 64] : b_e1[i - 128];
  }
}

// ---------------------------------------------------------------------------
// Fused GAT input GEMM:  hg(bf16)[N,512] = x[N,15] @ w_gat[15,512]
// Epilogue accumulates a_s/a_d via 16-lane shuffles + one atomicAdd each.
// ---------------------------------------------------------------------------
__global__ __launch_bounds__(256) void gemm_gat_kernel(
    const float* __restrict__ x, const float* __restrict__ w,
    const float* __restrict__ att_s, const float* __restrict__ att_d,
    __hip_bfloat16* __restrict__ hg, float* __restrict__ a_s,
    float* __restrict__ a_d) {
  __shared__ __align__(16) float As[64 * 20];
  __shared__ __align__(16) float Bs[64 * 20];
  const int bm = blockIdx.x * 64;
  const int bn = blockIdx.y * 64;
  const int tid = threadIdx.x;
  const int tr = tid >> 4;
  const int tc = tid & 15;
  const int head = bn >> 7;
  const int cih0 = bn & 127;

  for (int l = tid; l < 64 * 16; l += 256) {
    int r = l >> 4, k = l & 15;
    int gr = bm + r;
    As[r * 20 + k] = (k < CIN && gr < NNODES) ? x[(size_t)gr * CIN + k] : 0.0f;
  }
  for (int l = tid; l < 64 * 16; l += 256) {
    int k = l >> 6;
    int c = l & 63;
    Bs[c * 20 + k] = (k < CIN) ? w[(size_t)k * 512 + bn + c] : 0.0f;
  }
  __syncthreads();

  float acc[4][4] = {};
  for (int k = 0; k < 16; k += 4) {
    float4 a[4], b[4];
#pragma unroll
    for (int i = 0; i < 4; ++i) a[i] = *(const float4*)&As[(tr + 16 * i) * 20 + k];
#pragma unroll
    for (int j = 0; j < 4; ++j) b[j] = *(const float4*)&Bs[(tc + 16 * j) * 20 + k];
#pragma unroll
    for (int i = 0; i < 4; ++i)
#pragma unroll
      for (int j = 0; j < 4; ++j)
        acc[i][j] += a[i].x * b[j].x + a[i].y * b[j].y +
                     a[i].z * b[j].z + a[i].w * b[j].w;
  }

  float asc[4], adc[4];
#pragma unroll
  for (int j = 0; j < 4; ++j) {
    int cih = cih0 + tc + 16 * j;
    asc[j] = att_s[head * HID + cih];
    adc[j] = att_d[head * HID + cih];
  }

#pragma unroll
  for (int i = 0; i < 4; ++i) {
    int r = bm + tr + 16 * i;
    float ps = 0.f, pd = 0.f;
    if (r < NNODES) {
#pragma unroll
      for (int j = 0; j < 4; ++j) {
        float v = acc[i][j];
        hg[(size_t)r * 512 + bn + tc + 16 * j] = __float2bfloat16(v);
        ps += v * asc[j];
        pd += v * adc[j];
      }
    }
#pragma unroll
    for (int off = 1; off < 16; off <<= 1) {
      ps += __shfl_xor(ps, off);
      pd += __shfl_xor(pd, off);
    }
    if (tc == 0 && r < NNODES) {
      atomicAdd(&a_s[r * 4 + head], ps);
      atomicAdd(&a_d[r * 4 + head], pd);
    }
  }
}

// ---------------------------------------------------------------------------
// CSR build (by dst): count -> scan -> scatter
// ---------------------------------------------------------------------------
__global__ void count_kernel(const int* __restrict__ ei, int* __restrict__ cnt) {
  int i = blockIdx.x * blockDim.x + threadIdx.x;
  if (i >= ETOT) return;
  int d = (i < NEDGES) ? ei[NEDGES + i] : (i - NEDGES);
  atomicAdd(&cnt[d], 1);
}

__global__ __launch_bounds__(1024) void scan_kernel(const int* __restrict__ cnt,
                                                    int* __restrict__ rowptr) {
  __shared__ int sums[1024];
  int t = threadIdx.x;
  int chunk = (NNODES + 1023) / 1024;
  int beg = t * chunk;
  int end = beg + chunk; if (end > NNODES) end = NNODES;
  int s = 0;
  for (int i = beg; i < end; ++i) s += cnt[i];
  sums[t] = s;
  __syncthreads();
  for (int off = 1; off < 1024; off <<= 1) {
    int v = (t >= off) ? sums[t - off] : 0;
    __syncthreads();
    sums[t] += v;
    __syncthreads();
  }
  int run = (t == 0) ? 0 : sums[t - 1];
  for (int i = beg; i < end; ++i) {
    rowptr[i] = run;
    run += cnt[i];
  }
  if (t == 1023) rowptr[NNODES] = sums[1023];
}

__global__ void scatter_kernel(const int* __restrict__ ei,
                               const float* __restrict__ ea,
                               const int* __restrict__ rowptr,
                               int* __restrict__ cursor,
                               int* __restrict__ csr_src,
                               float* __restrict__ csr_ew) {
  int i = blockIdx.x * blockDim.x + threadIdx.x;
  if (i >= ETOT) return;
  int s, d; float w;
  if (i < NEDGES) { s = ei[i]; d = ei[NEDGES + i]; w = ea[i]; }
  else            { s = d = i - NEDGES; w = 1.0f; }
  int pos = rowptr[d] + atomicAdd(&cursor[d], 1);
  csr_src[pos] = s;
  csr_ew[pos] = w;
}

__global__ void dinv_kernel(const int* __restrict__ rowptr,
                            const float* __restrict__ csr_ew,
                            float* __restrict__ dinv) {
  int n = blockIdx.x * blockDim.x + threadIdx.x;
  if (n >= NNODES) return;
  float s = 0.0f;
  int e0 = rowptr[n], e1 = rowptr[n + 1];
  for (int e = e0; e < e1; ++e) s += csr_ew[e];
  dinv[n] = (s > 0.0f) ? rsqrtf(fmaxf(s, 1e-12f)) : 0.0f;
}

// ---------------------------------------------------------------------------
// Per-node (wave) kernel: normalized GAT alpha[e][4]; in-place GCN edge norm.
// ---------------------------------------------------------------------------
__global__ __launch_bounds__(256) void alphaw_kernel(
    const float* __restrict__ a_s, const float* __restrict__ a_d,
    const float* __restrict__ dinv, const int* __restrict__ rowptr,
    const int* __restrict__ csr_src, float* __restrict__ csr_ew,
    float* __restrict__ alpha) {
  int wid = threadIdx.x >> 6, lane = threadIdx.x & 63;
  int n = blockIdx.x * 4 + wid;
  if (n >= NNODES) return;
  int e0 = rowptr[n], e1 = rowptr[n + 1];
  float4 ad = *(const float4*)&a_d[n * 4];
  float di = dinv[n];

  float m0 = -1e30f, m1 = -1e30f, m2 = -1e30f, m3 = -1e30f;
  for (int e = e0 + lane; e < e1; e += 64) {
    int s = csr_src[e];
    float4 as4 = *(const float4*)&a_s[s * 4];
    m0 = fmaxf(m0, lrelu02(as4.x + ad.x));
    m1 = fmaxf(m1, lrelu02(as4.y + ad.y));
    m2 = fmaxf(m2, lrelu02(as4.z + ad.z));
    m3 = fmaxf(m3, lrelu02(as4.w + ad.w));
  }
#pragma unroll
  for (int off = 32; off > 0; off >>= 1) {
    m0 = fmaxf(m0, __shfl_xor(m0, off));
    m1 = fmaxf(m1, __shfl_xor(m1, off));
    m2 = fmaxf(m2, __shfl_xor(m2, off));
    m3 = fmaxf(m3, __shfl_xor(m3, off));
  }

  float s0 = 0.f, s1 = 0.f, s2 = 0.f, s3 = 0.f;
  for (int e = e0 + lane; e < e1; e += 64) {
    int s = csr_src[e];
    float4 as4 = *(const float4*)&a_s[s * 4];
    float x0 = __expf(lrelu02(as4.x + ad.x) - m0);
    float x1 = __expf(lrelu02(as4.y + ad.y) - m1);
    float x2 = __expf(lrelu02(as4.z + ad.z) - m2);
    float x3 = __expf(lrelu02(as4.w + ad.w) - m3);
    s0 += x0; s1 += x1; s2 += x2; s3 += x3;
    float4 o; o.x = x0; o.y = x1; o.z = x2; o.w = x3;
    *(float4*)&alpha[(size_t)e * 4] = o;
    csr_ew[e] = dinv[s] * csr_ew[e] * di;
  }
#pragma unroll
  for (int off = 32; off > 0; off >>= 1) {
    s0 += __shfl_xor(s0, off);
    s1 += __shfl_xor(s1, off);
    s2 += __shfl_xor(s2, off);
    s3 += __shfl_xor(s3, off);
  }
  float r0 = 1.0f / (s0 + 1e-16f), r1 = 1.0f / (s1 + 1e-16f);
  float r2 = 1.0f / (s2 + 1e-16f), r3 = 1.0f / (s3 + 1e-16f);
  for (int e = e0 + lane; e < e1; e += 64) {
    float4 a = *(const float4*)&alpha[(size_t)e * 4];
    a.x *= r0; a.y *= r1; a.z *= r2; a.w *= r3;
    *(float4*)&alpha[(size_t)e * 4] = a;
  }
}

// ---------------------------------------------------------------------------
// GAT gather (pure fma): wave per node; bf16 hg; BN0+ReLU fused.
// ---------------------------------------------------------------------------
__global__ __launch_bounds__(256) void gat_gather_kernel(
    const __hip_bfloat16* __restrict__ hg, const float* __restrict__ alpha,
    const int* __restrict__ rowptr, const int* __restrict__ csr_src,
    const float* __restrict__ b_gat,
    const float* __restrict__ bg, const float* __restrict__ bb,
    const float* __restrict__ bm, const float* __restrict__ bv,
    float* __restrict__ out) {
  int wid = threadIdx.x >> 6, lane = threadIdx.x & 63;
  int n = blockIdx.x * 4 + wid;
  if (n >= NNODES) return;
  int e0 = rowptr[n], e1 = rowptr[n + 1];
  int c = 2 * lane;
  float a0x = 0.f, a0y = 0.f, a1x = 0.f, a1y = 0.f;
  float a2x = 0.f, a2y = 0.f, a3x = 0.f, a3y = 0.f;
  for (int e = e0; e < e1; ++e) {
    int s = csr_src[e];
    float4 al = *(const float4*)&alpha[(size_t)e * 4];
    const __hip_bfloat16* hrow = hg + (size_t)s * 512;
    ushort2 u0 = *(const ushort2*)(hrow + c);
    ushort2 u1 = *(const ushort2*)(hrow + 128 + c);
    ushort2 u2 = *(const ushort2*)(hrow + 256 + c);
    ushort2 u3 = *(const ushort2*)(hrow + 384 + c);
    a0x += al.x * bfu(u0.x); a0y += al.x * bfu(u0.y);
    a1x += al.y * bfu(u1.x); a1y += al.y * bfu(u1.y);
    a2x += al.z * bfu(u2.x); a2y += al.z * bfu(u2.y);
    a3x += al.w * bfu(u3.x); a3y += al.w * bfu(u3.y);
  }
  float ox = 0.25f * (a0x + a1x + a2x + a3x) + b_gat[c];
  float oy = 0.25f * (a0y + a1y + a2y + a3y) + b_gat[c + 1];
  ox = bg[c] * (ox - bm[c]) * rsqrtf(bv[c] + EPS_BN) + bb[c];
  oy = bg[c + 1] * (oy - bm[c + 1]) * rsqrtf(bv[c + 1] + EPS_BN) + bb[c + 1];
  ox = fmaxf(ox, 0.0f); oy = fmaxf(oy, 0.0f);
  float2 o; o.x = ox; o.y = oy;
  *(float2*)&out[(size_t)n * HID + c] = o;
}

// ---------------------------------------------------------------------------
// GCN gather: wave per node; h is bf16, csr_w prenormalized; BN+ReLU fused.
// ---------------------------------------------------------------------------
__global__ __launch_bounds__(256) void gcn_gather_kernel(
    const __hip_bfloat16* __restrict__ h, const int* __restrict__ rowptr,
    const int* __restrict__ csr_src, const float* __restrict__ csr_w,
    const float* __restrict__ bias,
    const float* __restrict__ bg, const float* __restrict__ bb,
    const float* __restrict__ bm, const float* __restrict__ bv,
    float* __restrict__ out) {
  int wid = threadIdx.x >> 6, lane = threadIdx.x & 63;
  int n = blockIdx.x * 4 + wid;
  if (n >= NNODES) return;
  int e0 = rowptr[n], e1 = rowptr[n + 1];
  int c = 2 * lane;
  float ax = 0.f, ay = 0.f;
  for (int e = e0; e < e1; ++e) {
    int s = csr_src[e];
    float w = csr_w[e];
    ushort2 u = *(const ushort2*)(h + (size_t)s * HID + c);
    ax += w * bfu(u.x);
    ay += w * bfu(u.y);
  }
  float ox = ax + bias[c];
  float oy = ay + bias[c + 1];
  ox = bg[c] * (ox - bm[c]) * rsqrtf(bv[c] + EPS_BN) + bb[c];
  oy = bg[c + 1] * (oy - bm[c + 1]) * rsqrtf(bv[c + 1] + EPS_BN) + bb[c + 1];
  ox = fmaxf(ox, 0.0f); oy = fmaxf(oy, 0.0f);
  float2 o; o.x = ox; o.y = oy;
  *(float2*)&out[(size_t)n * HID + c] = o;
}

// ---------------------------------------------------------------------------
// Final heads: from h192[N,192] (hm|hi|he) compute 5 outputs per node.
// ---------------------------------------------------------------------------
__global__ __launch_bounds__(256) void heads_final_kernel(
    const float* __restrict__ h192, const float* __restrict__ w_m2,
    const float* __restrict__ b_m2, const float* __restrict__ w_i2,
    const float* __restrict__ b_i2, const float* __restrict__ w_e2,
    const float* __restrict__ b_e2, float* __restrict__ out) {
  int wid = threadIdx.x >> 6;
  int lane = threadIdx.x & 63;
  int n = blockIdx.x * 4 + wid;
  if (n >= NNODES) return;
  const float* row = h192 + (size_t)n * 192;
  float hm = row[lane], hi = row[64 + lane], he = row[128 + lane];
  float p0 = hm * w_m2[lane * 2 + 0];
  float p1 = hm * w_m2[lane * 2 + 1];
  float p2 = hi * w_i2[lane * 2 + 0];
  float p3 = hi * w_i2[lane * 2 + 1];
  float p4 = he * w_e2[lane];
#pragma unroll
  for (int off = 32; off > 0; off >>= 1) {
    p0 += __shfl_down(p0, off);
    p1 += __shfl_down(p1, off);
    p2 += __shfl_down(p2, off);
    p3 += __shfl_down(p3, off);
    p4 += __shfl_down(p4, off);
  }
  if (lane == 0) {
    out[n * 2 + 0] = p0 + b_m2[0];
    out[n * 2 + 1] = p1 + b_m2[1];
    out[2 * NNODES + n * 2 + 0] = p2 + b_i2[0];
    out[2 * NNODES + n * 2 + 1] = p3 + b_i2[1];
    out[4 * NNODES + n] = p4 + b_e2[0];
  }
}

// ---------------------------------------------------------------------------
extern "C" void kernel_launch(void* const* d_in, const int* in_sizes, int n_in,
                              void* d_out, int out_size, void* d_ws, size_t ws_size,
                              hipStream_t stream) {
  const float* x       = (const float*)d_in[0];
  const int*   ei      = (const int*)d_in[1];
  const float* ea      = (const float*)d_in[2];
  const float* w_gat   = (const float*)d_in[3];
  const float* att_src = (const float*)d_in[4];
  const float* att_dst = (const float*)d_in[5];
  const float* b_gat   = (const float*)d_in[6];
  const float* w2 = (const float*)d_in[7];  const float* b2 = (const float*)d_in[8];
  const float* w3 = (const float*)d_in[9];  const float* b3 = (const float*)d_in[10];
  const float* w4 = (const float*)d_in[11]; const float* b4 = (const float*)d_in[12];
  const float* bn_g = (const float*)d_in[13];
  const float* bn_b = (const float*)d_in[14];
  const float* bn_m = (const float*)d_in[15];
  const float* bn_v = (const float*)d_in[16];
  const float* w_shared = (const float*)d_in[17]; const float* b_shared = (const float*)d_in[18];
  const float* w_m1 = (const float*)d_in[19]; const float* b_m1 = (const float*)d_in[20];
  const float* w_m2 = (const float*)d_in[21]; const float* b_m2 = (const float*)d_in[22];
  const float* w_i1 = (const float*)d_in[23]; const float* b_i1 = (const float*)d_in[24];
  const float* w_i2 = (const float*)d_in[25]; const float* b_i2 = (const float*)d_in[26];
  const float* w_e1 = (const float*)d_in[27]; const float* b_e1 = (const float*)d_in[28];
  const float* w_e2 = (const float*)d_in[29]; const float* b_e2 = (const float*)d_in[30];
  float* out = (float*)d_out;

  // ---- workspace layout ----
  size_t off = 0;
  auto alloc = [&](size_t bytes) -> char* {
    char* p = (char*)d_ws + off;
    off += (bytes + 255) & ~(size_t)255;
    return p;
  };
  char*  hgreg   = alloc((size_t)NNODES * 512 * 4);   // bf16 hg; later aliased f32
  float* p0      = (float*)alloc((size_t)NNODES * HID * 4);
  float* hb_f    = (float*)alloc((size_t)NNODES * HID * 4);  // bf16 hb / f32 alpha alias
  float* a_s     = (float*)alloc((size_t)NNODES * 4 * 4);
  float* a_d     = (float*)alloc((size_t)NNODES * 4 * 4);
  float* dinv    = (float*)alloc((size_t)NNODES * 4);
  float* csr_ew  = (float*)alloc((size_t)ETOT * 4);
  int*   rowptr  = (int*)alloc((size_t)(NNODES + 1) * 4);
  int*   cnt     = (int*)alloc((size_t)NNODES * 4);
  int*   csr_src = (int*)alloc((size_t)ETOT * 4);
  // split-bf16 transposed weights
  unsigned short* wt2h = (unsigned short*)alloc(128 * 128 * 2);
  unsigned short* wt2l = (unsigned short*)alloc(128 * 128 * 2);
  unsigned short* wt3h = (unsigned short*)alloc(128 * 128 * 2);
  unsigned short* wt3l = (unsigned short*)alloc(128 * 128 * 2);
  unsigned short* wt4h = (unsigned short*)alloc(128 * 128 * 2);
  unsigned short* wt4l = (unsigned short*)alloc(128 * 128 * 2);
  unsigned short* wsh  = (unsigned short*)alloc(128 * 128 * 2);
  unsigned short* wsl  = (unsigned short*)alloc(128 * 128 * 2);
  unsigned short* wt192h = (unsigned short*)alloc(192 * 128 * 2);
  unsigned short* wt192l = (unsigned short*)alloc(192 * 128 * 2);
  float* b192 = (float*)alloc(192 * 4);

  __hip_bfloat16* hg = (__hip_bfloat16*)hgreg;          // N*512 bf16
  __hip_bfloat16* hb = (__hip_bfloat16*)hb_f;           // N*128 bf16 (GEMM out)
  float* alpha = hb_f;                                  // ETOT*4 f32 (dead before hb)
  float* p1   = (float*)hgreg;                          // N*128 f32 (hg dead)
  float* h192 = (float*)hgreg + (size_t)NNODES * HID;   // N*192 f32, disjoint

  dim3 blk256(256);
  dim3 wgrid((NNODES + 3) / 4);
  dim3 mgrid((NNODES + 63) / 64);

  // 0) zero attention accumulators; pack weights (independent)
  hipMemsetAsync(a_s, 0, (size_t)NNODES * 4 * 4, stream);
  hipMemsetAsync(a_d, 0, (size_t)NNODES * 4 * 4, stream);
  pack_wt_kernel<<<(128 * 128 + 255) / 256, blk256, 0, stream>>>(w2, wt2h, wt2l, 128, 128);
  pack_wt_kernel<<<(128 * 128 + 255) / 256, blk256, 0, stream>>>(w3, wt3h, wt3l, 128, 128);
  pack_wt_kernel<<<(128 * 128 + 255) / 256, blk256, 0, stream>>>(w4, wt4h, wt4l, 128, 128);
  pack_wt_kernel<<<(128 * 128 + 255) / 256, blk256, 0, stream>>>(w_shared, wsh, wsl, 128, 128);
  pack_wt192_kernel<<<(192 * 128 + 255) / 256, blk256, 0, stream>>>(
      w_m1, w_i1, w_e1, b_m1, b_i1, b_e1, wt192h, wt192l, b192);

  // 1) fused GAT GEMM: hg(bf16) + a_s/a_d
  gemm_gat_kernel<<<dim3((NNODES + 63) / 64, 8), blk256, 0, stream>>>(
      x, w_gat, att_src, att_dst, hg, a_s, a_d);

  // 2) CSR build
  hipMemsetAsync(cnt, 0, NNODES * 4, stream);
  count_kernel<<<(ETOT + 255) / 256, blk256, 0, stream>>>(ei, cnt);
  scan_kernel<<<1, 1024, 0, stream>>>(cnt, rowptr);
  hipMemsetAsync(cnt, 0, NNODES * 4, stream);
  scatter_kernel<<<(ETOT + 255) / 256, blk256, 0, stream>>>(
      ei, ea, rowptr, cnt, csr_src, csr_ew);
  dinv_kernel<<<(NNODES + 255) / 256, blk256, 0, stream>>>(rowptr, csr_ew, dinv);

  // 3) per-edge alpha + normalized GCN weights
  alphaw_kernel<<<wgrid, blk256, 0, stream>>>(
      a_s, a_d, dinv, rowptr, csr_src, csr_ew, alpha);

  // 4) GAT gather + BN0 + ReLU -> p0 (f32)
  gat_gather_kernel<<<wgrid, blk256, 0, stream>>>(
      hg, alpha, rowptr, csr_src, b_gat,
      bn_g + 0, bn_b + 0, bn_m + 0, bn_v + 0, p0);

  // 5) GCN layer 2: hb(bf16) = p0 @ w2 ; gather -> p1
  gemm_mfma_kernel<8><<<mgrid, blk256, 0, stream>>>(p0, wt2h, wt2l, nullptr, hb, 0, 1);
  gcn_gather_kernel<<<wgrid, blk256, 0, stream>>>(
      hb, rowptr, csr_src, csr_ew, b2,
      bn_g + 128, bn_b + 128, bn_m + 128, bn_v + 128, p1);

  // 6) GCN layer 3
  gemm_mfma_kernel<8><<<mgrid, blk256, 0, stream>>>(p1, wt3h, wt3l, nullptr, hb, 0, 1);
  gcn_gather_kernel<<<wgrid, blk256, 0, stream>>>(
      hb, rowptr, csr_src, csr_ew, b3,
      bn_g + 256, bn_b + 256, bn_m + 256, bn_v + 256, p0);

  // 7) GCN layer 4
  gemm_mfma_kernel<8><<<mgrid, blk256, 0, stream>>>(p0, wt4h, wt4l, nullptr, hb, 0, 1);
  gcn_gather_kernel<<<wgrid, blk256, 0, stream>>>(
      hb, rowptr, csr_src, csr_ew, b4,
      bn_g + 384, bn_b + 384, bn_m + 384, bn_v + 384, p1);

  // 8) hs = relu(p1 @ w_shared + b_shared) -> p0 (f32)
  gemm_mfma_kernel<8><<<mgrid, blk256, 0, stream>>>(p1, wsh, wsl, b_shared, p0, 1, 0);

  // 9) h192 = relu(p0 @ wt192 + b192) (f32)
  gemm_mfma_kernel<12><<<mgrid, blk256, 0, stream>>>(p0, wt192h, wt192l, b192, h192, 1, 0);

  // 10) final heads -> d_out
  heads_final_kernel<<<wgrid, blk256, 0, stream>>>(
      h192, w_m2, b_m2, w_i2, b_i2, w_e2, b_e2, out);
}

// Round 8
// 610.642 us; speedup vs baseline: 1.4381x; 1.1449x over previous
//
#include <hip/hip_runtime.h>
#include <hip/hip_bf16.h>

#define NNODES 50000
#define NEDGES 400000
#define ETOT   (NEDGES + NNODES)
#define CIN    15
#define HID    128
#define HEADS  4
#define EPS_BN 1e-5f
#define NB_SCAN ((NNODES + 255) / 256)   // 196 blocks

typedef __attribute__((ext_vector_type(8))) short bf16x8_t;   // 8 bf16 = 4 VGPR
typedef __attribute__((ext_vector_type(4))) float f32x4_t;    // MFMA 16x16 acc

__device__ __forceinline__ float bfu(unsigned short u) {
  return __uint_as_float(((unsigned)u) << 16);
}
__device__ __forceinline__ unsigned short f2bf(float x) {
  union { __hip_bfloat16 b; unsigned short u; } c;
  c.b = __float2bfloat16(x);
  return c.u;
}
__device__ __forceinline__ float lrelu02(float x) {
  return x > 0.0f ? x : 0.2f * x;
}

// ---------------------------------------------------------------------------
// Split-bf16 MFMA GEMM:  C[M, NT*16] = act(A[M,128] @ W + bias)
// acc = Ah*Wh + Ah*Wl + Al*Wh (f32 accumulate) ~ f32 precision.
// ---------------------------------------------------------------------------
template <int NT>
__global__ __launch_bounds__(256) void gemm_mfma_kernel(
    const float* __restrict__ A, const unsigned short* __restrict__ WTh,
    const unsigned short* __restrict__ WTl, const float* __restrict__ bias,
    void* __restrict__ Cout, int act, int obf16) {
  constexpr int K = 128;
  constexpr int NC = NT * 16;
  __shared__ unsigned short Ah[64 * K];
  __shared__ unsigned short Al[64 * K];
  const int tid = threadIdx.x;
  const int bm = blockIdx.x * 64;

#pragma unroll
  for (int i = 0; i < 4; ++i) {
    int cch = tid + 256 * i;
    int r = cch >> 4, k0 = (cch & 15) << 3;
    int gr = bm + r;
    float v[8];
    if (gr < NNODES) {
      float4 v0 = *(const float4*)&A[(size_t)gr * K + k0];
      float4 v1 = *(const float4*)&A[(size_t)gr * K + k0 + 4];
      v[0] = v0.x; v[1] = v0.y; v[2] = v0.z; v[3] = v0.w;
      v[4] = v1.x; v[5] = v1.y; v[6] = v1.z; v[7] = v1.w;
    } else {
#pragma unroll
      for (int j = 0; j < 8; ++j) v[j] = 0.0f;
    }
    bf16x8_t hv, lv;
#pragma unroll
    for (int j = 0; j < 8; ++j) {
      unsigned short h = f2bf(v[j]);
      hv[j] = (short)h;
      lv[j] = (short)f2bf(v[j] - bfu(h));
    }
    int byte = (k0 << 1) ^ ((r & 7) << 4);
    *(bf16x8_t*)((char*)(Ah + r * K) + byte) = hv;
    *(bf16x8_t*)((char*)(Al + r * K) + byte) = lv;
  }
  __syncthreads();

  const int wv = tid >> 6, l = tid & 63;
  const int lrow = (wv << 4) + (l & 15);
  const int kg = (l >> 4) << 3;
  const int lcol = l & 15;

  f32x4_t acc[NT];
#pragma unroll
  for (int j = 0; j < NT; ++j) acc[j] = (f32x4_t){0.f, 0.f, 0.f, 0.f};

#pragma unroll
  for (int kc = 0; kc < 4; ++kc) {
    int k = kc * 32 + kg;
    int byte = (k << 1) ^ ((lrow & 7) << 4);
    bf16x8_t ah = *(const bf16x8_t*)((const char*)(Ah + lrow * K) + byte);
    bf16x8_t al = *(const bf16x8_t*)((const char*)(Al + lrow * K) + byte);
#pragma unroll
    for (int j = 0; j < NT; ++j) {
      size_t boff = (size_t)(j * 16 + lcol) * K + k;
      bf16x8_t bh = *(const bf16x8_t*)(WTh + boff);
      bf16x8_t bl = *(const bf16x8_t*)(WTl + boff);
      acc[j] = __builtin_amdgcn_mfma_f32_16x16x32_bf16(ah, bh, acc[j], 0, 0, 0);
      acc[j] = __builtin_amdgcn_mfma_f32_16x16x32_bf16(ah, bl, acc[j], 0, 0, 0);
      acc[j] = __builtin_amdgcn_mfma_f32_16x16x32_bf16(al, bh, acc[j], 0, 0, 0);
    }
  }

  const int orow0 = bm + (wv << 4) + ((l >> 4) << 2);
#pragma unroll
  for (int j = 0; j < NT; ++j) {
    int col = j * 16 + lcol;
    float bs = bias ? bias[col] : 0.0f;
#pragma unroll
    for (int r = 0; r < 4; ++r) {
      int row = orow0 + r;
      if (row >= NNODES) continue;
      float vv = acc[j][r] + bs;
      if (act) vv = fmaxf(vv, 0.0f);
      if (obf16)
        ((unsigned short*)Cout)[(size_t)row * NC + col] = f2bf(vv);
      else
        ((float*)Cout)[(size_t)row * NC + col] = vv;
    }
  }
}

// ---------------------------------------------------------------------------
// Fused pack of the four 128x128 weights -> [N][K] bf16 hi/lo (transposed)
// ---------------------------------------------------------------------------
__global__ void pack_wt4_kernel(
    const float* __restrict__ w2, const float* __restrict__ w3,
    const float* __restrict__ w4, const float* __restrict__ ws,
    unsigned short* __restrict__ Hbase, unsigned short* __restrict__ Lbase) {
  int i = blockIdx.x * blockDim.x + threadIdx.x;
  if (i >= 128 * 128) return;
  const float* W = (blockIdx.y == 0) ? w2 : (blockIdx.y == 1) ? w3
                 : (blockIdx.y == 2) ? w4 : ws;
  unsigned short* Wh = Hbase + (size_t)blockIdx.y * 128 * 128;
  unsigned short* Wl = Lbase + (size_t)blockIdx.y * 128 * 128;
  int k = i >> 7, n = i & 127;
  float x = W[i];
  unsigned short h = f2bf(x);
  Wh[n * 128 + k] = h;
  Wl[n * 128 + k] = f2bf(x - bfu(h));
}

// Pack the three 128x64 head weights into WT192 [192][128] hi/lo + b192
__global__ void pack_wt192_kernel(
    const float* __restrict__ w_m1, const float* __restrict__ w_i1,
    const float* __restrict__ w_e1, const float* __restrict__ b_m1,
    const float* __restrict__ b_i1, const float* __restrict__ b_e1,
    unsigned short* __restrict__ WTh, unsigned short* __restrict__ WTl,
    float* __restrict__ b192) {
  int i = blockIdx.x * blockDim.x + threadIdx.x;
  if (i < 192 * 128) {
    int n = i >> 7, k = i & 127;
    float x = (n < 64) ? w_m1[k * 64 + n]
            : (n < 128) ? w_i1[k * 64 + (n - 64)]
                        : w_e1[k * 64 + (n - 128)];
    unsigned short h = f2bf(x);
    WTh[(size_t)n * 128 + k] = h;
    WTl[(size_t)n * 128 + k] = f2bf(x - bfu(h));
  }
  if (i < 192) {
    b192[i] = (i < 64) ? b_m1[i] : (i < 128) ? b_i1[i - 64] : b_e1[i - 128];
  }
}

// ---------------------------------------------------------------------------
// Fused GAT input GEMM (atomic-free): blockIdx.y = head; block = 64 rows x
// 128 cols (one full head). Epilogue reduces a_s/a_d within block -> store.
// ---------------------------------------------------------------------------
__global__ __launch_bounds__(256) void gemm_gat_kernel(
    const float* __restrict__ x, const float* __restrict__ w,
    const float* __restrict__ att_s, const float* __restrict__ att_d,
    __hip_bfloat16* __restrict__ hg, float* __restrict__ a_s,
    float* __restrict__ a_d) {
  __shared__ __align__(16) float As[64 * 20];   // [row][k]
  __shared__ __align__(16) float Bs[128 * 20];  // [col][k]
  const int bm = blockIdx.x * 64;
  const int head = blockIdx.y;
  const int tid = threadIdx.x;
  const int tr = tid >> 4;   // 0..15 -> 4 rows each
  const int tc = tid & 15;   // 0..15 -> 8 cols each

  for (int l = tid; l < 64 * 16; l += 256) {
    int r = l >> 4, k = l & 15;
    int gr = bm + r;
    As[r * 20 + k] = (k < CIN && gr < NNODES) ? x[(size_t)gr * CIN + k] : 0.0f;
  }
  for (int l = tid; l < 128 * 16; l += 256) {
    int k = l >> 7, c = l & 127;
    Bs[c * 20 + k] = (k < CIN) ? w[(size_t)k * 512 + head * 128 + c] : 0.0f;
  }
  __syncthreads();

  float acc[4][8] = {};
  for (int k = 0; k < 16; k += 4) {
    float4 a[4], b[8];
#pragma unroll
    for (int i = 0; i < 4; ++i) a[i] = *(const float4*)&As[(tr + 16 * i) * 20 + k];
#pragma unroll
    for (int j = 0; j < 8; ++j) b[j] = *(const float4*)&Bs[(tc + 16 * j) * 20 + k];
#pragma unroll
    for (int i = 0; i < 4; ++i)
#pragma unroll
      for (int j = 0; j < 8; ++j)
        acc[i][j] += a[i].x * b[j].x + a[i].y * b[j].y +
                     a[i].z * b[j].z + a[i].w * b[j].w;
  }

  float asc[8], adc[8];
#pragma unroll
  for (int j = 0; j < 8; ++j) {
    int cih = tc + 16 * j;
    asc[j] = att_s[head * HID + cih];
    adc[j] = att_d[head * HID + cih];
  }

#pragma unroll
  for (int i = 0; i < 4; ++i) {
    int r = bm + tr + 16 * i;
    float ps = 0.f, pd = 0.f;
    if (r < NNODES) {
#pragma unroll
      for (int j = 0; j < 8; ++j) {
        float v = acc[i][j];
        hg[(size_t)r * 512 + head * 128 + tc + 16 * j] = __float2bfloat16(v);
        ps += v * asc[j];
        pd += v * adc[j];
      }
    }
#pragma unroll
    for (int off = 1; off < 16; off <<= 1) {
      ps += __shfl_xor(ps, off);
      pd += __shfl_xor(pd, off);
    }
    if (tc == 0 && r < NNODES) {
      a_s[r * 4 + head] = ps;
      a_d[r * 4 + head] = pd;
    }
  }
}

// ---------------------------------------------------------------------------
// CSR build (by dst): count -> hierarchical scan -> scatter
// ---------------------------------------------------------------------------
__global__ void count_kernel(const int* __restrict__ ei, int* __restrict__ cnt) {
  int i = blockIdx.x * blockDim.x + threadIdx.x;
  if (i >= ETOT) return;
  int d = (i < NEDGES) ? ei[NEDGES + i] : (i - NEDGES);
  atomicAdd(&cnt[d], 1);
}

__global__ __launch_bounds__(256) void csr_reduce_kernel(
    const int* __restrict__ cnt, int* __restrict__ bsum) {
  __shared__ int red[256];
  int t = threadIdx.x;
  int i = blockIdx.x * 256 + t;
  red[t] = (i < NNODES) ? cnt[i] : 0;
  __syncthreads();
  for (int off = 128; off > 0; off >>= 1) {
    if (t < off) red[t] += red[t + off];
    __syncthreads();
  }
  if (t == 0) bsum[blockIdx.x] = red[0];
}

__global__ __launch_bounds__(256) void csr_scanb_kernel(
    const int* __restrict__ bsum, int* __restrict__ boff) {
  __shared__ int s[256];
  int t = threadIdx.x;
  s[t] = (t < NB_SCAN) ? bsum[t] : 0;
  __syncthreads();
  for (int off = 1; off < 256; off <<= 1) {
    int u = (t >= off) ? s[t - off] : 0;
    __syncthreads();
    s[t] += u;
    __syncthreads();
  }
  if (t < NB_SCAN) boff[t] = (t == 0) ? 0 : s[t - 1];
}

__global__ __launch_bounds__(256) void csr_scan_kernel(
    int* __restrict__ cnt, const int* __restrict__ boff,
    int* __restrict__ rowptr) {
  __shared__ int s[256];
  int t = threadIdx.x;
  int i = blockIdx.x * 256 + t;
  int v = (i < NNODES) ? cnt[i] : 0;
  s[t] = v;
  __syncthreads();
  for (int off = 1; off < 256; off <<= 1) {
    int u = (t >= off) ? s[t - off] : 0;
    __syncthreads();
    s[t] += u;
    __syncthreads();
  }
  if (i < NNODES) {
    rowptr[i] = boff[blockIdx.x] + s[t] - v;  // exclusive
    cnt[i] = 0;                               // reset -> scatter cursor
  }
  if (i == 0) rowptr[NNODES] = ETOT;
}

__global__ void scatter_kernel(const int* __restrict__ ei,
                               const float* __restrict__ ea,
                               const int* __restrict__ rowptr,
                               int* __restrict__ cursor,
                               int* __restrict__ csr_src,
                               float* __restrict__ csr_ew) {
  int i = blockIdx.x * blockDim.x + threadIdx.x;
  if (i >= ETOT) return;
  int s, d; float w;
  if (i < NEDGES) { s = ei[i]; d = ei[NEDGES + i]; w = ea[i]; }
  else            { s = d = i - NEDGES; w = 1.0f; }
  int pos = rowptr[d] + atomicAdd(&cursor[d], 1);
  csr_src[pos] = s;
  csr_ew[pos] = w;
}

__global__ void dinv_kernel(const int* __restrict__ rowptr,
                            const float* __restrict__ csr_ew,
                            float* __restrict__ dinv) {
  int n = blockIdx.x * blockDim.x + threadIdx.x;
  if (n >= NNODES) return;
  float s = 0.0f;
  int e0 = rowptr[n], e1 = rowptr[n + 1];
  for (int e = e0; e < e1; ++e) s += csr_ew[e];
  dinv[n] = (s > 0.0f) ? rsqrtf(fmaxf(s, 1e-12f)) : 0.0f;
}

// ---------------------------------------------------------------------------
// Per-node (wave) kernel: normalized GAT alpha[e][4]; in-place GCN edge norm.
// ---------------------------------------------------------------------------
__global__ __launch_bounds__(256) void alphaw_kernel(
    const float* __restrict__ a_s, const float* __restrict__ a_d,
    const float* __restrict__ dinv, const int* __restrict__ rowptr,
    const int* __restrict__ csr_src, float* __restrict__ csr_ew,
    float* __restrict__ alpha) {
  int wid = threadIdx.x >> 6, lane = threadIdx.x & 63;
  int n = blockIdx.x * 4 + wid;
  if (n >= NNODES) return;
  int e0 = rowptr[n], e1 = rowptr[n + 1];
  float4 ad = *(const float4*)&a_d[n * 4];
  float di = dinv[n];

  float m0 = -1e30f, m1 = -1e30f, m2 = -1e30f, m3 = -1e30f;
  for (int e = e0 + lane; e < e1; e += 64) {
    int s = csr_src[e];
    float4 as4 = *(const float4*)&a_s[s * 4];
    m0 = fmaxf(m0, lrelu02(as4.x + ad.x));
    m1 = fmaxf(m1, lrelu02(as4.y + ad.y));
    m2 = fmaxf(m2, lrelu02(as4.z + ad.z));
    m3 = fmaxf(m3, lrelu02(as4.w + ad.w));
  }
#pragma unroll
  for (int off = 32; off > 0; off >>= 1) {
    m0 = fmaxf(m0, __shfl_xor(m0, off));
    m1 = fmaxf(m1, __shfl_xor(m1, off));
    m2 = fmaxf(m2, __shfl_xor(m2, off));
    m3 = fmaxf(m3, __shfl_xor(m3, off));
  }

  float s0 = 0.f, s1 = 0.f, s2 = 0.f, s3 = 0.f;
  for (int e = e0 + lane; e < e1; e += 64) {
    int s = csr_src[e];
    float4 as4 = *(const float4*)&a_s[s * 4];
    float x0 = __expf(lrelu02(as4.x + ad.x) - m0);
    float x1 = __expf(lrelu02(as4.y + ad.y) - m1);
    float x2 = __expf(lrelu02(as4.z + ad.z) - m2);
    float x3 = __expf(lrelu02(as4.w + ad.w) - m3);
    s0 += x0; s1 += x1; s2 += x2; s3 += x3;
    float4 o; o.x = x0; o.y = x1; o.z = x2; o.w = x3;
    *(float4*)&alpha[(size_t)e * 4] = o;
    csr_ew[e] = dinv[s] * csr_ew[e] * di;
  }
#pragma unroll
  for (int off = 32; off > 0; off >>= 1) {
    s0 += __shfl_xor(s0, off);
    s1 += __shfl_xor(s1, off);
    s2 += __shfl_xor(s2, off);
    s3 += __shfl_xor(s3, off);
  }
  float r0 = 1.0f / (s0 + 1e-16f), r1 = 1.0f / (s1 + 1e-16f);
  float r2 = 1.0f / (s2 + 1e-16f), r3 = 1.0f / (s3 + 1e-16f);
  for (int e = e0 + lane; e < e1; e += 64) {
    float4 a = *(const float4*)&alpha[(size_t)e * 4];
    a.x *= r0; a.y *= r1; a.z *= r2; a.w *= r3;
    *(float4*)&alpha[(size_t)e * 4] = a;
  }
}

// ---------------------------------------------------------------------------
// GAT gather (pure fma): wave per node; bf16 hg; BN0+ReLU fused.
// ---------------------------------------------------------------------------
__global__ __launch_bounds__(256) void gat_gather_kernel(
    const __hip_bfloat16* __restrict__ hg, const float* __restrict__ alpha,
    const int* __restrict__ rowptr, const int* __restrict__ csr_src,
    const float* __restrict__ b_gat,
    const float* __restrict__ bg, const float* __restrict__ bb,
    const float* __restrict__ bm, const float* __restrict__ bv,
    float* __restrict__ out) {
  int wid = threadIdx.x >> 6, lane = threadIdx.x & 63;
  int n = blockIdx.x * 4 + wid;
  if (n >= NNODES) return;
  int e0 = rowptr[n], e1 = rowptr[n + 1];
  int c = 2 * lane;
  float a0x = 0.f, a0y = 0.f, a1x = 0.f, a1y = 0.f;
  float a2x = 0.f, a2y = 0.f, a3x = 0.f, a3y = 0.f;
  for (int e = e0; e < e1; ++e) {
    int s = csr_src[e];
    float4 al = *(const float4*)&alpha[(size_t)e * 4];
    const __hip_bfloat16* hrow = hg + (size_t)s * 512;
    ushort2 u0 = *(const ushort2*)(hrow + c);
    ushort2 u1 = *(const ushort2*)(hrow + 128 + c);
    ushort2 u2 = *(const ushort2*)(hrow + 256 + c);
    ushort2 u3 = *(const ushort2*)(hrow + 384 + c);
    a0x += al.x * bfu(u0.x); a0y += al.x * bfu(u0.y);
    a1x += al.y * bfu(u1.x); a1y += al.y * bfu(u1.y);
    a2x += al.z * bfu(u2.x); a2y += al.z * bfu(u2.y);
    a3x += al.w * bfu(u3.x); a3y += al.w * bfu(u3.y);
  }
  float ox = 0.25f * (a0x + a1x + a2x + a3x) + b_gat[c];
  float oy = 0.25f * (a0y + a1y + a2y + a3y) + b_gat[c + 1];
  ox = bg[c] * (ox - bm[c]) * rsqrtf(bv[c] + EPS_BN) + bb[c];
  oy = bg[c + 1] * (oy - bm[c + 1]) * rsqrtf(bv[c + 1] + EPS_BN) + bb[c + 1];
  ox = fmaxf(ox, 0.0f); oy = fmaxf(oy, 0.0f);
  float2 o; o.x = ox; o.y = oy;
  *(float2*)&out[(size_t)n * HID + c] = o;
}

// ---------------------------------------------------------------------------
// GCN gather: wave per node; h is bf16, csr_w prenormalized; BN+ReLU fused.
// ---------------------------------------------------------------------------
__global__ __launch_bounds__(256) void gcn_gather_kernel(
    const __hip_bfloat16* __restrict__ h, const int* __restrict__ rowptr,
    const int* __restrict__ csr_src, const float* __restrict__ csr_w,
    const float* __restrict__ bias,
    const float* __restrict__ bg, const float* __restrict__ bb,
    const float* __restrict__ bm, const float* __restrict__ bv,
    float* __restrict__ out) {
  int wid = threadIdx.x >> 6, lane = threadIdx.x & 63;
  int n = blockIdx.x * 4 + wid;
  if (n >= NNODES) return;
  int e0 = rowptr[n], e1 = rowptr[n + 1];
  int c = 2 * lane;
  float ax = 0.f, ay = 0.f;
  for (int e = e0; e < e1; ++e) {
    int s = csr_src[e];
    float w = csr_w[e];
    ushort2 u = *(const ushort2*)(h + (size_t)s * HID + c);
    ax += w * bfu(u.x);
    ay += w * bfu(u.y);
  }
  float ox = ax + bias[c];
  float oy = ay + bias[c + 1];
  ox = bg[c] * (ox - bm[c]) * rsqrtf(bv[c] + EPS_BN) + bb[c];
  oy = bg[c + 1] * (oy - bm[c + 1]) * rsqrtf(bv[c + 1] + EPS_BN) + bb[c + 1];
  ox = fmaxf(ox, 0.0f); oy = fmaxf(oy, 0.0f);
  float2 o; o.x = ox; o.y = oy;
  *(float2*)&out[(size_t)n * HID + c] = o;
}

// ---------------------------------------------------------------------------
// Final heads: from h192[N,192] (hm|hi|he) compute 5 outputs per node.
// ---------------------------------------------------------------------------
__global__ __launch_bounds__(256) void heads_final_kernel(
    const float* __restrict__ h192, const float* __restrict__ w_m2,
    const float* __restrict__ b_m2, const float* __restrict__ w_i2,
    const float* __restrict__ b_i2, const float* __restrict__ w_e2,
    const float* __restrict__ b_e2, float* __restrict__ out) {
  int wid = threadIdx.x >> 6;
  int lane = threadIdx.x & 63;
  int n = blockIdx.x * 4 + wid;
  if (n >= NNODES) return;
  const float* row = h192 + (size_t)n * 192;
  float hm = row[lane], hi = row[64 + lane], he = row[128 + lane];
  float p0 = hm * w_m2[lane * 2 + 0];
  float p1 = hm * w_m2[lane * 2 + 1];
  float p2 = hi * w_i2[lane * 2 + 0];
  float p3 = hi * w_i2[lane * 2 + 1];
  float p4 = he * w_e2[lane];
#pragma unroll
  for (int off = 32; off > 0; off >>= 1) {
    p0 += __shfl_down(p0, off);
    p1 += __shfl_down(p1, off);
    p2 += __shfl_down(p2, off);
    p3 += __shfl_down(p3, off);
    p4 += __shfl_down(p4, off);
  }
  if (lane == 0) {
    out[n * 2 + 0] = p0 + b_m2[0];
    out[n * 2 + 1] = p1 + b_m2[1];
    out[2 * NNODES + n * 2 + 0] = p2 + b_i2[0];
    out[2 * NNODES + n * 2 + 1] = p3 + b_i2[1];
    out[4 * NNODES + n] = p4 + b_e2[0];
  }
}

// ---------------------------------------------------------------------------
extern "C" void kernel_launch(void* const* d_in, const int* in_sizes, int n_in,
                              void* d_out, int out_size, void* d_ws, size_t ws_size,
                              hipStream_t stream) {
  const float* x       = (const float*)d_in[0];
  const int*   ei      = (const int*)d_in[1];
  const float* ea      = (const float*)d_in[2];
  const float* w_gat   = (const float*)d_in[3];
  const float* att_src = (const float*)d_in[4];
  const float* att_dst = (const float*)d_in[5];
  const float* b_gat   = (const float*)d_in[6];
  const float* w2 = (const float*)d_in[7];  const float* b2 = (const float*)d_in[8];
  const float* w3 = (const float*)d_in[9];  const float* b3 = (const float*)d_in[10];
  const float* w4 = (const float*)d_in[11]; const float* b4 = (const float*)d_in[12];
  const float* bn_g = (const float*)d_in[13];
  const float* bn_b = (const float*)d_in[14];
  const float* bn_m = (const float*)d_in[15];
  const float* bn_v = (const float*)d_in[16];
  const float* w_shared = (const float*)d_in[17]; const float* b_shared = (const float*)d_in[18];
  const float* w_m1 = (const float*)d_in[19]; const float* b_m1 = (const float*)d_in[20];
  const float* w_m2 = (const float*)d_in[21]; const float* b_m2 = (const float*)d_in[22];
  const float* w_i1 = (const float*)d_in[23]; const float* b_i1 = (const float*)d_in[24];
  const float* w_i2 = (const float*)d_in[25]; const float* b_i2 = (const float*)d_in[26];
  const float* w_e1 = (const float*)d_in[27]; const float* b_e1 = (const float*)d_in[28];
  const float* w_e2 = (const float*)d_in[29]; const float* b_e2 = (const float*)d_in[30];
  float* out = (float*)d_out;

  // ---- workspace layout ----
  size_t off = 0;
  auto alloc = [&](size_t bytes) -> char* {
    char* p = (char*)d_ws + off;
    off += (bytes + 255) & ~(size_t)255;
    return p;
  };
  char*  hgreg   = alloc((size_t)NNODES * 512 * 4);   // bf16 hg; later aliased f32
  float* p0      = (float*)alloc((size_t)NNODES * HID * 4);
  float* hb_f    = (float*)alloc((size_t)NNODES * HID * 4);  // bf16 hb / f32 alpha alias
  float* a_s     = (float*)alloc((size_t)NNODES * 4 * 4);
  float* a_d     = (float*)alloc((size_t)NNODES * 4 * 4);
  float* dinv    = (float*)alloc((size_t)NNODES * 4);
  float* csr_ew  = (float*)alloc((size_t)ETOT * 4);
  int*   rowptr  = (int*)alloc((size_t)(NNODES + 1) * 4);
  int*   cnt     = (int*)alloc((size_t)NNODES * 4);
  int*   csr_src = (int*)alloc((size_t)ETOT * 4);
  int*   bsum    = (int*)alloc((size_t)NB_SCAN * 4);
  int*   boff    = (int*)alloc((size_t)NB_SCAN * 4);
  // split-bf16 transposed weights: 4x 128x128 contiguous + 192x128
  unsigned short* wtH = (unsigned short*)alloc(4 * 128 * 128 * 2);
  unsigned short* wtL = (unsigned short*)alloc(4 * 128 * 128 * 2);
  unsigned short* wt192h = (unsigned short*)alloc(192 * 128 * 2);
  unsigned short* wt192l = (unsigned short*)alloc(192 * 128 * 2);
  float* b192 = (float*)alloc(192 * 4);

  unsigned short* wt2h = wtH + 0 * 16384; unsigned short* wt2l = wtL + 0 * 16384;
  unsigned short* wt3h = wtH + 1 * 16384; unsigned short* wt3l = wtL + 1 * 16384;
  unsigned short* wt4h = wtH + 2 * 16384; unsigned short* wt4l = wtL + 2 * 16384;
  unsigned short* wsh  = wtH + 3 * 16384; unsigned short* wsl  = wtL + 3 * 16384;

  __hip_bfloat16* hg = (__hip_bfloat16*)hgreg;          // N*512 bf16
  __hip_bfloat16* hb = (__hip_bfloat16*)hb_f;           // N*128 bf16 (GEMM out)
  float* alpha = hb_f;                                  // ETOT*4 f32 (dead before hb)
  float* p1   = (float*)hgreg;                          // N*128 f32 (hg dead)
  float* h192 = (float*)hgreg + (size_t)NNODES * HID;   // N*192 f32, disjoint

  dim3 blk256(256);
  dim3 wgrid((NNODES + 3) / 4);
  dim3 mgrid((NNODES + 63) / 64);

  // 1) CSR build: count -> hierarchical scan (also zeroes cnt) -> scatter
  hipMemsetAsync(cnt, 0, NNODES * 4, stream);
  count_kernel<<<(ETOT + 255) / 256, blk256, 0, stream>>>(ei, cnt);
  csr_reduce_kernel<<<NB_SCAN, blk256, 0, stream>>>(cnt, bsum);
  csr_scanb_kernel<<<1, blk256, 0, stream>>>(bsum, boff);
  csr_scan_kernel<<<NB_SCAN, blk256, 0, stream>>>(cnt, boff, rowptr);
  scatter_kernel<<<(ETOT + 255) / 256, blk256, 0, stream>>>(
      ei, ea, rowptr, cnt, csr_src, csr_ew);
  dinv_kernel<<<(NNODES + 255) / 256, blk256, 0, stream>>>(rowptr, csr_ew, dinv);

  // 2) weight packs (independent)
  pack_wt4_kernel<<<dim3((128 * 128 + 255) / 256, 4), blk256, 0, stream>>>(
      w2, w3, w4, w_shared, wtH, wtL);
  pack_wt192_kernel<<<(192 * 128 + 255) / 256, blk256, 0, stream>>>(
      w_m1, w_i1, w_e1, b_m1, b_i1, b_e1, wt192h, wt192l, b192);

  // 3) fused GAT GEMM: hg(bf16) + a_s/a_d (atomic-free)
  gemm_gat_kernel<<<dim3((NNODES + 63) / 64, 4), blk256, 0, stream>>>(
      x, w_gat, att_src, att_dst, hg, a_s, a_d);

  // 4) per-edge alpha + normalized GCN weights
  alphaw_kernel<<<wgrid, blk256, 0, stream>>>(
      a_s, a_d, dinv, rowptr, csr_src, csr_ew, alpha);

  // 5) GAT gather + BN0 + ReLU -> p0 (f32)
  gat_gather_kernel<<<wgrid, blk256, 0, stream>>>(
      hg, alpha, rowptr, csr_src, b_gat,
      bn_g + 0, bn_b + 0, bn_m + 0, bn_v + 0, p0);

  // 6) GCN layer 2: hb(bf16) = p0 @ w2 ; gather -> p1
  gemm_mfma_kernel<8><<<mgrid, blk256, 0, stream>>>(p0, wt2h, wt2l, nullptr, hb, 0, 1);
  gcn_gather_kernel<<<wgrid, blk256, 0, stream>>>(
      hb, rowptr, csr_src, csr_ew, b2,
      bn_g + 128, bn_b + 128, bn_m + 128, bn_v + 128, p1);

  // 7) GCN layer 3
  gemm_mfma_kernel<8><<<mgrid, blk256, 0, stream>>>(p1, wt3h, wt3l, nullptr, hb, 0, 1);
  gcn_gather_kernel<<<wgrid, blk256, 0, stream>>>(
      hb, rowptr, csr_src, csr_ew, b3,
      bn_g + 256, bn_b + 256, bn_m + 256, bn_v + 256, p0);

  // 8) GCN layer 4
  gemm_mfma_kernel<8><<<mgrid, blk256, 0, stream>>>(p0, wt4h, wt4l, nullptr, hb, 0, 1);
  gcn_gather_kernel<<<wgrid, blk256, 0, stream>>>(
      hb, rowptr, csr_src, csr_ew, b4,
      bn_g + 384, bn_b + 384, bn_m + 384, bn_v + 384, p1);

  // 9) hs = relu(p1 @ w_shared + b_shared) -> p0 (f32)
  gemm_mfma_kernel<8><<<mgrid, blk256, 0, stream>>>(p1, wsh, wsl, b_shared, p0, 1, 0);

  // 10) h192 = relu(p0 @ wt192 + b192) (f32)
  gemm_mfma_kernel<12><<<mgrid, blk256, 0, stream>>>(p0, wt192h, wt192l, b192, h192, 1, 0);

  // 11) final heads -> d_out
  heads_final_kernel<<<wgrid, blk256, 0, stream>>>(
      h192, w_m2, b_m2, w_i2, b_i2, w_e2, b_e2, out);
}

// Round 9
// 514.431 us; speedup vs baseline: 1.7070x; 1.1870x over previous
//
#include <hip/hip_runtime.h>
#include <hip/hip_bf16.h>

#define NNODES 50000
#define NEDGES 400000
#define ETOT   (NEDGES + NNODES)
#define CIN    15
#define HID    128
#define HEADS  4
#define EPS_BN 1e-5f
#define NB_SCAN ((NNODES + 255) / 256)   // 196 blocks

typedef __attribute__((ext_vector_type(8))) short bf16x8_t;   // 8 bf16 = 4 VGPR
typedef __attribute__((ext_vector_type(4))) float f32x4_t;    // MFMA 16x16 acc

__device__ __forceinline__ float bfu(unsigned short u) {
  return __uint_as_float(((unsigned)u) << 16);
}
__device__ __forceinline__ unsigned short f2bf(float x) {
  union { __hip_bfloat16 b; unsigned short u; } c;
  c.b = __float2bfloat16(x);
  return c.u;
}
__device__ __forceinline__ float lrelu02(float x) {
  return x > 0.0f ? x : 0.2f * x;
}

// ---------------------------------------------------------------------------
// Split-bf16 MFMA GEMM:  C[M, WPT*64] = act(A[M,128] @ W + bias)
// Wave w owns ALL 64 rows x cols [w*WPT*16, (w+1)*WPT*16). B fragments are
// loaded ONCE into registers before the K-loop (WPT*4*2 frags); the inner
// loop is pure LDS ds_read_b128 + MFMA -> no global loads on the chain.
// acc = Ah*Wh + Ah*Wl + Al*Wh (f32 accumulate) ~ f32 precision.
// ---------------------------------------------------------------------------
template <int WPT>
__global__ __launch_bounds__(256) void gemm_mfma_kernel(
    const float* __restrict__ A, const unsigned short* __restrict__ WTh,
    const unsigned short* __restrict__ WTl, const float* __restrict__ bias,
    void* __restrict__ Cout, int act, int obf16) {
  constexpr int K = 128;
  constexpr int NC = WPT * 64;
  __shared__ unsigned short Ah[64 * K];
  __shared__ unsigned short Al[64 * K];
  const int tid = threadIdx.x;
  const int bm = blockIdx.x * 64;
  const int wv = tid >> 6, l = tid & 63;
  const int lcol = l & 15;
  const int kg = (l >> 4) << 3;
  const int colbase = wv * (WPT * 16);

  // preload ALL B fragments for this wave's column strip (L2-resident, reused
  // by every block) -- issued first so latency overlaps the A staging below
  bf16x8_t bh[WPT][4], bl[WPT][4];
#pragma unroll
  for (int jj = 0; jj < WPT; ++jj)
#pragma unroll
    for (int kc = 0; kc < 4; ++kc) {
      size_t boff = (size_t)(colbase + jj * 16 + lcol) * K + kc * 32 + kg;
      bh[jj][kc] = *(const bf16x8_t*)(WTh + boff);
      bl[jj][kc] = *(const bf16x8_t*)(WTl + boff);
    }

  // stage A tile (64 x 128 f32) -> hi/lo bf16 in LDS, XOR-swizzled
#pragma unroll
  for (int i = 0; i < 4; ++i) {
    int cch = tid + 256 * i;
    int r = cch >> 4, k0 = (cch & 15) << 3;
    int gr = bm + r;
    float v[8];
    if (gr < NNODES) {
      float4 v0 = *(const float4*)&A[(size_t)gr * K + k0];
      float4 v1 = *(const float4*)&A[(size_t)gr * K + k0 + 4];
      v[0] = v0.x; v[1] = v0.y; v[2] = v0.z; v[3] = v0.w;
      v[4] = v1.x; v[5] = v1.y; v[6] = v1.z; v[7] = v1.w;
    } else {
#pragma unroll
      for (int j = 0; j < 8; ++j) v[j] = 0.0f;
    }
    bf16x8_t hv, lv;
#pragma unroll
    for (int j = 0; j < 8; ++j) {
      unsigned short h = f2bf(v[j]);
      hv[j] = (short)h;
      lv[j] = (short)f2bf(v[j] - bfu(h));
    }
    int byte = (k0 << 1) ^ ((r & 7) << 4);
    *(bf16x8_t*)((char*)(Ah + r * K) + byte) = hv;
    *(bf16x8_t*)((char*)(Al + r * K) + byte) = lv;
  }
  __syncthreads();

  f32x4_t acc[4][WPT];
#pragma unroll
  for (int rt = 0; rt < 4; ++rt)
#pragma unroll
    for (int jj = 0; jj < WPT; ++jj) acc[rt][jj] = (f32x4_t){0.f, 0.f, 0.f, 0.f};

#pragma unroll
  for (int kc = 0; kc < 4; ++kc) {
    int k = kc * 32 + kg;
#pragma unroll
    for (int rt = 0; rt < 4; ++rt) {
      int lrow = rt * 16 + (l & 15);
      int byte = (k << 1) ^ ((lrow & 7) << 4);
      bf16x8_t ah = *(const bf16x8_t*)((const char*)(Ah + lrow * K) + byte);
      bf16x8_t al = *(const bf16x8_t*)((const char*)(Al + lrow * K) + byte);
#pragma unroll
      for (int jj = 0; jj < WPT; ++jj) {
        acc[rt][jj] = __builtin_amdgcn_mfma_f32_16x16x32_bf16(ah, bh[jj][kc], acc[rt][jj], 0, 0, 0);
        acc[rt][jj] = __builtin_amdgcn_mfma_f32_16x16x32_bf16(ah, bl[jj][kc], acc[rt][jj], 0, 0, 0);
        acc[rt][jj] = __builtin_amdgcn_mfma_f32_16x16x32_bf16(al, bh[jj][kc], acc[rt][jj], 0, 0, 0);
      }
    }
  }

  // C/D layout (m89-verified): col = lane&15, row = (lane>>4)*4 + reg
#pragma unroll
  for (int rt = 0; rt < 4; ++rt) {
    int orow0 = bm + rt * 16 + ((l >> 4) << 2);
#pragma unroll
    for (int jj = 0; jj < WPT; ++jj) {
      int col = colbase + jj * 16 + lcol;
      float bs = bias ? bias[col] : 0.0f;
#pragma unroll
      for (int r = 0; r < 4; ++r) {
        int row = orow0 + r;
        if (row >= NNODES) continue;
        float vv = acc[rt][jj][r] + bs;
        if (act) vv = fmaxf(vv, 0.0f);
        if (obf16)
          ((unsigned short*)Cout)[(size_t)row * NC + col] = f2bf(vv);
        else
          ((float*)Cout)[(size_t)row * NC + col] = vv;
      }
    }
  }
}

// ---------------------------------------------------------------------------
// Fused pack of the four 128x128 weights -> [N][K] bf16 hi/lo (transposed)
// ---------------------------------------------------------------------------
__global__ void pack_wt4_kernel(
    const float* __restrict__ w2, const float* __restrict__ w3,
    const float* __restrict__ w4, const float* __restrict__ ws,
    unsigned short* __restrict__ Hbase, unsigned short* __restrict__ Lbase) {
  int i = blockIdx.x * blockDim.x + threadIdx.x;
  if (i >= 128 * 128) return;
  const float* W = (blockIdx.y == 0) ? w2 : (blockIdx.y == 1) ? w3
                 : (blockIdx.y == 2) ? w4 : ws;
  unsigned short* Wh = Hbase + (size_t)blockIdx.y * 128 * 128;
  unsigned short* Wl = Lbase + (size_t)blockIdx.y * 128 * 128;
  int k = i >> 7, n = i & 127;
  float x = W[i];
  unsigned short h = f2bf(x);
  Wh[n * 128 + k] = h;
  Wl[n * 128 + k] = f2bf(x - bfu(h));
}

// Pack the three 128x64 head weights into WT192 [192][128] hi/lo + b192
__global__ void pack_wt192_kernel(
    const float* __restrict__ w_m1, const float* __restrict__ w_i1,
    const float* __restrict__ w_e1, const float* __restrict__ b_m1,
    const float* __restrict__ b_i1, const float* __restrict__ b_e1,
    unsigned short* __restrict__ WTh, unsigned short* __restrict__ WTl,
    float* __restrict__ b192) {
  int i = blockIdx.x * blockDim.x + threadIdx.x;
  if (i < 192 * 128) {
    int n = i >> 7, k = i & 127;
    float x = (n < 64) ? w_m1[k * 64 + n]
            : (n < 128) ? w_i1[k * 64 + (n - 64)]
                        : w_e1[k * 64 + (n - 128)];
    unsigned short h = f2bf(x);
    WTh[(size_t)n * 128 + k] = h;
    WTl[(size_t)n * 128 + k] = f2bf(x - bfu(h));
  }
  if (i < 192) {
    b192[i] = (i < 64) ? b_m1[i] : (i < 128) ? b_i1[i - 64] : b_e1[i - 128];
  }
}

// ---------------------------------------------------------------------------
// Fused GAT input GEMM (atomic-free): blockIdx.y = head; block = 64 rows x
// 128 cols (one full head). Epilogue reduces a_s/a_d within block -> store.
// ---------------------------------------------------------------------------
__global__ __launch_bounds__(256) void gemm_gat_kernel(
    const float* __restrict__ x, const float* __restrict__ w,
    const float* __restrict__ att_s, const float* __restrict__ att_d,
    __hip_bfloat16* __restrict__ hg, float* __restrict__ a_s,
    float* __restrict__ a_d) {
  __shared__ __align__(16) float As[64 * 20];   // [row][k]
  __shared__ __align__(16) float Bs[128 * 20];  // [col][k]
  const int bm = blockIdx.x * 64;
  const int head = blockIdx.y;
  const int tid = threadIdx.x;
  const int tr = tid >> 4;   // 0..15 -> 4 rows each
  const int tc = tid & 15;   // 0..15 -> 8 cols each

  for (int l = tid; l < 64 * 16; l += 256) {
    int r = l >> 4, k = l & 15;
    int gr = bm + r;
    As[r * 20 + k] = (k < CIN && gr < NNODES) ? x[(size_t)gr * CIN + k] : 0.0f;
  }
  for (int l = tid; l < 128 * 16; l += 256) {
    int k = l >> 7, c = l & 127;
    Bs[c * 20 + k] = (k < CIN) ? w[(size_t)k * 512 + head * 128 + c] : 0.0f;
  }
  __syncthreads();

  float acc[4][8] = {};
  for (int k = 0; k < 16; k += 4) {
    float4 a[4], b[8];
#pragma unroll
    for (int i = 0; i < 4; ++i) a[i] = *(const float4*)&As[(tr + 16 * i) * 20 + k];
#pragma unroll
    for (int j = 0; j < 8; ++j) b[j] = *(const float4*)&Bs[(tc + 16 * j) * 20 + k];
#pragma unroll
    for (int i = 0; i < 4; ++i)
#pragma unroll
      for (int j = 0; j < 8; ++j)
        acc[i][j] += a[i].x * b[j].x + a[i].y * b[j].y +
                     a[i].z * b[j].z + a[i].w * b[j].w;
  }

  float asc[8], adc[8];
#pragma unroll
  for (int j = 0; j < 8; ++j) {
    int cih = tc + 16 * j;
    asc[j] = att_s[head * HID + cih];
    adc[j] = att_d[head * HID + cih];
  }

#pragma unroll
  for (int i = 0; i < 4; ++i) {
    int r = bm + tr + 16 * i;
    float ps = 0.f, pd = 0.f;
    if (r < NNODES) {
#pragma unroll
      for (int j = 0; j < 8; ++j) {
        float v = acc[i][j];
        hg[(size_t)r * 512 + head * 128 + tc + 16 * j] = __float2bfloat16(v);
        ps += v * asc[j];
        pd += v * adc[j];
      }
    }
#pragma unroll
    for (int off = 1; off < 16; off <<= 1) {
      ps += __shfl_xor(ps, off);
      pd += __shfl_xor(pd, off);
    }
    if (tc == 0 && r < NNODES) {
      a_s[r * 4 + head] = ps;
      a_d[r * 4 + head] = pd;
    }
  }
}

// ---------------------------------------------------------------------------
// CSR build (by dst): count -> hierarchical scan -> scatter
// ---------------------------------------------------------------------------
__global__ void count_kernel(const int* __restrict__ ei, int* __restrict__ cnt) {
  int i = blockIdx.x * blockDim.x + threadIdx.x;
  if (i >= ETOT) return;
  int d = (i < NEDGES) ? ei[NEDGES + i] : (i - NEDGES);
  atomicAdd(&cnt[d], 1);
}

__global__ __launch_bounds__(256) void csr_reduce_kernel(
    const int* __restrict__ cnt, int* __restrict__ bsum) {
  __shared__ int red[256];
  int t = threadIdx.x;
  int i = blockIdx.x * 256 + t;
  red[t] = (i < NNODES) ? cnt[i] : 0;
  __syncthreads();
  for (int off = 128; off > 0; off >>= 1) {
    if (t < off) red[t] += red[t + off];
    __syncthreads();
  }
  if (t == 0) bsum[blockIdx.x] = red[0];
}

__global__ __launch_bounds__(256) void csr_scanb_kernel(
    const int* __restrict__ bsum, int* __restrict__ boff) {
  __shared__ int s[256];
  int t = threadIdx.x;
  s[t] = (t < NB_SCAN) ? bsum[t] : 0;
  __syncthreads();
  for (int off = 1; off < 256; off <<= 1) {
    int u = (t >= off) ? s[t - off] : 0;
    __syncthreads();
    s[t] += u;
    __syncthreads();
  }
  if (t < NB_SCAN) boff[t] = (t == 0) ? 0 : s[t - 1];
}

__global__ __launch_bounds__(256) void csr_scan_kernel(
    int* __restrict__ cnt, const int* __restrict__ boff,
    int* __restrict__ rowptr) {
  __shared__ int s[256];
  int t = threadIdx.x;
  int i = blockIdx.x * 256 + t;
  int v = (i < NNODES) ? cnt[i] : 0;
  s[t] = v;
  __syncthreads();
  for (int off = 1; off < 256; off <<= 1) {
    int u = (t >= off) ? s[t - off] : 0;
    __syncthreads();
    s[t] += u;
    __syncthreads();
  }
  if (i < NNODES) {
    rowptr[i] = boff[blockIdx.x] + s[t] - v;  // exclusive
    cnt[i] = 0;                               // reset -> scatter cursor
  }
  if (i == 0) rowptr[NNODES] = ETOT;
}

__global__ void scatter_kernel(const int* __restrict__ ei,
                               const float* __restrict__ ea,
                               const int* __restrict__ rowptr,
                               int* __restrict__ cursor,
                               int* __restrict__ csr_src,
                               float* __restrict__ csr_ew) {
  int i = blockIdx.x * blockDim.x + threadIdx.x;
  if (i >= ETOT) return;
  int s, d; float w;
  if (i < NEDGES) { s = ei[i]; d = ei[NEDGES + i]; w = ea[i]; }
  else            { s = d = i - NEDGES; w = 1.0f; }
  int pos = rowptr[d] + atomicAdd(&cursor[d], 1);
  csr_src[pos] = s;
  csr_ew[pos] = w;
}

__global__ void dinv_kernel(const int* __restrict__ rowptr,
                            const float* __restrict__ csr_ew,
                            float* __restrict__ dinv) {
  int n = blockIdx.x * blockDim.x + threadIdx.x;
  if (n >= NNODES) return;
  float s = 0.0f;
  int e0 = rowptr[n], e1 = rowptr[n + 1];
  for (int e = e0; e < e1; ++e) s += csr_ew[e];
  dinv[n] = (s > 0.0f) ? rsqrtf(fmaxf(s, 1e-12f)) : 0.0f;
}

// ---------------------------------------------------------------------------
// Per-node (wave) kernel: normalized GAT alpha[e][4]; in-place GCN edge norm.
// ---------------------------------------------------------------------------
__global__ __launch_bounds__(256) void alphaw_kernel(
    const float* __restrict__ a_s, const float* __restrict__ a_d,
    const float* __restrict__ dinv, const int* __restrict__ rowptr,
    const int* __restrict__ csr_src, float* __restrict__ csr_ew,
    float* __restrict__ alpha) {
  int wid = threadIdx.x >> 6, lane = threadIdx.x & 63;
  int n = blockIdx.x * 4 + wid;
  if (n >= NNODES) return;
  int e0 = rowptr[n], e1 = rowptr[n + 1];
  float4 ad = *(const float4*)&a_d[n * 4];
  float di = dinv[n];

  float m0 = -1e30f, m1 = -1e30f, m2 = -1e30f, m3 = -1e30f;
  for (int e = e0 + lane; e < e1; e += 64) {
    int s = csr_src[e];
    float4 as4 = *(const float4*)&a_s[s * 4];
    m0 = fmaxf(m0, lrelu02(as4.x + ad.x));
    m1 = fmaxf(m1, lrelu02(as4.y + ad.y));
    m2 = fmaxf(m2, lrelu02(as4.z + ad.z));
    m3 = fmaxf(m3, lrelu02(as4.w + ad.w));
  }
#pragma unroll
  for (int off = 32; off > 0; off >>= 1) {
    m0 = fmaxf(m0, __shfl_xor(m0, off));
    m1 = fmaxf(m1, __shfl_xor(m1, off));
    m2 = fmaxf(m2, __shfl_xor(m2, off));
    m3 = fmaxf(m3, __shfl_xor(m3, off));
  }

  float s0 = 0.f, s1 = 0.f, s2 = 0.f, s3 = 0.f;
  for (int e = e0 + lane; e < e1; e += 64) {
    int s = csr_src[e];
    float4 as4 = *(const float4*)&a_s[s * 4];
    float x0 = __expf(lrelu02(as4.x + ad.x) - m0);
    float x1 = __expf(lrelu02(as4.y + ad.y) - m1);
    float x2 = __expf(lrelu02(as4.z + ad.z) - m2);
    float x3 = __expf(lrelu02(as4.w + ad.w) - m3);
    s0 += x0; s1 += x1; s2 += x2; s3 += x3;
    float4 o; o.x = x0; o.y = x1; o.z = x2; o.w = x3;
    *(float4*)&alpha[(size_t)e * 4] = o;
    csr_ew[e] = dinv[s] * csr_ew[e] * di;
  }
#pragma unroll
  for (int off = 32; off > 0; off >>= 1) {
    s0 += __shfl_xor(s0, off);
    s1 += __shfl_xor(s1, off);
    s2 += __shfl_xor(s2, off);
    s3 += __shfl_xor(s3, off);
  }
  float r0 = 1.0f / (s0 + 1e-16f), r1 = 1.0f / (s1 + 1e-16f);
  float r2 = 1.0f / (s2 + 1e-16f), r3 = 1.0f / (s3 + 1e-16f);
  for (int e = e0 + lane; e < e1; e += 64) {
    float4 a = *(const float4*)&alpha[(size_t)e * 4];
    a.x *= r0; a.y *= r1; a.z *= r2; a.w *= r3;
    *(float4*)&alpha[(size_t)e * 4] = a;
  }
}

// ---------------------------------------------------------------------------
// GAT gather (pure fma): wave per node; bf16 hg; BN0+ReLU fused.
// ---------------------------------------------------------------------------
__global__ __launch_bounds__(256) void gat_gather_kernel(
    const __hip_bfloat16* __restrict__ hg, const float* __restrict__ alpha,
    const int* __restrict__ rowptr, const int* __restrict__ csr_src,
    const float* __restrict__ b_gat,
    const float* __restrict__ bg, const float* __restrict__ bb,
    const float* __restrict__ bm, const float* __restrict__ bv,
    float* __restrict__ out) {
  int wid = threadIdx.x >> 6, lane = threadIdx.x & 63;
  int n = blockIdx.x * 4 + wid;
  if (n >= NNODES) return;
  int e0 = rowptr[n], e1 = rowptr[n + 1];
  int c = 2 * lane;
  float a0x = 0.f, a0y = 0.f, a1x = 0.f, a1y = 0.f;
  float a2x = 0.f, a2y = 0.f, a3x = 0.f, a3y = 0.f;
  for (int e = e0; e < e1; ++e) {
    int s = csr_src[e];
    float4 al = *(const float4*)&alpha[(size_t)e * 4];
    const __hip_bfloat16* hrow = hg + (size_t)s * 512;
    ushort2 u0 = *(const ushort2*)(hrow + c);
    ushort2 u1 = *(const ushort2*)(hrow + 128 + c);
    ushort2 u2 = *(const ushort2*)(hrow + 256 + c);
    ushort2 u3 = *(const ushort2*)(hrow + 384 + c);
    a0x += al.x * bfu(u0.x); a0y += al.x * bfu(u0.y);
    a1x += al.y * bfu(u1.x); a1y += al.y * bfu(u1.y);
    a2x += al.z * bfu(u2.x); a2y += al.z * bfu(u2.y);
    a3x += al.w * bfu(u3.x); a3y += al.w * bfu(u3.y);
  }
  float ox = 0.25f * (a0x + a1x + a2x + a3x) + b_gat[c];
  float oy = 0.25f * (a0y + a1y + a2y + a3y) + b_gat[c + 1];
  ox = bg[c] * (ox - bm[c]) * rsqrtf(bv[c] + EPS_BN) + bb[c];
  oy = bg[c + 1] * (oy - bm[c + 1]) * rsqrtf(bv[c + 1] + EPS_BN) + bb[c + 1];
  ox = fmaxf(ox, 0.0f); oy = fmaxf(oy, 0.0f);
  float2 o; o.x = ox; o.y = oy;
  *(float2*)&out[(size_t)n * HID + c] = o;
}

// ---------------------------------------------------------------------------
// GCN gather: wave per node; h is bf16, csr_w prenormalized; BN+ReLU fused.
// ---------------------------------------------------------------------------
__global__ __launch_bounds__(256) void gcn_gather_kernel(
    const __hip_bfloat16* __restrict__ h, const int* __restrict__ rowptr,
    const int* __restrict__ csr_src, const float* __restrict__ csr_w,
    const float* __restrict__ bias,
    const float* __restrict__ bg, const float* __restrict__ bb,
    const float* __restrict__ bm, const float* __restrict__ bv,
    float* __restrict__ out) {
  int wid = threadIdx.x >> 6, lane = threadIdx.x & 63;
  int n = blockIdx.x * 4 + wid;
  if (n >= NNODES) return;
  int e0 = rowptr[n], e1 = rowptr[n + 1];
  int c = 2 * lane;
  float ax = 0.f, ay = 0.f;
  for (int e = e0; e < e1; ++e) {
    int s = csr_src[e];
    float w = csr_w[e];
    ushort2 u = *(const ushort2*)(h + (size_t)s * HID + c);
    ax += w * bfu(u.x);
    ay += w * bfu(u.y);
  }
  float ox = ax + bias[c];
  float oy = ay + bias[c + 1];
  ox = bg[c] * (ox - bm[c]) * rsqrtf(bv[c] + EPS_BN) + bb[c];
  oy = bg[c + 1] * (oy - bm[c + 1]) * rsqrtf(bv[c + 1] + EPS_BN) + bb[c + 1];
  ox = fmaxf(ox, 0.0f); oy = fmaxf(oy, 0.0f);
  float2 o; o.x = ox; o.y = oy;
  *(float2*)&out[(size_t)n * HID + c] = o;
}

// ---------------------------------------------------------------------------
// Final heads: from h192[N,192] (hm|hi|he) compute 5 outputs per node.
// ---------------------------------------------------------------------------
__global__ __launch_bounds__(256) void heads_final_kernel(
    const float* __restrict__ h192, const float* __restrict__ w_m2,
    const float* __restrict__ b_m2, const float* __restrict__ w_i2,
    const float* __restrict__ b_i2, const float* __restrict__ w_e2,
    const float* __restrict__ b_e2, float* __restrict__ out) {
  int wid = threadIdx.x >> 6;
  int lane = threadIdx.x & 63;
  int n = blockIdx.x * 4 + wid;
  if (n >= NNODES) return;
  const float* row = h192 + (size_t)n * 192;
  float hm = row[lane], hi = row[64 + lane], he = row[128 + lane];
  float p0 = hm * w_m2[lane * 2 + 0];
  float p1 = hm * w_m2[lane * 2 + 1];
  float p2 = hi * w_i2[lane * 2 + 0];
  float p3 = hi * w_i2[lane * 2 + 1];
  float p4 = he * w_e2[lane];
#pragma unroll
  for (int off = 32; off > 0; off >>= 1) {
    p0 += __shfl_down(p0, off);
    p1 += __shfl_down(p1, off);
    p2 += __shfl_down(p2, off);
    p3 += __shfl_down(p3, off);
    p4 += __shfl_down(p4, off);
  }
  if (lane == 0) {
    out[n * 2 + 0] = p0 + b_m2[0];
    out[n * 2 + 1] = p1 + b_m2[1];
    out[2 * NNODES + n * 2 + 0] = p2 + b_i2[0];
    out[2 * NNODES + n * 2 + 1] = p3 + b_i2[1];
    out[4 * NNODES + n] = p4 + b_e2[0];
  }
}

// ---------------------------------------------------------------------------
extern "C" void kernel_launch(void* const* d_in, const int* in_sizes, int n_in,
                              void* d_out, int out_size, void* d_ws, size_t ws_size,
                              hipStream_t stream) {
  const float* x       = (const float*)d_in[0];
  const int*   ei      = (const int*)d_in[1];
  const float* ea      = (const float*)d_in[2];
  const float* w_gat   = (const float*)d_in[3];
  const float* att_src = (const float*)d_in[4];
  const float* att_dst = (const float*)d_in[5];
  const float* b_gat   = (const float*)d_in[6];
  const float* w2 = (const float*)d_in[7];  const float* b2 = (const float*)d_in[8];
  const float* w3 = (const float*)d_in[9];  const float* b3 = (const float*)d_in[10];
  const float* w4 = (const float*)d_in[11]; const float* b4 = (const float*)d_in[12];
  const float* bn_g = (const float*)d_in[13];
  const float* bn_b = (const float*)d_in[14];
  const float* bn_m = (const float*)d_in[15];
  const float* bn_v = (const float*)d_in[16];
  const float* w_shared = (const float*)d_in[17]; const float* b_shared = (const float*)d_in[18];
  const float* w_m1 = (const float*)d_in[19]; const float* b_m1 = (const float*)d_in[20];
  const float* w_m2 = (const float*)d_in[21]; const float* b_m2 = (const float*)d_in[22];
  const float* w_i1 = (const float*)d_in[23]; const float* b_i1 = (const float*)d_in[24];
  const float* w_i2 = (const float*)d_in[25]; const float* b_i2 = (const float*)d_in[26];
  const float* w_e1 = (const float*)d_in[27]; const float* b_e1 = (const float*)d_in[28];
  const float* w_e2 = (const float*)d_in[29]; const float* b_e2 = (const float*)d_in[30];
  float* out = (float*)d_out;

  // ---- workspace layout ----
  size_t off = 0;
  auto alloc = [&](size_t bytes) -> char* {
    char* p = (char*)d_ws + off;
    off += (bytes + 255) & ~(size_t)255;
    return p;
  };
  char*  hgreg   = alloc((size_t)NNODES * 512 * 4);   // bf16 hg; later aliased f32
  float* p0      = (float*)alloc((size_t)NNODES * HID * 4);
  float* hb_f    = (float*)alloc((size_t)NNODES * HID * 4);  // bf16 hb / f32 alpha alias
  float* a_s     = (float*)alloc((size_t)NNODES * 4 * 4);
  float* a_d     = (float*)alloc((size_t)NNODES * 4 * 4);
  float* dinv    = (float*)alloc((size_t)NNODES * 4);
  float* csr_ew  = (float*)alloc((size_t)ETOT * 4);
  int*   rowptr  = (int*)alloc((size_t)(NNODES + 1) * 4);
  int*   cnt     = (int*)alloc((size_t)NNODES * 4);
  int*   csr_src = (int*)alloc((size_t)ETOT * 4);
  int*   bsum    = (int*)alloc((size_t)NB_SCAN * 4);
  int*   boff    = (int*)alloc((size_t)NB_SCAN * 4);
  // split-bf16 transposed weights: 4x 128x128 contiguous + 192x128
  unsigned short* wtH = (unsigned short*)alloc(4 * 128 * 128 * 2);
  unsigned short* wtL = (unsigned short*)alloc(4 * 128 * 128 * 2);
  unsigned short* wt192h = (unsigned short*)alloc(192 * 128 * 2);
  unsigned short* wt192l = (unsigned short*)alloc(192 * 128 * 2);
  float* b192 = (float*)alloc(192 * 4);

  unsigned short* wt2h = wtH + 0 * 16384; unsigned short* wt2l = wtL + 0 * 16384;
  unsigned short* wt3h = wtH + 1 * 16384; unsigned short* wt3l = wtL + 1 * 16384;
  unsigned short* wt4h = wtH + 2 * 16384; unsigned short* wt4l = wtL + 2 * 16384;
  unsigned short* wsh  = wtH + 3 * 16384; unsigned short* wsl  = wtL + 3 * 16384;

  __hip_bfloat16* hg = (__hip_bfloat16*)hgreg;          // N*512 bf16
  __hip_bfloat16* hb = (__hip_bfloat16*)hb_f;           // N*128 bf16 (GEMM out)
  float* alpha = hb_f;                                  // ETOT*4 f32 (dead before hb)
  float* p1   = (float*)hgreg;                          // N*128 f32 (hg dead)
  float* h192 = (float*)hgreg + (size_t)NNODES * HID;   // N*192 f32, disjoint

  dim3 blk256(256);
  dim3 wgrid((NNODES + 3) / 4);
  dim3 mgrid((NNODES + 63) / 64);

  // 1) CSR build: count -> hierarchical scan (also zeroes cnt) -> scatter
  hipMemsetAsync(cnt, 0, NNODES * 4, stream);
  count_kernel<<<(ETOT + 255) / 256, blk256, 0, stream>>>(ei, cnt);
  csr_reduce_kernel<<<NB_SCAN, blk256, 0, stream>>>(cnt, bsum);
  csr_scanb_kernel<<<1, blk256, 0, stream>>>(bsum, boff);
  csr_scan_kernel<<<NB_SCAN, blk256, 0, stream>>>(cnt, boff, rowptr);
  scatter_kernel<<<(ETOT + 255) / 256, blk256, 0, stream>>>(
      ei, ea, rowptr, cnt, csr_src, csr_ew);
  dinv_kernel<<<(NNODES + 255) / 256, blk256, 0, stream>>>(rowptr, csr_ew, dinv);

  // 2) weight packs (independent)
  pack_wt4_kernel<<<dim3((128 * 128 + 255) / 256, 4), blk256, 0, stream>>>(
      w2, w3, w4, w_shared, wtH, wtL);
  pack_wt192_kernel<<<(192 * 128 + 255) / 256, blk256, 0, stream>>>(
      w_m1, w_i1, w_e1, b_m1, b_i1, b_e1, wt192h, wt192l, b192);

  // 3) fused GAT GEMM: hg(bf16) + a_s/a_d (atomic-free)
  gemm_gat_kernel<<<dim3((NNODES + 63) / 64, 4), blk256, 0, stream>>>(
      x, w_gat, att_src, att_dst, hg, a_s, a_d);

  // 4) per-edge alpha + normalized GCN weights
  alphaw_kernel<<<wgrid, blk256, 0, stream>>>(
      a_s, a_d, dinv, rowptr, csr_src, csr_ew, alpha);

  // 5) GAT gather + BN0 + ReLU -> p0 (f32)
  gat_gather_kernel<<<wgrid, blk256, 0, stream>>>(
      hg, alpha, rowptr, csr_src, b_gat,
      bn_g + 0, bn_b + 0, bn_m + 0, bn_v + 0, p0);

  // 6) GCN layer 2: hb(bf16) = p0 @ w2 ; gather -> p1
  gemm_mfma_kernel<2><<<mgrid, blk256, 0, stream>>>(p0, wt2h, wt2l, nullptr, hb, 0, 1);
  gcn_gather_kernel<<<wgrid, blk256, 0, stream>>>(
      hb, rowptr, csr_src, csr_ew, b2,
      bn_g + 128, bn_b + 128, bn_m + 128, bn_v + 128, p1);

  // 7) GCN layer 3
  gemm_mfma_kernel<2><<<mgrid, blk256, 0, stream>>>(p1, wt3h, wt3l, nullptr, hb, 0, 1);
  gcn_gather_kernel<<<wgrid, blk256, 0, stream>>>(
      hb, rowptr, csr_src, csr_ew, b3,
      bn_g + 256, bn_b + 256, bn_m + 256, bn_v + 256, p0);

  // 8) GCN layer 4
  gemm_mfma_kernel<2><<<mgrid, blk256, 0, stream>>>(p0, wt4h, wt4l, nullptr, hb, 0, 1);
  gcn_gather_kernel<<<wgrid, blk256, 0, stream>>>(
      hb, rowptr, csr_src, csr_ew, b4,
      bn_g + 384, bn_b + 384, bn_m + 384, bn_v + 384, p1);

  // 9) hs = relu(p1 @ w_shared + b_shared) -> p0 (f32)
  gemm_mfma_kernel<2><<<mgrid, blk256, 0, stream>>>(p1, wsh, wsl, b_shared, p0, 1, 0);

  // 10) h192 = relu(p0 @ wt192 + b192) (f32)
  gemm_mfma_kernel<3><<<mgrid, blk256, 0, stream>>>(p0, wt192h, wt192l, b192, h192, 1, 0);

  // 11) final heads -> d_out
  heads_final_kernel<<<wgrid, blk256, 0, stream>>>(
      h192, w_m2, b_m2, w_i2, b_i2, w_e2, b_e2, out);
}

// Round 10
// 500.300 us; speedup vs baseline: 1.7552x; 1.0282x over previous
//
#include <hip/hip_runtime.h>
#include <hip/hip_bf16.h>

#define NNODES 50000
#define NEDGES 400000
#define ETOT   (NEDGES + NNODES)
#define CIN    15
#define HID    128
#define HEADS  4
#define EPS_BN 1e-5f
#define NB_SCAN ((NNODES + 255) / 256)   // 196 blocks

typedef __attribute__((ext_vector_type(8))) short bf16x8_t;   // 8 bf16 = 4 VGPR
typedef __attribute__((ext_vector_type(4))) float f32x4_t;    // MFMA 16x16 acc

__device__ __forceinline__ float bfu(unsigned short u) {
  return __uint_as_float(((unsigned)u) << 16);
}
__device__ __forceinline__ unsigned short f2bf(float x) {
  union { __hip_bfloat16 b; unsigned short u; } c;
  c.b = __float2bfloat16(x);
  return c.u;
}
__device__ __forceinline__ float lrelu02(float x) {
  return x > 0.0f ? x : 0.2f * x;
}

// ---------------------------------------------------------------------------
// Split-bf16 MFMA GEMM:  C[M=NNODES, WPT*64] = epi(A[M,KT] @ W + bias)
// Wave w owns ALL 64 rows x cols [w*WPT*16, (w+1)*WPT*16). B fragments loaded
// ONCE to registers; inner loop pure ds_read_b128 + MFMA.
// Epilogue: +bias, optional BN (bg!=null), optional ReLU.
// ---------------------------------------------------------------------------
template <int WPT, int KT>
__global__ __launch_bounds__(256) void gemm_mfma_kernel(
    const float* __restrict__ A, const unsigned short* __restrict__ WTh,
    const unsigned short* __restrict__ WTl, const float* __restrict__ bias,
    const float* __restrict__ bg, const float* __restrict__ bb,
    const float* __restrict__ bm, const float* __restrict__ bv,
    void* __restrict__ Cout, int act, int obf16) {
  constexpr int NC = WPT * 64;
  constexpr int CPR = KT / 8;          // 8-elem chunks per row
  __shared__ unsigned short Ah[64 * KT];
  __shared__ unsigned short Al[64 * KT];
  const int tid = threadIdx.x;
  const int bm_ = blockIdx.x * 64;
  const int wv = tid >> 6, l = tid & 63;
  const int lcol = l & 15;
  const int kg = (l >> 4) << 3;
  const int colbase = wv * (WPT * 16);

  // preload ALL B fragments for this wave's column strip
  bf16x8_t bh[WPT][KT / 32], bl[WPT][KT / 32];
#pragma unroll
  for (int jj = 0; jj < WPT; ++jj)
#pragma unroll
    for (int kc = 0; kc < KT / 32; ++kc) {
      size_t boff = (size_t)(colbase + jj * 16 + lcol) * KT + kc * 32 + kg;
      bh[jj][kc] = *(const bf16x8_t*)(WTh + boff);
      bl[jj][kc] = *(const bf16x8_t*)(WTl + boff);
    }

  // stage A tile (64 x KT f32) -> hi/lo bf16 in LDS, XOR-swizzled
#pragma unroll
  for (int i = 0; i < (64 * CPR) / 256; ++i) {
    int cch = tid + 256 * i;
    int r = cch / CPR, k0 = (cch % CPR) << 3;
    int gr = bm_ + r;
    float v[8];
    if (gr < NNODES) {
      float4 v0 = *(const float4*)&A[(size_t)gr * KT + k0];
      float4 v1 = *(const float4*)&A[(size_t)gr * KT + k0 + 4];
      v[0] = v0.x; v[1] = v0.y; v[2] = v0.z; v[3] = v0.w;
      v[4] = v1.x; v[5] = v1.y; v[6] = v1.z; v[7] = v1.w;
    } else {
#pragma unroll
      for (int j = 0; j < 8; ++j) v[j] = 0.0f;
    }
    bf16x8_t hv, lv;
#pragma unroll
    for (int j = 0; j < 8; ++j) {
      unsigned short h = f2bf(v[j]);
      hv[j] = (short)h;
      lv[j] = (short)f2bf(v[j] - bfu(h));
    }
    int byte = (k0 << 1) ^ ((r & 7) << 4);
    *(bf16x8_t*)((char*)(Ah + r * KT) + byte) = hv;
    *(bf16x8_t*)((char*)(Al + r * KT) + byte) = lv;
  }
  __syncthreads();

  f32x4_t acc[4][WPT];
#pragma unroll
  for (int rt = 0; rt < 4; ++rt)
#pragma unroll
    for (int jj = 0; jj < WPT; ++jj) acc[rt][jj] = (f32x4_t){0.f, 0.f, 0.f, 0.f};

#pragma unroll
  for (int kc = 0; kc < KT / 32; ++kc) {
    int k = kc * 32 + kg;
#pragma unroll
    for (int rt = 0; rt < 4; ++rt) {
      int lrow = rt * 16 + (l & 15);
      int byte = (k << 1) ^ ((lrow & 7) << 4);
      bf16x8_t ah = *(const bf16x8_t*)((const char*)(Ah + lrow * KT) + byte);
      bf16x8_t al = *(const bf16x8_t*)((const char*)(Al + lrow * KT) + byte);
#pragma unroll
      for (int jj = 0; jj < WPT; ++jj) {
        acc[rt][jj] = __builtin_amdgcn_mfma_f32_16x16x32_bf16(ah, bh[jj][kc], acc[rt][jj], 0, 0, 0);
        acc[rt][jj] = __builtin_amdgcn_mfma_f32_16x16x32_bf16(ah, bl[jj][kc], acc[rt][jj], 0, 0, 0);
        acc[rt][jj] = __builtin_amdgcn_mfma_f32_16x16x32_bf16(al, bh[jj][kc], acc[rt][jj], 0, 0, 0);
      }
    }
  }

  // C/D layout (m89-verified): col = lane&15, row = (lane>>4)*4 + reg
#pragma unroll
  for (int rt = 0; rt < 4; ++rt) {
    int orow0 = bm_ + rt * 16 + ((l >> 4) << 2);
#pragma unroll
    for (int jj = 0; jj < WPT; ++jj) {
      int col = colbase + jj * 16 + lcol;
      float bs = bias ? bias[col] : 0.0f;
#pragma unroll
      for (int r = 0; r < 4; ++r) {
        int row = orow0 + r;
        if (row >= NNODES) continue;
        float vv = acc[rt][jj][r] + bs;
        if (bg) vv = bg[col] * (vv - bm[col]) * rsqrtf(bv[col] + EPS_BN) + bb[col];
        if (act) vv = fmaxf(vv, 0.0f);
        if (obf16)
          ((unsigned short*)Cout)[(size_t)row * NC + col] = f2bf(vv);
        else
          ((float*)Cout)[(size_t)row * NC + col] = vv;
      }
    }
  }
}

// ---------------------------------------------------------------------------
// GAT precompute: wv_s[k,h] = sum_c w_gat[k, h*128+c]*att_s[h,c] (and _d)
// ---------------------------------------------------------------------------
__global__ void prep_att_kernel(const float* __restrict__ w,
                                const float* __restrict__ att_s,
                                const float* __restrict__ att_d,
                                float* __restrict__ wv_s,
                                float* __restrict__ wv_d) {
  int t = threadIdx.x;
  if (t >= 60) return;
  int k = t / 4, h = t & 3;
  float s = 0.f, d = 0.f;
  for (int c = 0; c < 128; ++c) {
    float wk = w[(size_t)k * 512 + h * 128 + c];
    s += wk * att_s[h * 128 + c];
    d += wk * att_d[h * 128 + c];
  }
  wv_s[k * 4 + h] = s;
  wv_d[k * 4 + h] = d;
}

// Pack post-GAT weight: Wp[c][j] = 0.25*w_gat[k, h*128+c], j=h*15+k (64-pad)
__global__ void pack_wtp_kernel(const float* __restrict__ w,
                                unsigned short* __restrict__ WTh,
                                unsigned short* __restrict__ WTl) {
  int i = blockIdx.x * blockDim.x + threadIdx.x;
  if (i >= 128 * 64) return;
  int c = i >> 6, j = i & 63;
  float xv = 0.f;
  if (j < 60) {
    int h = j / 15, k = j - h * 15;
    xv = 0.25f * w[(size_t)k * 512 + h * 128 + c];
  }
  unsigned short hh = f2bf(xv);
  WTh[i] = hh;
  WTl[i] = f2bf(xv - bfu(hh));
}

// ---------------------------------------------------------------------------
// Per-node attention logits: a_s[n,h] = sum_k x[n,k]*wv_s[k,h]
// ---------------------------------------------------------------------------
__global__ __launch_bounds__(256) void a_sd_kernel(
    const float* __restrict__ x, const float* __restrict__ wv_s,
    const float* __restrict__ wv_d, float* __restrict__ a_s,
    float* __restrict__ a_d) {
  __shared__ float xs[256 * 15];
  __shared__ float wvs[60], wvd[60];
  int t = threadIdx.x;
  int base = blockIdx.x * 256;
  if (t < 60) { wvs[t] = wv_s[t]; wvd[t] = wv_d[t]; }
  for (int i = t; i < 256 * 15; i += 256) {
    int gi = base * 15 + i;
    xs[i] = (gi < NNODES * 15) ? x[gi] : 0.0f;
  }
  __syncthreads();
  int n = base + t;
  if (n >= NNODES) return;
  float a0 = 0, a1 = 0, a2 = 0, a3 = 0, d0 = 0, d1 = 0, d2 = 0, d3 = 0;
#pragma unroll
  for (int k = 0; k < 15; ++k) {
    float xv = xs[t * 15 + k];
    a0 += xv * wvs[k * 4 + 0]; a1 += xv * wvs[k * 4 + 1];
    a2 += xv * wvs[k * 4 + 2]; a3 += xv * wvs[k * 4 + 3];
    d0 += xv * wvd[k * 4 + 0]; d1 += xv * wvd[k * 4 + 1];
    d2 += xv * wvd[k * 4 + 2]; d3 += xv * wvd[k * 4 + 3];
  }
  float4 A; A.x = a0; A.y = a1; A.z = a2; A.w = a3;
  float4 D; D.x = d0; D.y = d1; D.z = d2; D.w = d3;
  *(float4*)&a_s[n * 4] = A;
  *(float4*)&a_d[n * 4] = D;
}

// ---------------------------------------------------------------------------
// Fused GAT gather over x: wave per node; lane<60 -> (h=lane/15, k=lane%15).
// pass1: per-head max; pass2: ex=exp(lrelu(a_s+a_d)-m), ssum+=ex,
// acc+=ex*x[src,k]; lane60 normalizes csr_ew (GCN). g[n,lane]=acc/ssum.
// ---------------------------------------------------------------------------
__global__ __launch_bounds__(256) void gat_fused_kernel(
    const float* __restrict__ x, const float* __restrict__ a_s,
    const float* __restrict__ a_d, const float* __restrict__ dinv,
    const int* __restrict__ rowptr, const int* __restrict__ csr_src,
    float* __restrict__ csr_ew, float* __restrict__ g) {
  int wid = threadIdx.x >> 6, lane = threadIdx.x & 63;
  int n = blockIdx.x * 4 + wid;
  if (n >= NNODES) return;
  int e0 = rowptr[n], e1 = rowptr[n + 1];
  int h = lane / 15;                 // 0..3 active, 4 for lanes 60..63
  int k = lane - h * 15;
  bool on = lane < 60;
  float adn = on ? a_d[n * 4 + h] : 0.0f;
  float di = dinv[n];

  float m = -1e30f;
  for (int e = e0; e < e1; ++e) {
    int s = csr_src[e];
    if (on) m = fmaxf(m, lrelu02(a_s[s * 4 + h] + adn));
  }

  float ssum = 0.f, acc = 0.f;
  for (int e = e0; e < e1; ++e) {
    int s = csr_src[e];
    if (on) {
      float ex = __expf(lrelu02(a_s[s * 4 + h] + adn) - m);
      ssum += ex;
      acc += ex * x[(size_t)s * CIN + k];
    } else if (lane == 60) {
      csr_ew[e] = dinv[s] * csr_ew[e] * di;
    }
  }
  g[(size_t)n * 64 + lane] = on ? acc / (ssum + 1e-16f) : 0.0f;
}

// ---------------------------------------------------------------------------
// Fused pack of the four 128x128 weights -> [N][K] bf16 hi/lo (transposed)
// ---------------------------------------------------------------------------
__global__ void pack_wt4_kernel(
    const float* __restrict__ w2, const float* __restrict__ w3,
    const float* __restrict__ w4, const float* __restrict__ ws,
    unsigned short* __restrict__ Hbase, unsigned short* __restrict__ Lbase) {
  int i = blockIdx.x * blockDim.x + threadIdx.x;
  if (i >= 128 * 128) return;
  const float* W = (blockIdx.y == 0) ? w2 : (blockIdx.y == 1) ? w3
                 : (blockIdx.y == 2) ? w4 : ws;
  unsigned short* Wh = Hbase + (size_t)blockIdx.y * 128 * 128;
  unsigned short* Wl = Lbase + (size_t)blockIdx.y * 128 * 128;
  int k = i >> 7, n = i & 127;
  float x = W[i];
  unsigned short h = f2bf(x);
  Wh[n * 128 + k] = h;
  Wl[n * 128 + k] = f2bf(x - bfu(h));
}

// Pack the three 128x64 head weights into WT192 [192][128] hi/lo + b192
__global__ void pack_wt192_kernel(
    const float* __restrict__ w_m1, const float* __restrict__ w_i1,
    const float* __restrict__ w_e1, const float* __restrict__ b_m1,
    const float* __restrict__ b_i1, const float* __restrict__ b_e1,
    unsigned short* __restrict__ WTh, unsigned short* __restrict__ WTl,
    float* __restrict__ b192) {
  int i = blockIdx.x * blockDim.x + threadIdx.x;
  if (i < 192 * 128) {
    int n = i >> 7, k = i & 127;
    float x = (n < 64) ? w_m1[k * 64 + n]
            : (n < 128) ? w_i1[k * 64 + (n - 64)]
                        : w_e1[k * 64 + (n - 128)];
    unsigned short h = f2bf(x);
    WTh[(size_t)n * 128 + k] = h;
    WTl[(size_t)n * 128 + k] = f2bf(x - bfu(h));
  }
  if (i < 192) {
    b192[i] = (i < 64) ? b_m1[i] : (i < 128) ? b_i1[i - 64] : b_e1[i - 128];
  }
}

// ---------------------------------------------------------------------------
// CSR build (by dst): count -> hierarchical scan -> scatter
// ---------------------------------------------------------------------------
__global__ void count_kernel(const int* __restrict__ ei, int* __restrict__ cnt) {
  int i = blockIdx.x * blockDim.x + threadIdx.x;
  if (i >= ETOT) return;
  int d = (i < NEDGES) ? ei[NEDGES + i] : (i - NEDGES);
  atomicAdd(&cnt[d], 1);
}

__global__ __launch_bounds__(256) void csr_reduce_kernel(
    const int* __restrict__ cnt, int* __restrict__ bsum) {
  __shared__ int red[256];
  int t = threadIdx.x;
  int i = blockIdx.x * 256 + t;
  red[t] = (i < NNODES) ? cnt[i] : 0;
  __syncthreads();
  for (int off = 128; off > 0; off >>= 1) {
    if (t < off) red[t] += red[t + off];
    __syncthreads();
  }
  if (t == 0) bsum[blockIdx.x] = red[0];
}

__global__ __launch_bounds__(256) void csr_scanb_kernel(
    const int* __restrict__ bsum, int* __restrict__ boff) {
  __shared__ int s[256];
  int t = threadIdx.x;
  s[t] = (t < NB_SCAN) ? bsum[t] : 0;
  __syncthreads();
  for (int off = 1; off < 256; off <<= 1) {
    int u = (t >= off) ? s[t - off] : 0;
    __syncthreads();
    s[t] += u;
    __syncthreads();
  }
  if (t < NB_SCAN) boff[t] = (t == 0) ? 0 : s[t - 1];
}

__global__ __launch_bounds__(256) void csr_scan_kernel(
    int* __restrict__ cnt, const int* __restrict__ boff,
    int* __restrict__ rowptr) {
  __shared__ int s[256];
  int t = threadIdx.x;
  int i = blockIdx.x * 256 + t;
  int v = (i < NNODES) ? cnt[i] : 0;
  s[t] = v;
  __syncthreads();
  for (int off = 1; off < 256; off <<= 1) {
    int u = (t >= off) ? s[t - off] : 0;
    __syncthreads();
    s[t] += u;
    __syncthreads();
  }
  if (i < NNODES) {
    rowptr[i] = boff[blockIdx.x] + s[t] - v;  // exclusive
    cnt[i] = 0;                               // reset -> scatter cursor
  }
  if (i == 0) rowptr[NNODES] = ETOT;
}

__global__ void scatter_kernel(const int* __restrict__ ei,
                               const float* __restrict__ ea,
                               const int* __restrict__ rowptr,
                               int* __restrict__ cursor,
                               int* __restrict__ csr_src,
                               float* __restrict__ csr_ew) {
  int i = blockIdx.x * blockDim.x + threadIdx.x;
  if (i >= ETOT) return;
  int s, d; float w;
  if (i < NEDGES) { s = ei[i]; d = ei[NEDGES + i]; w = ea[i]; }
  else            { s = d = i - NEDGES; w = 1.0f; }
  int pos = rowptr[d] + atomicAdd(&cursor[d], 1);
  csr_src[pos] = s;
  csr_ew[pos] = w;
}

__global__ void dinv_kernel(const int* __restrict__ rowptr,
                            const float* __restrict__ csr_ew,
                            float* __restrict__ dinv) {
  int n = blockIdx.x * blockDim.x + threadIdx.x;
  if (n >= NNODES) return;
  float s = 0.0f;
  int e0 = rowptr[n], e1 = rowptr[n + 1];
  for (int e = e0; e < e1; ++e) s += csr_ew[e];
  dinv[n] = (s > 0.0f) ? rsqrtf(fmaxf(s, 1e-12f)) : 0.0f;
}

// ---------------------------------------------------------------------------
// GCN gather: wave per node; h is bf16, csr_w prenormalized; BN+ReLU fused.
// ---------------------------------------------------------------------------
__global__ __launch_bounds__(256) void gcn_gather_kernel(
    const __hip_bfloat16* __restrict__ h, const int* __restrict__ rowptr,
    const int* __restrict__ csr_src, const float* __restrict__ csr_w,
    const float* __restrict__ bias,
    const float* __restrict__ bg, const float* __restrict__ bb,
    const float* __restrict__ bm, const float* __restrict__ bv,
    float* __restrict__ out) {
  int wid = threadIdx.x >> 6, lane = threadIdx.x & 63;
  int n = blockIdx.x * 4 + wid;
  if (n >= NNODES) return;
  int e0 = rowptr[n], e1 = rowptr[n + 1];
  int c = 2 * lane;
  float ax = 0.f, ay = 0.f;
  for (int e = e0; e < e1; ++e) {
    int s = csr_src[e];
    float w = csr_w[e];
    ushort2 u = *(const ushort2*)(h + (size_t)s * HID + c);
    ax += w * bfu(u.x);
    ay += w * bfu(u.y);
  }
  float ox = ax + bias[c];
  float oy = ay + bias[c + 1];
  ox = bg[c] * (ox - bm[c]) * rsqrtf(bv[c] + EPS_BN) + bb[c];
  oy = bg[c + 1] * (oy - bm[c + 1]) * rsqrtf(bv[c + 1] + EPS_BN) + bb[c + 1];
  ox = fmaxf(ox, 0.0f); oy = fmaxf(oy, 0.0f);
  float2 o; o.x = ox; o.y = oy;
  *(float2*)&out[(size_t)n * HID + c] = o;
}

// ---------------------------------------------------------------------------
// Final heads: from h192[N,192] (hm|hi|he) compute 5 outputs per node.
// ---------------------------------------------------------------------------
__global__ __launch_bounds__(256) void heads_final_kernel(
    const float* __restrict__ h192, const float* __restrict__ w_m2,
    const float* __restrict__ b_m2, const float* __restrict__ w_i2,
    const float* __restrict__ b_i2, const float* __restrict__ w_e2,
    const float* __restrict__ b_e2, float* __restrict__ out) {
  int wid = threadIdx.x >> 6;
  int lane = threadIdx.x & 63;
  int n = blockIdx.x * 4 + wid;
  if (n >= NNODES) return;
  const float* row = h192 + (size_t)n * 192;
  float hm = row[lane], hi = row[64 + lane], he = row[128 + lane];
  float p0 = hm * w_m2[lane * 2 + 0];
  float p1 = hm * w_m2[lane * 2 + 1];
  float p2 = hi * w_i2[lane * 2 + 0];
  float p3 = hi * w_i2[lane * 2 + 1];
  float p4 = he * w_e2[lane];
#pragma unroll
  for (int off = 32; off > 0; off >>= 1) {
    p0 += __shfl_down(p0, off);
    p1 += __shfl_down(p1, off);
    p2 += __shfl_down(p2, off);
    p3 += __shfl_down(p3, off);
    p4 += __shfl_down(p4, off);
  }
  if (lane == 0) {
    out[n * 2 + 0] = p0 + b_m2[0];
    out[n * 2 + 1] = p1 + b_m2[1];
    out[2 * NNODES + n * 2 + 0] = p2 + b_i2[0];
    out[2 * NNODES + n * 2 + 1] = p3 + b_i2[1];
    out[4 * NNODES + n] = p4 + b_e2[0];
  }
}

// ---------------------------------------------------------------------------
extern "C" void kernel_launch(void* const* d_in, const int* in_sizes, int n_in,
                              void* d_out, int out_size, void* d_ws, size_t ws_size,
                              hipStream_t stream) {
  const float* x       = (const float*)d_in[0];
  const int*   ei      = (const int*)d_in[1];
  const float* ea      = (const float*)d_in[2];
  const float* w_gat   = (const float*)d_in[3];
  const float* att_src = (const float*)d_in[4];
  const float* att_dst = (const float*)d_in[5];
  const float* b_gat   = (const float*)d_in[6];
  const float* w2 = (const float*)d_in[7];  const float* b2 = (const float*)d_in[8];
  const float* w3 = (const float*)d_in[9];  const float* b3 = (const float*)d_in[10];
  const float* w4 = (const float*)d_in[11]; const float* b4 = (const float*)d_in[12];
  const float* bn_g = (const float*)d_in[13];
  const float* bn_b = (const float*)d_in[14];
  const float* bn_m = (const float*)d_in[15];
  const float* bn_v = (const float*)d_in[16];
  const float* w_shared = (const float*)d_in[17]; const float* b_shared = (const float*)d_in[18];
  const float* w_m1 = (const float*)d_in[19]; const float* b_m1 = (const float*)d_in[20];
  const float* w_m2 = (const float*)d_in[21]; const float* b_m2 = (const float*)d_in[22];
  const float* w_i1 = (const float*)d_in[23]; const float* b_i1 = (const float*)d_in[24];
  const float* w_i2 = (const float*)d_in[25]; const float* b_i2 = (const float*)d_in[26];
  const float* w_e1 = (const float*)d_in[27]; const float* b_e1 = (const float*)d_in[28];
  const float* w_e2 = (const float*)d_in[29]; const float* b_e2 = (const float*)d_in[30];
  float* out = (float*)d_out;

  // ---- workspace layout ----
  size_t off = 0;
  auto alloc = [&](size_t bytes) -> char* {
    char* p = (char*)d_ws + off;
    off += (bytes + 255) & ~(size_t)255;
    return p;
  };
  float* p0      = (float*)alloc((size_t)NNODES * HID * 4);
  float* p1      = (float*)alloc((size_t)NNODES * HID * 4);
  float* h192    = (float*)alloc((size_t)NNODES * 192 * 4);
  float* g       = (float*)alloc((size_t)NNODES * 64 * 4);
  __hip_bfloat16* hb = (__hip_bfloat16*)alloc((size_t)NNODES * HID * 2);
  float* a_s     = (float*)alloc((size_t)NNODES * 4 * 4);
  float* a_d     = (float*)alloc((size_t)NNODES * 4 * 4);
  float* dinv    = (float*)alloc((size_t)NNODES * 4);
  float* csr_ew  = (float*)alloc((size_t)ETOT * 4);
  int*   rowptr  = (int*)alloc((size_t)(NNODES + 1) * 4);
  int*   cnt     = (int*)alloc((size_t)NNODES * 4);
  int*   csr_src = (int*)alloc((size_t)ETOT * 4);
  int*   bsum    = (int*)alloc((size_t)NB_SCAN * 4);
  int*   boff    = (int*)alloc((size_t)NB_SCAN * 4);
  // split-bf16 transposed weights
  unsigned short* wtH = (unsigned short*)alloc(4 * 128 * 128 * 2);
  unsigned short* wtL = (unsigned short*)alloc(4 * 128 * 128 * 2);
  unsigned short* wt192h = (unsigned short*)alloc(192 * 128 * 2);
  unsigned short* wt192l = (unsigned short*)alloc(192 * 128 * 2);
  unsigned short* wtph = (unsigned short*)alloc(128 * 64 * 2);
  unsigned short* wtpl = (unsigned short*)alloc(128 * 64 * 2);
  float* b192 = (float*)alloc(192 * 4);
  float* wv_s = (float*)alloc(60 * 4);
  float* wv_d = (float*)alloc(60 * 4);

  unsigned short* wt2h = wtH + 0 * 16384; unsigned short* wt2l = wtL + 0 * 16384;
  unsigned short* wt3h = wtH + 1 * 16384; unsigned short* wt3l = wtL + 1 * 16384;
  unsigned short* wt4h = wtH + 2 * 16384; unsigned short* wt4l = wtL + 2 * 16384;
  unsigned short* wsh  = wtH + 3 * 16384; unsigned short* wsl  = wtL + 3 * 16384;

  dim3 blk256(256);
  dim3 wgrid((NNODES + 3) / 4);
  dim3 mgrid((NNODES + 63) / 64);

  // 1) CSR build: count -> hierarchical scan (also zeroes cnt) -> scatter
  hipMemsetAsync(cnt, 0, NNODES * 4, stream);
  count_kernel<<<(ETOT + 255) / 256, blk256, 0, stream>>>(ei, cnt);
  csr_reduce_kernel<<<NB_SCAN, blk256, 0, stream>>>(cnt, bsum);
  csr_scanb_kernel<<<1, blk256, 0, stream>>>(bsum, boff);
  csr_scan_kernel<<<NB_SCAN, blk256, 0, stream>>>(cnt, boff, rowptr);
  scatter_kernel<<<(ETOT + 255) / 256, blk256, 0, stream>>>(
      ei, ea, rowptr, cnt, csr_src, csr_ew);
  dinv_kernel<<<(NNODES + 255) / 256, blk256, 0, stream>>>(rowptr, csr_ew, dinv);

  // 2) precompute + packs (independent)
  prep_att_kernel<<<1, 64, 0, stream>>>(w_gat, att_src, att_dst, wv_s, wv_d);
  pack_wtp_kernel<<<(128 * 64 + 255) / 256, blk256, 0, stream>>>(w_gat, wtph, wtpl);
  pack_wt4_kernel<<<dim3((128 * 128 + 255) / 256, 4), blk256, 0, stream>>>(
      w2, w3, w4, w_shared, wtH, wtL);
  pack_wt192_kernel<<<(192 * 128 + 255) / 256, blk256, 0, stream>>>(
      w_m1, w_i1, w_e1, b_m1, b_i1, b_e1, wt192h, wt192l, b192);

  // 3) per-node attention logits
  a_sd_kernel<<<NB_SCAN, blk256, 0, stream>>>(x, wv_s, wv_d, a_s, a_d);

  // 4) fused GAT gather over x -> g[N,64]; also normalizes csr_ew for GCN
  gat_fused_kernel<<<wgrid, blk256, 0, stream>>>(
      x, a_s, a_d, dinv, rowptr, csr_src, csr_ew, g);

  // 5) GAT post-GEMM: p0 = relu(BN0(g @ Wp + b_gat))
  gemm_mfma_kernel<2, 64><<<mgrid, blk256, 0, stream>>>(
      g, wtph, wtpl, b_gat, bn_g + 0, bn_b + 0, bn_m + 0, bn_v + 0, p0, 1, 0);

  // 6) GCN layer 2: hb(bf16) = p0 @ w2 ; gather -> p1
  gemm_mfma_kernel<2, 128><<<mgrid, blk256, 0, stream>>>(
      p0, wt2h, wt2l, nullptr, nullptr, nullptr, nullptr, nullptr, hb, 0, 1);
  gcn_gather_kernel<<<wgrid, blk256, 0, stream>>>(
      hb, rowptr, csr_src, csr_ew, b2,
      bn_g + 128, bn_b + 128, bn_m + 128, bn_v + 128, p1);

  // 7) GCN layer 3
  gemm_mfma_kernel<2, 128><<<mgrid, blk256, 0, stream>>>(
      p1, wt3h, wt3l, nullptr, nullptr, nullptr, nullptr, nullptr, hb, 0, 1);
  gcn_gather_kernel<<<wgrid, blk256, 0, stream>>>(
      hb, rowptr, csr_src, csr_ew, b3,
      bn_g + 256, bn_b + 256, bn_m + 256, bn_v + 256, p0);

  // 8) GCN layer 4
  gemm_mfma_kernel<2, 128><<<mgrid, blk256, 0, stream>>>(
      p0, wt4h, wt4l, nullptr, nullptr, nullptr, nullptr, nullptr, hb, 0, 1);
  gcn_gather_kernel<<<wgrid, blk256, 0, stream>>>(
      hb, rowptr, csr_src, csr_ew, b4,
      bn_g + 384, bn_b + 384, bn_m + 384, bn_v + 384, p1);

  // 9) hs = relu(p1 @ w_shared + b_shared) -> p0 (f32)
  gemm_mfma_kernel<2, 128><<<mgrid, blk256, 0, stream>>>(
      p1, wsh, wsl, b_shared, nullptr, nullptr, nullptr, nullptr, p0, 1, 0);

  // 10) h192 = relu(p0 @ wt192 + b192) (f32)
  gemm_mfma_kernel<3, 128><<<mgrid, blk256, 0, stream>>>(
      p0, wt192h, wt192l, b192, nullptr, nullptr, nullptr, nullptr, h192, 1, 0);

  // 11) final heads -> d_out
  heads_final_kernel<<<wgrid, blk256, 0, stream>>>(
      h192, w_m2, b_m2, w_i2, b_i2, w_e2, b_e2, out);
}

// Round 11
// 369.840 us; speedup vs baseline: 2.3744x; 1.3527x over previous
//
#include <hip/hip_runtime.h>
#include <hip/hip_bf16.h>

#define NNODES 50000
#define NEDGES 400000
#define ETOT   (NEDGES + NNODES)
#define CIN    15
#define HID    128
#define HEADS  4
#define EPS_BN 1e-5f
#define NB_SCAN ((NNODES + 255) / 256)   // 196 blocks

typedef __attribute__((ext_vector_type(8))) short bf16x8_t;   // 8 bf16 = 4 VGPR
typedef __attribute__((ext_vector_type(4))) float f32x4_t;    // MFMA 16x16 acc

__device__ __forceinline__ float bfu(unsigned short u) {
  return __uint_as_float(((unsigned)u) << 16);
}
__device__ __forceinline__ unsigned short f2bf(float x) {
  union { __hip_bfloat16 b; unsigned short u; } c;
  c.b = __float2bfloat16(x);
  return c.u;
}
__device__ __forceinline__ float lrelu02(float x) {
  return x > 0.0f ? x : 0.2f * x;
}

// ---------------------------------------------------------------------------
// Split-bf16 MFMA GEMM:  C[M=NNODES, WPT*64] = epi(A[M,KT] @ W + bias)
// Wave w owns ALL 64 rows x cols [w*WPT*16, (w+1)*WPT*16). B fragments loaded
// ONCE to registers; inner loop pure ds_read_b128 + MFMA.
// ---------------------------------------------------------------------------
template <int WPT, int KT>
__global__ __launch_bounds__(256) void gemm_mfma_kernel(
    const float* __restrict__ A, const unsigned short* __restrict__ WTh,
    const unsigned short* __restrict__ WTl, const float* __restrict__ bias,
    const float* __restrict__ bg, const float* __restrict__ bb,
    const float* __restrict__ bm, const float* __restrict__ bv,
    void* __restrict__ Cout, int act, int obf16) {
  constexpr int NC = WPT * 64;
  constexpr int CPR = KT / 8;          // 8-elem chunks per row
  __shared__ unsigned short Ah[64 * KT];
  __shared__ unsigned short Al[64 * KT];
  const int tid = threadIdx.x;
  const int bm_ = blockIdx.x * 64;
  const int wv = tid >> 6, l = tid & 63;
  const int lcol = l & 15;
  const int kg = (l >> 4) << 3;
  const int colbase = wv * (WPT * 16);

  bf16x8_t bh[WPT][KT / 32], bl[WPT][KT / 32];
#pragma unroll
  for (int jj = 0; jj < WPT; ++jj)
#pragma unroll
    for (int kc = 0; kc < KT / 32; ++kc) {
      size_t boff = (size_t)(colbase + jj * 16 + lcol) * KT + kc * 32 + kg;
      bh[jj][kc] = *(const bf16x8_t*)(WTh + boff);
      bl[jj][kc] = *(const bf16x8_t*)(WTl + boff);
    }

#pragma unroll
  for (int i = 0; i < (64 * CPR) / 256; ++i) {
    int cch = tid + 256 * i;
    int r = cch / CPR, k0 = (cch % CPR) << 3;
    int gr = bm_ + r;
    float v[8];
    if (gr < NNODES) {
      float4 v0 = *(const float4*)&A[(size_t)gr * KT + k0];
      float4 v1 = *(const float4*)&A[(size_t)gr * KT + k0 + 4];
      v[0] = v0.x; v[1] = v0.y; v[2] = v0.z; v[3] = v0.w;
      v[4] = v1.x; v[5] = v1.y; v[6] = v1.z; v[7] = v1.w;
    } else {
#pragma unroll
      for (int j = 0; j < 8; ++j) v[j] = 0.0f;
    }
    bf16x8_t hv, lv;
#pragma unroll
    for (int j = 0; j < 8; ++j) {
      unsigned short h = f2bf(v[j]);
      hv[j] = (short)h;
      lv[j] = (short)f2bf(v[j] - bfu(h));
    }
    int byte = (k0 << 1) ^ ((r & 7) << 4);
    *(bf16x8_t*)((char*)(Ah + r * KT) + byte) = hv;
    *(bf16x8_t*)((char*)(Al + r * KT) + byte) = lv;
  }
  __syncthreads();

  f32x4_t acc[4][WPT];
#pragma unroll
  for (int rt = 0; rt < 4; ++rt)
#pragma unroll
    for (int jj = 0; jj < WPT; ++jj) acc[rt][jj] = (f32x4_t){0.f, 0.f, 0.f, 0.f};

#pragma unroll
  for (int kc = 0; kc < KT / 32; ++kc) {
    int k = kc * 32 + kg;
#pragma unroll
    for (int rt = 0; rt < 4; ++rt) {
      int lrow = rt * 16 + (l & 15);
      int byte = (k << 1) ^ ((lrow & 7) << 4);
      bf16x8_t ah = *(const bf16x8_t*)((const char*)(Ah + lrow * KT) + byte);
      bf16x8_t al = *(const bf16x8_t*)((const char*)(Al + lrow * KT) + byte);
#pragma unroll
      for (int jj = 0; jj < WPT; ++jj) {
        acc[rt][jj] = __builtin_amdgcn_mfma_f32_16x16x32_bf16(ah, bh[jj][kc], acc[rt][jj], 0, 0, 0);
        acc[rt][jj] = __builtin_amdgcn_mfma_f32_16x16x32_bf16(ah, bl[jj][kc], acc[rt][jj], 0, 0, 0);
        acc[rt][jj] = __builtin_amdgcn_mfma_f32_16x16x32_bf16(al, bh[jj][kc], acc[rt][jj], 0, 0, 0);
      }
    }
  }

  // C/D layout (m89-verified): col = lane&15, row = (lane>>4)*4 + reg
#pragma unroll
  for (int rt = 0; rt < 4; ++rt) {
    int orow0 = bm_ + rt * 16 + ((l >> 4) << 2);
#pragma unroll
    for (int jj = 0; jj < WPT; ++jj) {
      int col = colbase + jj * 16 + lcol;
      float bs = bias ? bias[col] : 0.0f;
#pragma unroll
      for (int r = 0; r < 4; ++r) {
        int row = orow0 + r;
        if (row >= NNODES) continue;
        float vv = acc[rt][jj][r] + bs;
        if (bg) vv = bg[col] * (vv - bm[col]) * rsqrtf(bv[col] + EPS_BN) + bb[col];
        if (act) vv = fmaxf(vv, 0.0f);
        if (obf16)
          ((unsigned short*)Cout)[(size_t)row * NC + col] = f2bf(vv);
        else
          ((float*)Cout)[(size_t)row * NC + col] = vv;
      }
    }
  }
}

// ---------------------------------------------------------------------------
// GAT precompute: wv_s[k,h] = sum_c w_gat[k, h*128+c]*att_s[h,c] (and _d)
// ---------------------------------------------------------------------------
__global__ void prep_att_kernel(const float* __restrict__ w,
                                const float* __restrict__ att_s,
                                const float* __restrict__ att_d,
                                float* __restrict__ wv_s,
                                float* __restrict__ wv_d) {
  int t = threadIdx.x;
  if (t >= 60) return;
  int k = t / 4, h = t & 3;
  float s = 0.f, d = 0.f;
  for (int c = 0; c < 128; ++c) {
    float wk = w[(size_t)k * 512 + h * 128 + c];
    s += wk * att_s[h * 128 + c];
    d += wk * att_d[h * 128 + c];
  }
  wv_s[k * 4 + h] = s;
  wv_d[k * 4 + h] = d;
}

// Pack post-GAT weight: Wp[c][j] = 0.25*w_gat[k, h*128+c], j=h*15+k (64-pad)
__global__ void pack_wtp_kernel(const float* __restrict__ w,
                                unsigned short* __restrict__ WTh,
                                unsigned short* __restrict__ WTl) {
  int i = blockIdx.x * blockDim.x + threadIdx.x;
  if (i >= 128 * 64) return;
  int c = i >> 6, j = i & 63;
  float xv = 0.f;
  if (j < 60) {
    int h = j / 15, k = j - h * 15;
    xv = 0.25f * w[(size_t)k * 512 + h * 128 + c];
  }
  unsigned short hh = f2bf(xv);
  WTh[i] = hh;
  WTl[i] = f2bf(xv - bfu(hh));
}

// ---------------------------------------------------------------------------
// Per-node attention logits: a_s[n,h] = sum_k x[n,k]*wv_s[k,h]
// ---------------------------------------------------------------------------
__global__ __launch_bounds__(256) void a_sd_kernel(
    const float* __restrict__ x, const float* __restrict__ wv_s,
    const float* __restrict__ wv_d, float* __restrict__ a_s,
    float* __restrict__ a_d) {
  __shared__ float xs[256 * 15];
  __shared__ float wvs[60], wvd[60];
  int t = threadIdx.x;
  int base = blockIdx.x * 256;
  if (t < 60) { wvs[t] = wv_s[t]; wvd[t] = wv_d[t]; }
  for (int i = t; i < 256 * 15; i += 256) {
    int gi = base * 15 + i;
    xs[i] = (gi < NNODES * 15) ? x[gi] : 0.0f;
  }
  __syncthreads();
  int n = base + t;
  if (n >= NNODES) return;
  float a0 = 0, a1 = 0, a2 = 0, a3 = 0, d0 = 0, d1 = 0, d2 = 0, d3 = 0;
#pragma unroll
  for (int k = 0; k < 15; ++k) {
    float xv = xs[t * 15 + k];
    a0 += xv * wvs[k * 4 + 0]; a1 += xv * wvs[k * 4 + 1];
    a2 += xv * wvs[k * 4 + 2]; a3 += xv * wvs[k * 4 + 3];
    d0 += xv * wvd[k * 4 + 0]; d1 += xv * wvd[k * 4 + 1];
    d2 += xv * wvd[k * 4 + 2]; d3 += xv * wvd[k * 4 + 3];
  }
  float4 A; A.x = a0; A.y = a1; A.z = a2; A.w = a3;
  float4 D; D.x = d0; D.y = d1; D.z = d2; D.w = d3;
  *(float4*)&a_s[n * 4] = A;
  *(float4*)&a_d[n * 4] = D;
}

// ---------------------------------------------------------------------------
// Fused GAT gather over x: wave per node; lane<60 -> (h=lane/15, k=lane%15).
// SINGLE pass (no max: |logits| <~ 12, exp safe in f32), unroll-4 for MLP.
// g[n,lane] = (sum_e ex_e * x[src_e,k]) / (sum_e ex_e)
// ---------------------------------------------------------------------------
__global__ __launch_bounds__(256) void gat_fused_kernel(
    const float* __restrict__ x, const float* __restrict__ a_s,
    const float* __restrict__ a_d, const int* __restrict__ rowptr,
    const int* __restrict__ csr_src, float* __restrict__ g) {
  int wid = threadIdx.x >> 6, lane = threadIdx.x & 63;
  int n = blockIdx.x * 4 + wid;
  if (n >= NNODES) return;
  int e0 = rowptr[n], e1 = rowptr[n + 1];
  bool on = lane < 60;
  int h = on ? (lane / 15) : 0;
  int k = on ? (lane - h * 15) : 0;
  float adn = a_d[n * 4 + h];

  float ssum = 0.f, acc = 0.f;
  int e = e0;
  for (; e + 4 <= e1; e += 4) {
    int s0 = csr_src[e + 0], s1 = csr_src[e + 1];
    int s2 = csr_src[e + 2], s3 = csr_src[e + 3];
    float as0 = a_s[s0 * 4 + h], as1 = a_s[s1 * 4 + h];
    float as2 = a_s[s2 * 4 + h], as3 = a_s[s3 * 4 + h];
    float x0 = x[(size_t)s0 * CIN + k], x1 = x[(size_t)s1 * CIN + k];
    float x2 = x[(size_t)s2 * CIN + k], x3 = x[(size_t)s3 * CIN + k];
    float ex0 = __expf(lrelu02(as0 + adn));
    float ex1 = __expf(lrelu02(as1 + adn));
    float ex2 = __expf(lrelu02(as2 + adn));
    float ex3 = __expf(lrelu02(as3 + adn));
    ssum += (ex0 + ex1) + (ex2 + ex3);
    acc += ex0 * x0 + ex1 * x1 + ex2 * x2 + ex3 * x3;
  }
  for (; e < e1; ++e) {
    int s = csr_src[e];
    float ex = __expf(lrelu02(a_s[s * 4 + h] + adn));
    ssum += ex;
    acc += ex * x[(size_t)s * CIN + k];
  }
  g[(size_t)n * 64 + lane] = on ? acc / (ssum + 1e-16f) : 0.0f;
}

// ---------------------------------------------------------------------------
// Fused pack of the four 128x128 weights -> [N][K] bf16 hi/lo (transposed)
// ---------------------------------------------------------------------------
__global__ void pack_wt4_kernel(
    const float* __restrict__ w2, const float* __restrict__ w3,
    const float* __restrict__ w4, const float* __restrict__ ws,
    unsigned short* __restrict__ Hbase, unsigned short* __restrict__ Lbase) {
  int i = blockIdx.x * blockDim.x + threadIdx.x;
  if (i >= 128 * 128) return;
  const float* W = (blockIdx.y == 0) ? w2 : (blockIdx.y == 1) ? w3
                 : (blockIdx.y == 2) ? w4 : ws;
  unsigned short* Wh = Hbase + (size_t)blockIdx.y * 128 * 128;
  unsigned short* Wl = Lbase + (size_t)blockIdx.y * 128 * 128;
  int k = i >> 7, n = i & 127;
  float x = W[i];
  unsigned short h = f2bf(x);
  Wh[n * 128 + k] = h;
  Wl[n * 128 + k] = f2bf(x - bfu(h));
}

// Pack the three 128x64 head weights into WT192 [192][128] hi/lo + b192
__global__ void pack_wt192_kernel(
    const float* __restrict__ w_m1, const float* __restrict__ w_i1,
    const float* __restrict__ w_e1, const float* __restrict__ b_m1,
    const float* __restrict__ b_i1, const float* __restrict__ b_e1,
    unsigned short* __restrict__ WTh, unsigned short* __restrict__ WTl,
    float* __restrict__ b192) {
  int i = blockIdx.x * blockDim.x + threadIdx.x;
  if (i < 192 * 128) {
    int n = i >> 7, k = i & 127;
    float x = (n < 64) ? w_m1[k * 64 + n]
            : (n < 128) ? w_i1[k * 64 + (n - 64)]
                        : w_e1[k * 64 + (n - 128)];
    unsigned short h = f2bf(x);
    WTh[(size_t)n * 128 + k] = h;
    WTl[(size_t)n * 128 + k] = f2bf(x - bfu(h));
  }
  if (i < 192) {
    b192[i] = (i < 64) ? b_m1[i] : (i < 128) ? b_i1[i - 64] : b_e1[i - 128];
  }
}

// ---------------------------------------------------------------------------
// CSR build: count+deg -> hierarchical scan -> dinv -> scatter(normalized)
// ---------------------------------------------------------------------------
__global__ void count_deg_kernel(const int* __restrict__ ei,
                                 const float* __restrict__ ea,
                                 int* __restrict__ cnt,
                                 float* __restrict__ deg) {
  int i = blockIdx.x * blockDim.x + threadIdx.x;
  if (i >= ETOT) return;
  int d; float w;
  if (i < NEDGES) { d = ei[NEDGES + i]; w = ea[i]; }
  else            { d = i - NEDGES; w = 1.0f; }
  atomicAdd(&cnt[d], 1);
  atomicAdd(&deg[d], w);
}

__global__ __launch_bounds__(256) void csr_reduce_kernel(
    const int* __restrict__ cnt, int* __restrict__ bsum) {
  __shared__ int red[256];
  int t = threadIdx.x;
  int i = blockIdx.x * 256 + t;
  red[t] = (i < NNODES) ? cnt[i] : 0;
  __syncthreads();
  for (int off = 128; off > 0; off >>= 1) {
    if (t < off) red[t] += red[t + off];
    __syncthreads();
  }
  if (t == 0) bsum[blockIdx.x] = red[0];
}

__global__ __launch_bounds__(256) void csr_scanb_kernel(
    const int* __restrict__ bsum, int* __restrict__ boff) {
  __shared__ int s[256];
  int t = threadIdx.x;
  s[t] = (t < NB_SCAN) ? bsum[t] : 0;
  __syncthreads();
  for (int off = 1; off < 256; off <<= 1) {
    int u = (t >= off) ? s[t - off] : 0;
    __syncthreads();
    s[t] += u;
    __syncthreads();
  }
  if (t < NB_SCAN) boff[t] = (t == 0) ? 0 : s[t - 1];
}

__global__ __launch_bounds__(256) void csr_scan_kernel(
    int* __restrict__ cnt, const int* __restrict__ boff,
    int* __restrict__ rowptr) {
  __shared__ int s[256];
  int t = threadIdx.x;
  int i = blockIdx.x * 256 + t;
  int v = (i < NNODES) ? cnt[i] : 0;
  s[t] = v;
  __syncthreads();
  for (int off = 1; off < 256; off <<= 1) {
    int u = (t >= off) ? s[t - off] : 0;
    __syncthreads();
    s[t] += u;
    __syncthreads();
  }
  if (i < NNODES) {
    rowptr[i] = boff[blockIdx.x] + s[t] - v;  // exclusive
    cnt[i] = 0;                               // reset -> scatter cursor
  }
  if (i == 0) rowptr[NNODES] = ETOT;
}

__global__ void dinv_kernel(const float* __restrict__ deg,
                            float* __restrict__ dinv) {
  int n = blockIdx.x * blockDim.x + threadIdx.x;
  if (n >= NNODES) return;
  float s = deg[n];
  dinv[n] = (s > 0.0f) ? rsqrtf(fmaxf(s, 1e-12f)) : 0.0f;
}

// scatter with pre-normalized GCN weight dinv[s]*w*dinv[d]
__global__ void scatter_kernel(const int* __restrict__ ei,
                               const float* __restrict__ ea,
                               const float* __restrict__ dinv,
                               const int* __restrict__ rowptr,
                               int* __restrict__ cursor,
                               int* __restrict__ csr_src,
                               float* __restrict__ csr_ew) {
  int i = blockIdx.x * blockDim.x + threadIdx.x;
  if (i >= ETOT) return;
  int s, d; float w;
  if (i < NEDGES) { s = ei[i]; d = ei[NEDGES + i]; w = ea[i]; }
  else            { s = d = i - NEDGES; w = 1.0f; }
  int pos = rowptr[d] + atomicAdd(&cursor[d], 1);
  csr_src[pos] = s;
  csr_ew[pos] = dinv[s] * w * dinv[d];
}

// ---------------------------------------------------------------------------
// GCN gather: wave per node; h bf16; csr_w prenormalized; unroll-4 for MLP;
// BN+ReLU fused.
// ---------------------------------------------------------------------------
__global__ __launch_bounds__(256) void gcn_gather_kernel(
    const __hip_bfloat16* __restrict__ h, const int* __restrict__ rowptr,
    const int* __restrict__ csr_src, const float* __restrict__ csr_w,
    const float* __restrict__ bias,
    const float* __restrict__ bg, const float* __restrict__ bb,
    const float* __restrict__ bm, const float* __restrict__ bv,
    float* __restrict__ out) {
  int wid = threadIdx.x >> 6, lane = threadIdx.x & 63;
  int n = blockIdx.x * 4 + wid;
  if (n >= NNODES) return;
  int e0 = rowptr[n], e1 = rowptr[n + 1];
  int c = 2 * lane;
  float ax = 0.f, ay = 0.f;
  int e = e0;
  for (; e + 4 <= e1; e += 4) {
    int s0 = csr_src[e + 0], s1 = csr_src[e + 1];
    int s2 = csr_src[e + 2], s3 = csr_src[e + 3];
    float w0 = csr_w[e + 0], w1 = csr_w[e + 1];
    float w2 = csr_w[e + 2], w3 = csr_w[e + 3];
    ushort2 u0 = *(const ushort2*)(h + (size_t)s0 * HID + c);
    ushort2 u1 = *(const ushort2*)(h + (size_t)s1 * HID + c);
    ushort2 u2 = *(const ushort2*)(h + (size_t)s2 * HID + c);
    ushort2 u3 = *(const ushort2*)(h + (size_t)s3 * HID + c);
    ax += w0 * bfu(u0.x) + w1 * bfu(u1.x) + w2 * bfu(u2.x) + w3 * bfu(u3.x);
    ay += w0 * bfu(u0.y) + w1 * bfu(u1.y) + w2 * bfu(u2.y) + w3 * bfu(u3.y);
  }
  for (; e < e1; ++e) {
    int s = csr_src[e];
    float w = csr_w[e];
    ushort2 u = *(const ushort2*)(h + (size_t)s * HID + c);
    ax += w * bfu(u.x);
    ay += w * bfu(u.y);
  }
  float ox = ax + bias[c];
  float oy = ay + bias[c + 1];
  ox = bg[c] * (ox - bm[c]) * rsqrtf(bv[c] + EPS_BN) + bb[c];
  oy = bg[c + 1] * (oy - bm[c + 1]) * rsqrtf(bv[c + 1] + EPS_BN) + bb[c + 1];
  ox = fmaxf(ox, 0.0f); oy = fmaxf(oy, 0.0f);
  float2 o; o.x = ox; o.y = oy;
  *(float2*)&out[(size_t)n * HID + c] = o;
}

// ---------------------------------------------------------------------------
// Final heads: from h192[N,192] (hm|hi|he) compute 5 outputs per node.
// ---------------------------------------------------------------------------
__global__ __launch_bounds__(256) void heads_final_kernel(
    const float* __restrict__ h192, const float* __restrict__ w_m2,
    const float* __restrict__ b_m2, const float* __restrict__ w_i2,
    const float* __restrict__ b_i2, const float* __restrict__ w_e2,
    const float* __restrict__ b_e2, float* __restrict__ out) {
  int wid = threadIdx.x >> 6;
  int lane = threadIdx.x & 63;
  int n = blockIdx.x * 4 + wid;
  if (n >= NNODES) return;
  const float* row = h192 + (size_t)n * 192;
  float hm = row[lane], hi = row[64 + lane], he = row[128 + lane];
  float p0 = hm * w_m2[lane * 2 + 0];
  float p1 = hm * w_m2[lane * 2 + 1];
  float p2 = hi * w_i2[lane * 2 + 0];
  float p3 = hi * w_i2[lane * 2 + 1];
  float p4 = he * w_e2[lane];
#pragma unroll
  for (int off = 32; off > 0; off >>= 1) {
    p0 += __shfl_down(p0, off);
    p1 += __shfl_down(p1, off);
    p2 += __shfl_down(p2, off);
    p3 += __shfl_down(p3, off);
    p4 += __shfl_down(p4, off);
  }
  if (lane == 0) {
    out[n * 2 + 0] = p0 + b_m2[0];
    out[n * 2 + 1] = p1 + b_m2[1];
    out[2 * NNODES + n * 2 + 0] = p2 + b_i2[0];
    out[2 * NNODES + n * 2 + 1] = p3 + b_i2[1];
    out[4 * NNODES + n] = p4 + b_e2[0];
  }
}

// ---------------------------------------------------------------------------
extern "C" void kernel_launch(void* const* d_in, const int* in_sizes, int n_in,
                              void* d_out, int out_size, void* d_ws, size_t ws_size,
                              hipStream_t stream) {
  const float* x       = (const float*)d_in[0];
  const int*   ei      = (const int*)d_in[1];
  const float* ea      = (const float*)d_in[2];
  const float* w_gat   = (const float*)d_in[3];
  const float* att_src = (const float*)d_in[4];
  const float* att_dst = (const float*)d_in[5];
  const float* b_gat   = (const float*)d_in[6];
  const float* w2 = (const float*)d_in[7];  const float* b2 = (const float*)d_in[8];
  const float* w3 = (const float*)d_in[9];  const float* b3 = (const float*)d_in[10];
  const float* w4 = (const float*)d_in[11]; const float* b4 = (const float*)d_in[12];
  const float* bn_g = (const float*)d_in[13];
  const float* bn_b = (const float*)d_in[14];
  const float* bn_m = (const float*)d_in[15];
  const float* bn_v = (const float*)d_in[16];
  const float* w_shared = (const float*)d_in[17]; const float* b_shared = (const float*)d_in[18];
  const float* w_m1 = (const float*)d_in[19]; const float* b_m1 = (const float*)d_in[20];
  const float* w_m2 = (const float*)d_in[21]; const float* b_m2 = (const float*)d_in[22];
  const float* w_i1 = (const float*)d_in[23]; const float* b_i1 = (const float*)d_in[24];
  const float* w_i2 = (const float*)d_in[25]; const float* b_i2 = (const float*)d_in[26];
  const float* w_e1 = (const float*)d_in[27]; const float* b_e1 = (const float*)d_in[28];
  const float* w_e2 = (const float*)d_in[29]; const float* b_e2 = (const float*)d_in[30];
  float* out = (float*)d_out;

  // ---- workspace layout ----
  size_t off = 0;
  auto alloc = [&](size_t bytes) -> char* {
    char* p = (char*)d_ws + off;
    off += (bytes + 255) & ~(size_t)255;
    return p;
  };
  float* p0      = (float*)alloc((size_t)NNODES * HID * 4);
  float* p1      = (float*)alloc((size_t)NNODES * HID * 4);
  float* h192    = (float*)alloc((size_t)NNODES * 192 * 4);
  float* g       = (float*)alloc((size_t)NNODES * 64 * 4);
  __hip_bfloat16* hb = (__hip_bfloat16*)alloc((size_t)NNODES * HID * 2);
  float* a_s     = (float*)alloc((size_t)NNODES * 4 * 4);
  float* a_d     = (float*)alloc((size_t)NNODES * 4 * 4);
  float* deg     = (float*)alloc((size_t)NNODES * 4);
  float* dinv    = (float*)alloc((size_t)NNODES * 4);
  float* csr_ew  = (float*)alloc((size_t)ETOT * 4);
  int*   rowptr  = (int*)alloc((size_t)(NNODES + 1) * 4);
  int*   cnt     = (int*)alloc((size_t)NNODES * 4);
  int*   csr_src = (int*)alloc((size_t)ETOT * 4);
  int*   bsum    = (int*)alloc((size_t)NB_SCAN * 4);
  int*   boff    = (int*)alloc((size_t)NB_SCAN * 4);
  // split-bf16 transposed weights
  unsigned short* wtH = (unsigned short*)alloc(4 * 128 * 128 * 2);
  unsigned short* wtL = (unsigned short*)alloc(4 * 128 * 128 * 2);
  unsigned short* wt192h = (unsigned short*)alloc(192 * 128 * 2);
  unsigned short* wt192l = (unsigned short*)alloc(192 * 128 * 2);
  unsigned short* wtph = (unsigned short*)alloc(128 * 64 * 2);
  unsigned short* wtpl = (unsigned short*)alloc(128 * 64 * 2);
  float* b192 = (float*)alloc(192 * 4);
  float* wv_s = (float*)alloc(60 * 4);
  float* wv_d = (float*)alloc(60 * 4);

  unsigned short* wt2h = wtH + 0 * 16384; unsigned short* wt2l = wtL + 0 * 16384;
  unsigned short* wt3h = wtH + 1 * 16384; unsigned short* wt3l = wtL + 1 * 16384;
  unsigned short* wt4h = wtH + 2 * 16384; unsigned short* wt4l = wtL + 2 * 16384;
  unsigned short* wsh  = wtH + 3 * 16384; unsigned short* wsl  = wtL + 3 * 16384;

  dim3 blk256(256);
  dim3 wgrid((NNODES + 3) / 4);
  dim3 mgrid((NNODES + 63) / 64);

  // 1) CSR build: count+deg -> scan (zeroes cnt) -> dinv -> scatter(norm'd)
  hipMemsetAsync(cnt, 0, NNODES * 4, stream);
  hipMemsetAsync(deg, 0, NNODES * 4, stream);
  count_deg_kernel<<<(ETOT + 255) / 256, blk256, 0, stream>>>(ei, ea, cnt, deg);
  csr_reduce_kernel<<<NB_SCAN, blk256, 0, stream>>>(cnt, bsum);
  csr_scanb_kernel<<<1, blk256, 0, stream>>>(bsum, boff);
  csr_scan_kernel<<<NB_SCAN, blk256, 0, stream>>>(cnt, boff, rowptr);
  dinv_kernel<<<(NNODES + 255) / 256, blk256, 0, stream>>>(deg, dinv);
  scatter_kernel<<<(ETOT + 255) / 256, blk256, 0, stream>>>(
      ei, ea, dinv, rowptr, cnt, csr_src, csr_ew);

  // 2) precompute + packs (independent)
  prep_att_kernel<<<1, 64, 0, stream>>>(w_gat, att_src, att_dst, wv_s, wv_d);
  pack_wtp_kernel<<<(128 * 64 + 255) / 256, blk256, 0, stream>>>(w_gat, wtph, wtpl);
  pack_wt4_kernel<<<dim3((128 * 128 + 255) / 256, 4), blk256, 0, stream>>>(
      w2, w3, w4, w_shared, wtH, wtL);
  pack_wt192_kernel<<<(192 * 128 + 255) / 256, blk256, 0, stream>>>(
      w_m1, w_i1, w_e1, b_m1, b_i1, b_e1, wt192h, wt192l, b192);

  // 3) per-node attention logits
  a_sd_kernel<<<NB_SCAN, blk256, 0, stream>>>(x, wv_s, wv_d, a_s, a_d);

  // 4) fused GAT gather over x -> g[N,64]
  gat_fused_kernel<<<wgrid, blk256, 0, stream>>>(
      x, a_s, a_d, rowptr, csr_src, g);

  // 5) GAT post-GEMM: p0 = relu(BN0(g @ Wp + b_gat))
  gemm_mfma_kernel<2, 64><<<mgrid, blk256, 0, stream>>>(
      g, wtph, wtpl, b_gat, bn_g + 0, bn_b + 0, bn_m + 0, bn_v + 0, p0, 1, 0);

  // 6) GCN layer 2: hb(bf16) = p0 @ w2 ; gather -> p1
  gemm_mfma_kernel<2, 128><<<mgrid, blk256, 0, stream>>>(
      p0, wt2h, wt2l, nullptr, nullptr, nullptr, nullptr, nullptr, hb, 0, 1);
  gcn_gather_kernel<<<wgrid, blk256, 0, stream>>>(
      hb, rowptr, csr_src, csr_ew, b2,
      bn_g + 128, bn_b + 128, bn_m + 128, bn_v + 128, p1);

  // 7) GCN layer 3
  gemm_mfma_kernel<2, 128><<<mgrid, blk256, 0, stream>>>(
      p1, wt3h, wt3l, nullptr, nullptr, nullptr, nullptr, nullptr, hb, 0, 1);
  gcn_gather_kernel<<<wgrid, blk256, 0, stream>>>(
      hb, rowptr, csr_src, csr_ew, b3,
      bn_g + 256, bn_b + 256, bn_m + 256, bn_v + 256, p0);

  // 8) GCN layer 4
  gemm_mfma_kernel<2, 128><<<mgrid, blk256, 0, stream>>>(
      p0, wt4h, wt4l, nullptr, nullptr, nullptr, nullptr, nullptr, hb, 0, 1);
  gcn_gather_kernel<<<wgrid, blk256, 0, stream>>>(
      hb, rowptr, csr_src, csr_ew, b4,
      bn_g + 384, bn_b + 384, bn_m + 384, bn_v + 384, p1);

  // 9) hs = relu(p1 @ w_shared + b_shared) -> p0 (f32)
  gemm_mfma_kernel<2, 128><<<mgrid, blk256, 0, stream>>>(
      p1, wsh, wsl, b_shared, nullptr, nullptr, nullptr, nullptr, p0, 1, 0);

  // 10) h192 = relu(p0 @ wt192 + b192) (f32)
  gemm_mfma_kernel<3, 128><<<mgrid, blk256, 0, stream>>>(
      p0, wt192h, wt192l, b192, nullptr, nullptr, nullptr, nullptr, h192, 1, 0);

  // 11) final heads -> d_out
  heads_final_kernel<<<wgrid, blk256, 0, stream>>>(
      h192, w_m2, b_m2, w_i2, b_i2, w_e2, b_e2, out);
}

// Round 12
// 353.455 us; speedup vs baseline: 2.4845x; 1.0464x over previous
//
#include <hip/hip_runtime.h>
#include <hip/hip_bf16.h>

#define NNODES 50000
#define NEDGES 400000
#define ETOT   (NEDGES + NNODES)
#define CIN    15
#define HID    128
#define HEADS  4
#define EPS_BN 1e-5f
#define NB_SCAN ((NNODES + 255) / 256)   // 196 blocks

typedef __attribute__((ext_vector_type(8))) short bf16x8_t;   // 8 bf16 = 4 VGPR
typedef __attribute__((ext_vector_type(4))) float f32x4_t;    // MFMA 16x16 acc

__device__ __forceinline__ float bfu(unsigned short u) {
  return __uint_as_float(((unsigned)u) << 16);
}
__device__ __forceinline__ unsigned short f2bf(float x) {
  union { __hip_bfloat16 b; unsigned short u; } c;
  c.b = __float2bfloat16(x);
  return c.u;
}
__device__ __forceinline__ float lrelu02(float x) {
  return x > 0.0f ? x : 0.2f * x;
}

// ---------------------------------------------------------------------------
// Split-bf16 MFMA GEMM:  C[M=NNODES, WPT*64] = epi(A[M,KT] @ W + bias)
// Wave w owns ALL 64 rows x cols [w*WPT*16,(w+1)*WPT*16); B frags in regs.
// Epilogue: bias/BN/ReLU applied into an LDS C-stage (stride NC+4, <=2-way
// bank aliasing), then flat coalesced copy-out (full 128B lines).
// ---------------------------------------------------------------------------
template <int WPT, int KT>
__global__ __launch_bounds__(256) void gemm_mfma_kernel(
    const float* __restrict__ A, const unsigned short* __restrict__ WTh,
    const unsigned short* __restrict__ WTl, const float* __restrict__ bias,
    const float* __restrict__ bg, const float* __restrict__ bb,
    const float* __restrict__ bm, const float* __restrict__ bv,
    void* __restrict__ Cout, int act, int obf16) {
  constexpr int NC = WPT * 64;
  constexpr int CST = NC + 4;          // C-stage stride (words)
  constexpr int CPR = KT / 8;          // 8-elem chunks per row
  constexpr int ABYTES = 64 * KT * 2 * 2;
  constexpr int CBYTES = 64 * CST * 4;
  constexpr int SBYTES = (ABYTES > CBYTES) ? ABYTES : CBYTES;
  __shared__ __align__(16) char smem[SBYTES];
  unsigned short* Ah = (unsigned short*)smem;
  unsigned short* Al = Ah + 64 * KT;
  float* Cs = (float*)smem;

  const int tid = threadIdx.x;
  const int bm_ = blockIdx.x * 64;
  const int wv = tid >> 6, l = tid & 63;
  const int lcol = l & 15;
  const int kg = (l >> 4) << 3;
  const int colbase = wv * (WPT * 16);

  // preload ALL B fragments for this wave's column strip (L2-resident)
  bf16x8_t bh[WPT][KT / 32], bl[WPT][KT / 32];
#pragma unroll
  for (int jj = 0; jj < WPT; ++jj)
#pragma unroll
    for (int kc = 0; kc < KT / 32; ++kc) {
      size_t boff = (size_t)(colbase + jj * 16 + lcol) * KT + kc * 32 + kg;
      bh[jj][kc] = *(const bf16x8_t*)(WTh + boff);
      bl[jj][kc] = *(const bf16x8_t*)(WTl + boff);
    }

  // stage A tile (64 x KT f32) -> hi/lo bf16 in LDS, XOR-swizzled
#pragma unroll
  for (int i = 0; i < (64 * CPR) / 256; ++i) {
    int cch = tid + 256 * i;
    int r = cch / CPR, k0 = (cch % CPR) << 3;
    int gr = bm_ + r;
    float v[8];
    if (gr < NNODES) {
      float4 v0 = *(const float4*)&A[(size_t)gr * KT + k0];
      float4 v1 = *(const float4*)&A[(size_t)gr * KT + k0 + 4];
      v[0] = v0.x; v[1] = v0.y; v[2] = v0.z; v[3] = v0.w;
      v[4] = v1.x; v[5] = v1.y; v[6] = v1.z; v[7] = v1.w;
    } else {
#pragma unroll
      for (int j = 0; j < 8; ++j) v[j] = 0.0f;
    }
    bf16x8_t hv, lv;
#pragma unroll
    for (int j = 0; j < 8; ++j) {
      unsigned short h = f2bf(v[j]);
      hv[j] = (short)h;
      lv[j] = (short)f2bf(v[j] - bfu(h));
    }
    int byte = (k0 << 1) ^ ((r & 7) << 4);
    *(bf16x8_t*)((char*)(Ah + r * KT) + byte) = hv;
    *(bf16x8_t*)((char*)(Al + r * KT) + byte) = lv;
  }
  __syncthreads();

  f32x4_t acc[4][WPT];
#pragma unroll
  for (int rt = 0; rt < 4; ++rt)
#pragma unroll
    for (int jj = 0; jj < WPT; ++jj) acc[rt][jj] = (f32x4_t){0.f, 0.f, 0.f, 0.f};

#pragma unroll
  for (int kc = 0; kc < KT / 32; ++kc) {
    int k = kc * 32 + kg;
#pragma unroll
    for (int rt = 0; rt < 4; ++rt) {
      int lrow = rt * 16 + (l & 15);
      int byte = (k << 1) ^ ((lrow & 7) << 4);
      bf16x8_t ah = *(const bf16x8_t*)((const char*)(Ah + lrow * KT) + byte);
      bf16x8_t al = *(const bf16x8_t*)((const char*)(Al + lrow * KT) + byte);
#pragma unroll
      for (int jj = 0; jj < WPT; ++jj) {
        acc[rt][jj] = __builtin_amdgcn_mfma_f32_16x16x32_bf16(ah, bh[jj][kc], acc[rt][jj], 0, 0, 0);
        acc[rt][jj] = __builtin_amdgcn_mfma_f32_16x16x32_bf16(ah, bl[jj][kc], acc[rt][jj], 0, 0, 0);
        acc[rt][jj] = __builtin_amdgcn_mfma_f32_16x16x32_bf16(al, bh[jj][kc], acc[rt][jj], 0, 0, 0);
      }
    }
  }

  // ---- epilogue: stage epi(C) into LDS (C/D layout m89: col=lane&15,
  // row=(lane>>4)*4+reg), then flat coalesced copy-out ----
  __syncthreads();   // all A reads done; safe to overwrite smem
#pragma unroll
  for (int rt = 0; rt < 4; ++rt) {
    int trow0 = rt * 16 + ((l >> 4) << 2);   // row within tile
#pragma unroll
    for (int jj = 0; jj < WPT; ++jj) {
      int col = colbase + jj * 16 + lcol;
      float bs = bias ? bias[col] : 0.0f;
#pragma unroll
      for (int r = 0; r < 4; ++r) {
        float vv = acc[rt][jj][r] + bs;
        if (bg) vv = bg[col] * (vv - bm[col]) * rsqrtf(bv[col] + EPS_BN) + bb[col];
        if (act) vv = fmaxf(vv, 0.0f);
        Cs[(trow0 + r) * CST + col] = vv;
      }
    }
  }
  __syncthreads();

  constexpr int NJ = NC / 16;   // float4s per thread
#pragma unroll
  for (int j = 0; j < NJ; ++j) {
    int f = tid * 4 + j * 1024;
    int r = f / NC, c = f - r * NC;
    int grow = bm_ + r;
    if (grow >= NNODES) continue;
    float4 v = *(const float4*)&Cs[r * CST + c];
    if (obf16) {
      ushort4 us;
      us.x = f2bf(v.x); us.y = f2bf(v.y); us.z = f2bf(v.z); us.w = f2bf(v.w);
      *(ushort4*)&((unsigned short*)Cout)[(size_t)grow * NC + c] = us;
    } else {
      *(float4*)&((float*)Cout)[(size_t)grow * NC + c] = v;
    }
  }
}

// ---------------------------------------------------------------------------
// GAT precompute: wv_s[k,h] = sum_c w_gat[k, h*128+c]*att_s[h,c] (and _d)
// ---------------------------------------------------------------------------
__global__ void prep_att_kernel(const float* __restrict__ w,
                                const float* __restrict__ att_s,
                                const float* __restrict__ att_d,
                                float* __restrict__ wv_s,
                                float* __restrict__ wv_d) {
  int t = threadIdx.x;
  if (t >= 60) return;
  int k = t / 4, h = t & 3;
  float s = 0.f, d = 0.f;
  for (int c = 0; c < 128; ++c) {
    float wk = w[(size_t)k * 512 + h * 128 + c];
    s += wk * att_s[h * 128 + c];
    d += wk * att_d[h * 128 + c];
  }
  wv_s[k * 4 + h] = s;
  wv_d[k * 4 + h] = d;
}

// Pack post-GAT weight: Wp[c][j] = 0.25*w_gat[k, h*128+c], j=h*15+k (64-pad)
__global__ void pack_wtp_kernel(const float* __restrict__ w,
                                unsigned short* __restrict__ WTh,
                                unsigned short* __restrict__ WTl) {
  int i = blockIdx.x * blockDim.x + threadIdx.x;
  if (i >= 128 * 64) return;
  int c = i >> 6, j = i & 63;
  float xv = 0.f;
  if (j < 60) {
    int h = j / 15, k = j - h * 15;
    xv = 0.25f * w[(size_t)k * 512 + h * 128 + c];
  }
  unsigned short hh = f2bf(xv);
  WTh[i] = hh;
  WTl[i] = f2bf(xv - bfu(hh));
}

// ---------------------------------------------------------------------------
// Per-node attention logits: a_s[n,h] = sum_k x[n,k]*wv_s[k,h]
// ---------------------------------------------------------------------------
__global__ __launch_bounds__(256) void a_sd_kernel(
    const float* __restrict__ x, const float* __restrict__ wv_s,
    const float* __restrict__ wv_d, float* __restrict__ a_s,
    float* __restrict__ a_d) {
  __shared__ float xs[256 * 15];
  __shared__ float wvs[60], wvd[60];
  int t = threadIdx.x;
  int base = blockIdx.x * 256;
  if (t < 60) { wvs[t] = wv_s[t]; wvd[t] = wv_d[t]; }
  for (int i = t; i < 256 * 15; i += 256) {
    int gi = base * 15 + i;
    xs[i] = (gi < NNODES * 15) ? x[gi] : 0.0f;
  }
  __syncthreads();
  int n = base + t;
  if (n >= NNODES) return;
  float a0 = 0, a1 = 0, a2 = 0, a3 = 0, d0 = 0, d1 = 0, d2 = 0, d3 = 0;
#pragma unroll
  for (int k = 0; k < 15; ++k) {
    float xv = xs[t * 15 + k];
    a0 += xv * wvs[k * 4 + 0]; a1 += xv * wvs[k * 4 + 1];
    a2 += xv * wvs[k * 4 + 2]; a3 += xv * wvs[k * 4 + 3];
    d0 += xv * wvd[k * 4 + 0]; d1 += xv * wvd[k * 4 + 1];
    d2 += xv * wvd[k * 4 + 2]; d3 += xv * wvd[k * 4 + 3];
  }
  float4 A; A.x = a0; A.y = a1; A.z = a2; A.w = a3;
  float4 D; D.x = d0; D.y = d1; D.z = d2; D.w = d3;
  *(float4*)&a_s[n * 4] = A;
  *(float4*)&a_d[n * 4] = D;
}

// ---------------------------------------------------------------------------
// Fused GAT gather over x: wave per node; lane<60 -> (h=lane/15, k=lane%15).
// SINGLE pass (no max: |logits| <~ 12, exp safe in f32), unroll-4 for MLP.
// ---------------------------------------------------------------------------
__global__ __launch_bounds__(256) void gat_fused_kernel(
    const float* __restrict__ x, const float* __restrict__ a_s,
    const float* __restrict__ a_d, const int* __restrict__ rowptr,
    const int* __restrict__ csr_src, float* __restrict__ g) {
  int wid = threadIdx.x >> 6, lane = threadIdx.x & 63;
  int n = blockIdx.x * 4 + wid;
  if (n >= NNODES) return;
  int e0 = rowptr[n], e1 = rowptr[n + 1];
  bool on = lane < 60;
  int h = on ? (lane / 15) : 0;
  int k = on ? (lane - h * 15) : 0;
  float adn = a_d[n * 4 + h];

  float ssum = 0.f, acc = 0.f;
  int e = e0;
  for (; e + 4 <= e1; e += 4) {
    int s0 = csr_src[e + 0], s1 = csr_src[e + 1];
    int s2 = csr_src[e + 2], s3 = csr_src[e + 3];
    float as0 = a_s[s0 * 4 + h], as1 = a_s[s1 * 4 + h];
    float as2 = a_s[s2 * 4 + h], as3 = a_s[s3 * 4 + h];
    float x0 = x[(size_t)s0 * CIN + k], x1 = x[(size_t)s1 * CIN + k];
    float x2 = x[(size_t)s2 * CIN + k], x3 = x[(size_t)s3 * CIN + k];
    float ex0 = __expf(lrelu02(as0 + adn));
    float ex1 = __expf(lrelu02(as1 + adn));
    float ex2 = __expf(lrelu02(as2 + adn));
    float ex3 = __expf(lrelu02(as3 + adn));
    ssum += (ex0 + ex1) + (ex2 + ex3);
    acc += ex0 * x0 + ex1 * x1 + ex2 * x2 + ex3 * x3;
  }
  for (; e < e1; ++e) {
    int s = csr_src[e];
    float ex = __expf(lrelu02(a_s[s * 4 + h] + adn));
    ssum += ex;
    acc += ex * x[(size_t)s * CIN + k];
  }
  g[(size_t)n * 64 + lane] = on ? acc / (ssum + 1e-16f) : 0.0f;
}

// ---------------------------------------------------------------------------
// Fused pack of the four 128x128 weights -> [N][K] bf16 hi/lo (transposed)
// ---------------------------------------------------------------------------
__global__ void pack_wt4_kernel(
    const float* __restrict__ w2, const float* __restrict__ w3,
    const float* __restrict__ w4, const float* __restrict__ ws,
    unsigned short* __restrict__ Hbase, unsigned short* __restrict__ Lbase) {
  int i = blockIdx.x * blockDim.x + threadIdx.x;
  if (i >= 128 * 128) return;
  const float* W = (blockIdx.y == 0) ? w2 : (blockIdx.y == 1) ? w3
                 : (blockIdx.y == 2) ? w4 : ws;
  unsigned short* Wh = Hbase + (size_t)blockIdx.y * 128 * 128;
  unsigned short* Wl = Lbase + (size_t)blockIdx.y * 128 * 128;
  int k = i >> 7, n = i & 127;
  float x = W[i];
  unsigned short h = f2bf(x);
  Wh[n * 128 + k] = h;
  Wl[n * 128 + k] = f2bf(x - bfu(h));
}

// Pack the three 128x64 head weights into WT192 [192][128] hi/lo + b192
__global__ void pack_wt192_kernel(
    const float* __restrict__ w_m1, const float* __restrict__ w_i1,
    const float* __restrict__ w_e1, const float* __restrict__ b_m1,
    const float* __restrict__ b_i1, const float* __restrict__ b_e1,
    unsigned short* __restrict__ WTh, unsigned short* __restrict__ WTl,
    float* __restrict__ b192) {
  int i = blockIdx.x * blockDim.x + threadIdx.x;
  if (i < 192 * 128) {
    int n = i >> 7, k = i & 127;
    float x = (n < 64) ? w_m1[k * 64 + n]
            : (n < 128) ? w_i1[k * 64 + (n - 64)]
                        : w_e1[k * 64 + (n - 128)];
    unsigned short h = f2bf(x);
    WTh[(size_t)n * 128 + k] = h;
    WTl[(size_t)n * 128 + k] = f2bf(x - bfu(h));
  }
  if (i < 192) {
    b192[i] = (i < 64) ? b_m1[i] : (i < 128) ? b_i1[i - 64] : b_e1[i - 128];
  }
}

// ---------------------------------------------------------------------------
// CSR build: count+deg -> hierarchical scan -> dinv -> scatter(normalized)
// ---------------------------------------------------------------------------
__global__ void count_deg_kernel(const int* __restrict__ ei,
                                 const float* __restrict__ ea,
                                 int* __restrict__ cnt,
                                 float* __restrict__ deg) {
  int i = blockIdx.x * blockDim.x + threadIdx.x;
  if (i >= ETOT) return;
  int d; float w;
  if (i < NEDGES) { d = ei[NEDGES + i]; w = ea[i]; }
  else            { d = i - NEDGES; w = 1.0f; }
  atomicAdd(&cnt[d], 1);
  atomicAdd(&deg[d], w);
}

__global__ __launch_bounds__(256) void csr_reduce_kernel(
    const int* __restrict__ cnt, int* __restrict__ bsum) {
  __shared__ int red[256];
  int t = threadIdx.x;
  int i = blockIdx.x * 256 + t;
  red[t] = (i < NNODES) ? cnt[i] : 0;
  __syncthreads();
  for (int off = 128; off > 0; off >>= 1) {
    if (t < off) red[t] += red[t + off];
    __syncthreads();
  }
  if (t == 0) bsum[blockIdx.x] = red[0];
}

__global__ __launch_bounds__(256) void csr_scanb_kernel(
    const int* __restrict__ bsum, int* __restrict__ boff) {
  __shared__ int s[256];
  int t = threadIdx.x;
  s[t] = (t < NB_SCAN) ? bsum[t] : 0;
  __syncthreads();
  for (int off = 1; off < 256; off <<= 1) {
    int u = (t >= off) ? s[t - off] : 0;
    __syncthreads();
    s[t] += u;
    __syncthreads();
  }
  if (t < NB_SCAN) boff[t] = (t == 0) ? 0 : s[t - 1];
}

__global__ __launch_bounds__(256) void csr_scan_kernel(
    int* __restrict__ cnt, const int* __restrict__ boff,
    int* __restrict__ rowptr) {
  __shared__ int s[256];
  int t = threadIdx.x;
  int i = blockIdx.x * 256 + t;
  int v = (i < NNODES) ? cnt[i] : 0;
  s[t] = v;
  __syncthreads();
  for (int off = 1; off < 256; off <<= 1) {
    int u = (t >= off) ? s[t - off] : 0;
    __syncthreads();
    s[t] += u;
    __syncthreads();
  }
  if (i < NNODES) {
    rowptr[i] = boff[blockIdx.x] + s[t] - v;  // exclusive
    cnt[i] = 0;                               // reset -> scatter cursor
  }
  if (i == 0) rowptr[NNODES] = ETOT;
}

__global__ void dinv_kernel(const float* __restrict__ deg,
                            float* __restrict__ dinv) {
  int n = blockIdx.x * blockDim.x + threadIdx.x;
  if (n >= NNODES) return;
  float s = deg[n];
  dinv[n] = (s > 0.0f) ? rsqrtf(fmaxf(s, 1e-12f)) : 0.0f;
}

// scatter with pre-normalized GCN weight dinv[s]*w*dinv[d]
__global__ void scatter_kernel(const int* __restrict__ ei,
                               const float* __restrict__ ea,
                               const float* __restrict__ dinv,
                               const int* __restrict__ rowptr,
                               int* __restrict__ cursor,
                               int* __restrict__ csr_src,
                               float* __restrict__ csr_ew) {
  int i = blockIdx.x * blockDim.x + threadIdx.x;
  if (i >= ETOT) return;
  int s, d; float w;
  if (i < NEDGES) { s = ei[i]; d = ei[NEDGES + i]; w = ea[i]; }
  else            { s = d = i - NEDGES; w = 1.0f; }
  int pos = rowptr[d] + atomicAdd(&cursor[d], 1);
  csr_src[pos] = s;
  csr_ew[pos] = dinv[s] * w * dinv[d];
}

// ---------------------------------------------------------------------------
// GCN gather: wave per node; h bf16; csr_w prenormalized; unroll-4 for MLP;
// BN+ReLU fused.
// ---------------------------------------------------------------------------
__global__ __launch_bounds__(256) void gcn_gather_kernel(
    const __hip_bfloat16* __restrict__ h, const int* __restrict__ rowptr,
    const int* __restrict__ csr_src, const float* __restrict__ csr_w,
    const float* __restrict__ bias,
    const float* __restrict__ bg, const float* __restrict__ bb,
    const float* __restrict__ bm, const float* __restrict__ bv,
    float* __restrict__ out) {
  int wid = threadIdx.x >> 6, lane = threadIdx.x & 63;
  int n = blockIdx.x * 4 + wid;
  if (n >= NNODES) return;
  int e0 = rowptr[n], e1 = rowptr[n + 1];
  int c = 2 * lane;
  float ax = 0.f, ay = 0.f;
  int e = e0;
  for (; e + 4 <= e1; e += 4) {
    int s0 = csr_src[e + 0], s1 = csr_src[e + 1];
    int s2 = csr_src[e + 2], s3 = csr_src[e + 3];
    float w0 = csr_w[e + 0], w1 = csr_w[e + 1];
    float w2 = csr_w[e + 2], w3 = csr_w[e + 3];
    ushort2 u0 = *(const ushort2*)(h + (size_t)s0 * HID + c);
    ushort2 u1 = *(const ushort2*)(h + (size_t)s1 * HID + c);
    ushort2 u2 = *(const ushort2*)(h + (size_t)s2 * HID + c);
    ushort2 u3 = *(const ushort2*)(h + (size_t)s3 * HID + c);
    ax += w0 * bfu(u0.x) + w1 * bfu(u1.x) + w2 * bfu(u2.x) + w3 * bfu(u3.x);
    ay += w0 * bfu(u0.y) + w1 * bfu(u1.y) + w2 * bfu(u2.y) + w3 * bfu(u3.y);
  }
  for (; e < e1; ++e) {
    int s = csr_src[e];
    float w = csr_w[e];
    ushort2 u = *(const ushort2*)(h + (size_t)s * HID + c);
    ax += w * bfu(u.x);
    ay += w * bfu(u.y);
  }
  float ox = ax + bias[c];
  float oy = ay + bias[c + 1];
  ox = bg[c] * (ox - bm[c]) * rsqrtf(bv[c] + EPS_BN) + bb[c];
  oy = bg[c + 1] * (oy - bm[c + 1]) * rsqrtf(bv[c + 1] + EPS_BN) + bb[c + 1];
  ox = fmaxf(ox, 0.0f); oy = fmaxf(oy, 0.0f);
  float2 o; o.x = ox; o.y = oy;
  *(float2*)&out[(size_t)n * HID + c] = o;
}

// ---------------------------------------------------------------------------
// Final heads: from h192[N,192] (hm|hi|he) compute 5 outputs per node.
// ---------------------------------------------------------------------------
__global__ __launch_bounds__(256) void heads_final_kernel(
    const float* __restrict__ h192, const float* __restrict__ w_m2,
    const float* __restrict__ b_m2, const float* __restrict__ w_i2,
    const float* __restrict__ b_i2, const float* __restrict__ w_e2,
    const float* __restrict__ b_e2, float* __restrict__ out) {
  int wid = threadIdx.x >> 6;
  int lane = threadIdx.x & 63;
  int n = blockIdx.x * 4 + wid;
  if (n >= NNODES) return;
  const float* row = h192 + (size_t)n * 192;
  float hm = row[lane], hi = row[64 + lane], he = row[128 + lane];
  float p0 = hm * w_m2[lane * 2 + 0];
  float p1 = hm * w_m2[lane * 2 + 1];
  float p2 = hi * w_i2[lane * 2 + 0];
  float p3 = hi * w_i2[lane * 2 + 1];
  float p4 = he * w_e2[lane];
#pragma unroll
  for (int off = 32; off > 0; off >>= 1) {
    p0 += __shfl_down(p0, off);
    p1 += __shfl_down(p1, off);
    p2 += __shfl_down(p2, off);
    p3 += __shfl_down(p3, off);
    p4 += __shfl_down(p4, off);
  }
  if (lane == 0) {
    out[n * 2 + 0] = p0 + b_m2[0];
    out[n * 2 + 1] = p1 + b_m2[1];
    out[2 * NNODES + n * 2 + 0] = p2 + b_i2[0];
    out[2 * NNODES + n * 2 + 1] = p3 + b_i2[1];
    out[4 * NNODES + n] = p4 + b_e2[0];
  }
}

// ---------------------------------------------------------------------------
extern "C" void kernel_launch(void* const* d_in, const int* in_sizes, int n_in,
                              void* d_out, int out_size, void* d_ws, size_t ws_size,
                              hipStream_t stream) {
  const float* x       = (const float*)d_in[0];
  const int*   ei      = (const int*)d_in[1];
  const float* ea      = (const float*)d_in[2];
  const float* w_gat   = (const float*)d_in[3];
  const float* att_src = (const float*)d_in[4];
  const float* att_dst = (const float*)d_in[5];
  const float* b_gat   = (const float*)d_in[6];
  const float* w2 = (const float*)d_in[7];  const float* b2 = (const float*)d_in[8];
  const float* w3 = (const float*)d_in[9];  const float* b3 = (const float*)d_in[10];
  const float* w4 = (const float*)d_in[11]; const float* b4 = (const float*)d_in[12];
  const float* bn_g = (const float*)d_in[13];
  const float* bn_b = (const float*)d_in[14];
  const float* bn_m = (const float*)d_in[15];
  const float* bn_v = (const float*)d_in[16];
  const float* w_shared = (const float*)d_in[17]; const float* b_shared = (const float*)d_in[18];
  const float* w_m1 = (const float*)d_in[19]; const float* b_m1 = (const float*)d_in[20];
  const float* w_m2 = (const float*)d_in[21]; const float* b_m2 = (const float*)d_in[22];
  const float* w_i1 = (const float*)d_in[23]; const float* b_i1 = (const float*)d_in[24];
  const float* w_i2 = (const float*)d_in[25]; const float* b_i2 = (const float*)d_in[26];
  const float* w_e1 = (const float*)d_in[27]; const float* b_e1 = (const float*)d_in[28];
  const float* w_e2 = (const float*)d_in[29]; const float* b_e2 = (const float*)d_in[30];
  float* out = (float*)d_out;

  // ---- workspace layout ----
  size_t off = 0;
  auto alloc = [&](size_t bytes) -> char* {
    char* p = (char*)d_ws + off;
    off += (bytes + 255) & ~(size_t)255;
    return p;
  };
  float* p0      = (float*)alloc((size_t)NNODES * HID * 4);
  float* p1      = (float*)alloc((size_t)NNODES * HID * 4);
  float* h192    = (float*)alloc((size_t)NNODES * 192 * 4);
  float* g       = (float*)alloc((size_t)NNODES * 64 * 4);
  __hip_bfloat16* hb = (__hip_bfloat16*)alloc((size_t)NNODES * HID * 2);
  float* a_s     = (float*)alloc((size_t)NNODES * 4 * 4);
  float* a_d     = (float*)alloc((size_t)NNODES * 4 * 4);
  float* deg     = (float*)alloc((size_t)NNODES * 4);
  float* dinv    = (float*)alloc((size_t)NNODES * 4);
  float* csr_ew  = (float*)alloc((size_t)ETOT * 4);
  int*   rowptr  = (int*)alloc((size_t)(NNODES + 1) * 4);
  int*   cnt     = (int*)alloc((size_t)NNODES * 4);
  int*   csr_src = (int*)alloc((size_t)ETOT * 4);
  int*   bsum    = (int*)alloc((size_t)NB_SCAN * 4);
  int*   boff    = (int*)alloc((size_t)NB_SCAN * 4);
  // split-bf16 transposed weights
  unsigned short* wtH = (unsigned short*)alloc(4 * 128 * 128 * 2);
  unsigned short* wtL = (unsigned short*)alloc(4 * 128 * 128 * 2);
  unsigned short* wt192h = (unsigned short*)alloc(192 * 128 * 2);
  unsigned short* wt192l = (unsigned short*)alloc(192 * 128 * 2);
  unsigned short* wtph = (unsigned short*)alloc(128 * 64 * 2);
  unsigned short* wtpl = (unsigned short*)alloc(128 * 64 * 2);
  float* b192 = (float*)alloc(192 * 4);
  float* wv_s = (float*)alloc(60 * 4);
  float* wv_d = (float*)alloc(60 * 4);

  unsigned short* wt2h = wtH + 0 * 16384; unsigned short* wt2l = wtL + 0 * 16384;
  unsigned short* wt3h = wtH + 1 * 16384; unsigned short* wt3l = wtL + 1 * 16384;
  unsigned short* wt4h = wtH + 2 * 16384; unsigned short* wt4l = wtL + 2 * 16384;
  unsigned short* wsh  = wtH + 3 * 16384; unsigned short* wsl  = wtL + 3 * 16384;

  dim3 blk256(256);
  dim3 wgrid((NNODES + 3) / 4);
  dim3 mgrid((NNODES + 63) / 64);

  // 1) CSR build: count+deg -> scan (zeroes cnt) -> dinv -> scatter(norm'd)
  hipMemsetAsync(cnt, 0, NNODES * 4, stream);
  hipMemsetAsync(deg, 0, NNODES * 4, stream);
  count_deg_kernel<<<(ETOT + 255) / 256, blk256, 0, stream>>>(ei, ea, cnt, deg);
  csr_reduce_kernel<<<NB_SCAN, blk256, 0, stream>>>(cnt, bsum);
  csr_scanb_kernel<<<1, blk256, 0, stream>>>(bsum, boff);
  csr_scan_kernel<<<NB_SCAN, blk256, 0, stream>>>(cnt, boff, rowptr);
  dinv_kernel<<<(NNODES + 255) / 256, blk256, 0, stream>>>(deg, dinv);
  scatter_kernel<<<(ETOT + 255) / 256, blk256, 0, stream>>>(
      ei, ea, dinv, rowptr, cnt, csr_src, csr_ew);

  // 2) precompute + packs (independent)
  prep_att_kernel<<<1, 64, 0, stream>>>(w_gat, att_src, att_dst, wv_s, wv_d);
  pack_wtp_kernel<<<(128 * 64 + 255) / 256, blk256, 0, stream>>>(w_gat, wtph, wtpl);
  pack_wt4_kernel<<<dim3((128 * 128 + 255) / 256, 4), blk256, 0, stream>>>(
      w2, w3, w4, w_shared, wtH, wtL);
  pack_wt192_kernel<<<(192 * 128 + 255) / 256, blk256, 0, stream>>>(
      w_m1, w_i1, w_e1, b_m1, b_i1, b_e1, wt192h, wt192l, b192);

  // 3) per-node attention logits
  a_sd_kernel<<<NB_SCAN, blk256, 0, stream>>>(x, wv_s, wv_d, a_s, a_d);

  // 4) fused GAT gather over x -> g[N,64]
  gat_fused_kernel<<<wgrid, blk256, 0, stream>>>(
      x, a_s, a_d, rowptr, csr_src, g);

  // 5) GAT post-GEMM: p0 = relu(BN0(g @ Wp + b_gat))
  gemm_mfma_kernel<2, 64><<<mgrid, blk256, 0, stream>>>(
      g, wtph, wtpl, b_gat, bn_g + 0, bn_b + 0, bn_m + 0, bn_v + 0, p0, 1, 0);

  // 6) GCN layer 2: hb(bf16) = p0 @ w2 ; gather -> p1
  gemm_mfma_kernel<2, 128><<<mgrid, blk256, 0, stream>>>(
      p0, wt2h, wt2l, nullptr, nullptr, nullptr, nullptr, nullptr, hb, 0, 1);
  gcn_gather_kernel<<<wgrid, blk256, 0, stream>>>(
      hb, rowptr, csr_src, csr_ew, b2,
      bn_g + 128, bn_b + 128, bn_m + 128, bn_v + 128, p1);

  // 7) GCN layer 3
  gemm_mfma_kernel<2, 128><<<mgrid, blk256, 0, stream>>>(
      p1, wt3h, wt3l, nullptr, nullptr, nullptr, nullptr, nullptr, hb, 0, 1);
  gcn_gather_kernel<<<wgrid, blk256, 0, stream>>>(
      hb, rowptr, csr_src, csr_ew, b3,
      bn_g + 256, bn_b + 256, bn_m + 256, bn_v + 256, p0);

  // 8) GCN layer 4
  gemm_mfma_kernel<2, 128><<<mgrid, blk256, 0, stream>>>(
      p0, wt4h, wt4l, nullptr, nullptr, nullptr, nullptr, nullptr, hb, 0, 1);
  gcn_gather_kernel<<<wgrid, blk256, 0, stream>>>(
      hb, rowptr, csr_src, csr_ew, b4,
      bn_g + 384, bn_b + 384, bn_m + 384, bn_v + 384, p1);

  // 9) hs = relu(p1 @ w_shared + b_shared) -> p0 (f32)
  gemm_mfma_kernel<2, 128><<<mgrid, blk256, 0, stream>>>(
      p1, wsh, wsl, b_shared, nullptr, nullptr, nullptr, nullptr, p0, 1, 0);

  // 10) h192 = relu(p0 @ wt192 + b192) (f32)
  gemm_mfma_kernel<3, 128><<<mgrid, blk256, 0, stream>>>(
      p0, wt192h, wt192l, b192, nullptr, nullptr, nullptr, nullptr, h192, 1, 0);

  // 11) final heads -> d_out
  heads_final_kernel<<<wgrid, blk256, 0, stream>>>(
      h192, w_m2, b_m2, w_i2, b_i2, w_e2, b_e2, out);
}